// Round 15
// baseline (466.682 us; speedup 1.0000x reference)
//
#include <hip/hip_runtime.h>
#include <math.h>
#include <stdint.h>

typedef __attribute__((ext_vector_type(8))) short short8;
typedef __attribute__((ext_vector_type(4))) float floatx4;

// fp32 -> (bf16 hi | bf16 lo) packed u32.  hi = RNE(x), lo = RNE(x - hi).
__device__ __forceinline__ uint32_t pack_hilo(float x) {
    uint32_t u = __float_as_uint(x);
    uint32_t hi = (u + 0x7FFFu + ((u >> 16) & 1u)) & 0xFFFF0000u;
    float r = x - __uint_as_float(hi);
    uint32_t v = __float_as_uint(r);
    uint32_t lo = ((v + 0x7FFFu + ((v >> 16) & 1u)) >> 16) & 0xFFFFu;
    return hi | lo;
}

// fp32 -> bf16 (RNE), low 16 bits of result.
__device__ __forceinline__ uint32_t bf16rne(float x) {
    uint32_t u = __float_as_uint(x);
    return ((u + 0x7FFFu + ((u >> 16) & 1u)) >> 16) & 0xFFFFu;
}

// async global->LDS DMA, 16 B per lane; lds dest must be wave-uniform base.
__device__ __forceinline__ void dma16(short* lds, const short* g) {
    __builtin_amdgcn_global_load_lds(
        (const __attribute__((address_space(1))) unsigned int*)g,
        (__attribute__((address_space(3))) unsigned int*)lds,
        16, 0, 0);
}

// ---------------------------------------------------------------------------
// Merged prep: conv weights (blocks 0..255) + all activations (256..5375).
// Activations store bf16-hi ONLY (2-term scheme).
// ---------------------------------------------------------------------------
__global__ __launch_bounds__(256) void prep_all(
    const float* __restrict__ wA, short* __restrict__ whA, short* __restrict__ wlA,
    const float* __restrict__ wB, short* __restrict__ whB, short* __restrict__ wlB,
    const float* __restrict__ xs, short* __restrict__ xhS,
    const float* __restrict__ xL, short* __restrict__ xhL,
    const float* __restrict__ xM, short* __restrict__ xhM,
    const float* __restrict__ xSm, short* __restrict__ xhSm)
{
    const int blk = blockIdx.x;
    if (blk < 256) {
        // ---- weight prep: fetch-order layout.  Lane-linear A-fragments:
        // frag(tile, cob, lane) at ((tile)*16 + cob)*512 + lane*8  ----
        int bx = blk;
        const float* w; short *wh, *wl;
        if (bx < 128) { w = wA; wh = whA; wl = wlA; }
        else          { w = wB; wh = whB; wl = wlB; bx -= 128; }
        const int idx = bx * 256 + threadIdx.x;
        const int co = idx >> 7, jp = idx & 127;      // ci = 2*jp
        const int c4 = jp >> 4;                       // ci>>5
        const int g  = (jp >> 2) & 3;                 // (ci>>3)&3
        const int cw = 2 * (jp & 3);                  // ci&7
        const float* s0 = w + ((size_t)co * 256 + 2 * jp) * 9;
        #pragma unroll
        for (int r = 0; r < 9; ++r) {
            uint32_t q0 = pack_hilo(s0[r]);
            uint32_t q1 = pack_hilo(s0[9 + r]);
            size_t o = ((size_t)(r * 8 + c4) * 16 + (co >> 4)) * 512
                     + (size_t)(g * 16 + (co & 15)) * 8 + cw;
            *(uint32_t*)(wh + o) = (q0 >> 16) | (q1 & 0xFFFF0000u);
            *(uint32_t*)(wl + o) = (q0 & 0xFFFFu) | (q1 << 16);
        }
        return;
    }
    // ---- activation prep (bf16 hi only) ----
    const int i = blk - 256;            // 0..5119
    const int bx = i % 20;
    const int by = (i / 20) & 3;
    const int b  = i / 80;

    const float* x; short *xh; int HW, p0;
    if (bx < 16)      { x = xs;  xh = xhS;  HW = 961; p0 = bx * 64; }
    else if (bx < 18) { x = xL;  xh = xhL;  HW = 81;  p0 = (bx - 16) * 64; }
    else if (bx < 19) { x = xM;  xh = xhM;  HW = 49;  p0 = 0; }
    else              { x = xSm; xh = xhSm; HW = 25;  p0 = 0; }

    const int c0 = by * 64;
    const int tid = threadIdx.x;
    const int a = tid & 63, g = tid >> 6;
    __shared__ uint32_t t[64][65];
    #pragma unroll
    for (int ii = 0; ii < 16; ++ii) {
        int c = g + ii * 4;
        int p = p0 + a;
        float v = (p < HW) ? x[((size_t)(b * 256) + c0 + c) * HW + p] : 0.0f;
        t[c][a] = pack_hilo(v);
    }
    __syncthreads();
    const int j = tid & 31;
    const int gg = tid >> 5;
    #pragma unroll
    for (int ii = 0; ii < 8; ++ii) {
        int p = gg + ii * 8;
        if (p0 + p < HW) {
            uint32_t w0 = t[2 * j][p], w1 = t[2 * j + 1][p];
            size_t o = ((size_t)b * HW + p0 + p) * 256 + c0 + 2 * j;
            *(uint32_t*)(xh + o) = (w0 >> 16) | (w1 & 0xFFFF0000u);
        }
    }
}

// ---------------------------------------------------------------------------
// Prep w1 (256,256) fp32 -> granule-swizzled chunk-major hi/lo (lane-linear
// A-fragment reads in head).  grid (64).  Runs after corr (lives in dead sq).
// ---------------------------------------------------------------------------
__global__ __launch_bounds__(256) void prep_w1(
    const float* __restrict__ w1, short* __restrict__ w1hT, short* __restrict__ w1lT)
{
    const int idx = (blockIdx.x * 256 + threadIdx.x) * 4;
    const int co = idx >> 8, ci = idx & 255;
    const int pos = (ci >> 5) * 8192 + (co >> 4) * 512 + ((ci >> 3) & 3) * 128
                  + (co & 15) * 8 + (ci & 7);
    float4 v4 = *(const float4*)(w1 + (size_t)co * 256 + ci);
    uint32_t pa = pack_hilo(v4.x), pb = pack_hilo(v4.y);
    uint32_t pc = pack_hilo(v4.z), pd = pack_hilo(v4.w);
    uint2 uh, ul;
    uh.x = (pa >> 16) | (pb & 0xFFFF0000u);
    uh.y = (pc >> 16) | (pd & 0xFFFF0000u);
    ul.x = (pa & 0xFFFFu) | (pb << 16);
    ul.y = (pc & 0xFFFFu) | (pd << 16);
    *(uint2*)(w1hT + pos) = uh;
    *(uint2*)(w1lT + pos) = ul;
}

// ===========================================================================
// MFMA conv body v10b (R13/R14-proven: 2-term, K=64 phases, 4x8KB LDS, 72
// barriers, A direct global->VGPR, vmcnt(4) queue discipline).
// ===========================================================================
template<bool FULL>
__device__ __forceinline__ void conv_body(
    const short* __restrict__ xh,
    const short* __restrict__ wh, const short* __restrict__ wl,
    const float* __restrict__ bias,
    const float* __restrict__ gam, const float* __restrict__ bet,
    const float* __restrict__ mu,  const float* __restrict__ var,
    float* __restrict__ out,
    int b, int co0, int p0, int H, int W, short* smem)
{
    const int HW = H * W;
    const int Wo = W - 2, P = Wo * Wo;
    const int tid  = threadIdx.x;
    const int wave = tid >> 6, lane = tid & 63;
    const int l15  = lane & 15, quad = lane >> 4;

    int NT = 8;
    if (!FULL) {
        NT = (P - p0 + 15) >> 4;
        if (NT > 8) NT = 8;
    }

    // ---- A-fragment rolling global pointers (direct to VGPR) ----
    const int cob = (co0 >> 4) + wave * 2;
    const short* wA0 = wh + (size_t)cob * 512 + lane * 8;
    const short* wA2 = wl + (size_t)cob * 512 + lane * 8;

    // ---- X staging (R2): coalesced rows + granule XOR ----
    const int lrow = lane >> 2;
    const int lci  = ((lane & 3) ^ ((lane >> 3) & 3)) * 8;
    int pr0 = p0 + wave * 32 + lrow;      if (pr0 >= P) pr0 = 0;
    int pr1 = p0 + wave * 32 + 16 + lrow; if (pr1 >= P) pr1 = 0;
    const size_t bbase0 = ((size_t)b * HW + (pr0 / Wo) * W + (pr0 % Wo)) * 256 + lci;
    const size_t bbase1 = ((size_t)b * HW + (pr1 / Wo) * W + (pr1 % Wo)) * 256 + lci;

    const short* xs0 = xh + bbase0;
    const short* xs1 = xh + bbase1;
    const int rowadv = (W - 2) * 256 - 224;

    const int ldsw = wave * 1024;
    const int fBB = l15 * 32 + ((quad ^ ((l15 >> 1) & 3)) * 8); // XOR-swizzled B

    floatx4 acc[2][8];
    #pragma unroll
    for (int s = 0; s < 2; ++s)
        #pragma unroll
        for (int t = 0; t < 8; ++t) acc[s][t] = (floatx4){0.f, 0.f, 0.f, 0.f};

    // LDS: 4 buffers x 4096 shorts (Xh only) = 32 KB
    int jn = 0;
    auto issueX = [&](int q) {          // one K=32 chunk into buffer q
        short* base = smem + q * 4096;
        dma16(base + ldsw,               xs0);
        dma16(base + ldsw + 512,         xs1);
        ++jn;
        const int adv = (jn % 24 == 0) ? rowadv : 32;
        xs0 += adv; xs1 += adv;
    };

    issueX(0);   // chunk 0
    issueX(1);   // chunk 1

    for (int ph = 0; ph < 36; ++ph) {
        const int c0q = (2 * ph) & 3;   // buffer of first chunk: 0 or 2
        // A(pair ph) issued FIRST: older than X(pair ph+1) in the vmcnt queue.
        short8 a0h = *(const short8*)(wA0);
        short8 a1h = *(const short8*)(wA0 + 512);
        short8 a0l = *(const short8*)(wA2);
        short8 a1l = *(const short8*)(wA2 + 512);
        short8 c0h = *(const short8*)(wA0 + 8192);
        short8 c1h = *(const short8*)(wA0 + 8704);
        short8 c0l = *(const short8*)(wA2 + 8192);
        short8 c1l = *(const short8*)(wA2 + 8704);
        wA0 += 16384; wA2 += 16384;
        asm volatile("s_barrier" ::: "memory");            // pair p-1 compute done
        if (ph < 35) {
            issueX((c0q + 2) & 3);
            issueX((c0q + 3) & 3);
            asm volatile("s_waitcnt vmcnt(4)" ::: "memory"); // pair p + A done
        } else {
            asm volatile("s_waitcnt vmcnt(0)" ::: "memory");
        }
        asm volatile("s_barrier" ::: "memory");            // pair p visible
        const short* bq0 = smem + c0q * 4096;
        const short* bq1 = smem + ((c0q + 1) & 3) * 4096;
        __builtin_amdgcn_s_setprio(1);
        #pragma unroll
        for (int t = 0; t < 8; ++t) {
            if (FULL || t < NT) {
                short8 vh = *(const short8*)(bq0 + t * 512 + fBB);
                acc[0][t] = __builtin_amdgcn_mfma_f32_16x16x32_bf16(a0h, vh, acc[0][t], 0, 0, 0);
                acc[1][t] = __builtin_amdgcn_mfma_f32_16x16x32_bf16(a1h, vh, acc[1][t], 0, 0, 0);
                acc[0][t] = __builtin_amdgcn_mfma_f32_16x16x32_bf16(a0l, vh, acc[0][t], 0, 0, 0);
                acc[1][t] = __builtin_amdgcn_mfma_f32_16x16x32_bf16(a1l, vh, acc[1][t], 0, 0, 0);
            }
        }
        #pragma unroll
        for (int t = 0; t < 8; ++t) {
            if (FULL || t < NT) {
                short8 vh = *(const short8*)(bq1 + t * 512 + fBB);
                acc[0][t] = __builtin_amdgcn_mfma_f32_16x16x32_bf16(c0h, vh, acc[0][t], 0, 0, 0);
                acc[1][t] = __builtin_amdgcn_mfma_f32_16x16x32_bf16(c1h, vh, acc[1][t], 0, 0, 0);
                acc[0][t] = __builtin_amdgcn_mfma_f32_16x16x32_bf16(c0l, vh, acc[0][t], 0, 0, 0);
                acc[1][t] = __builtin_amdgcn_mfma_f32_16x16x32_bf16(c1l, vh, acc[1][t], 0, 0, 0);
            }
        }
        __builtin_amdgcn_s_setprio(0);
    }

    #pragma unroll
    for (int s = 0; s < 2; ++s) {
        const int cobase = co0 + wave * 32 + s * 16 + quad * 4;
        #pragma unroll
        for (int reg = 0; reg < 4; ++reg) {
            const int co = cobase + reg;
            const float A   = gam[co] * rsqrtf(var[co] + 1e-5f);
            const float OFF = fmaf(bias[co] - mu[co], A, bet[co]);
            float* orow = out + ((size_t)(b * 256 + co)) * P;
            #pragma unroll
            for (int t = 0; t < 8; ++t) {
                int px = p0 + t * 16 + l15;
                if ((FULL || t < NT) && px < P)
                    orow[px] = fmaxf(fmaf(acc[s][t][reg], A, OFF), 0.0f);
            }
        }
    }
}

// ---------------------------------------------------------------------------
// conv_mfma_all: search (blocks 0..895, XCD swizzle) + all 3 template scales
// (blocks 896..1279) in ONE dispatch.  32 KB LDS.
// ---------------------------------------------------------------------------
__global__ __launch_bounds__(256) void conv_mfma_all(
    const short* __restrict__ xh_s,
    const short* __restrict__ wh_s, const short* __restrict__ wl_s,
    const float* __restrict__ bs, const float* __restrict__ gs,
    const float* __restrict__ bes, const float* __restrict__ ms,
    const float* __restrict__ vs, float* __restrict__ sq,
    const short* __restrict__ xhL, const short* __restrict__ xhM,
    const short* __restrict__ xhS,
    const short* __restrict__ wh_t, const short* __restrict__ wl_t,
    const float* __restrict__ bt, const float* __restrict__ gt,
    const float* __restrict__ bet, const float* __restrict__ mt,
    const float* __restrict__ vt,
    float* __restrict__ lf, float* __restrict__ mf, float* __restrict__ sf)
{
    __shared__ __align__(16) short smem[16384];   // 4 x 4096-short X buffers
    const int i = blockIdx.x;
    if (i < 896) {
        const int xcd = i & 7, slot = i >> 3;
        const int bl = slot / 14, tile = slot - bl * 14;
        const int b = xcd * 8 + bl;
        const int cohalf = tile & 1, ptile = tile >> 1;
        if (ptile < 6)
            conv_body<true >(xh_s, wh_s, wl_s, bs, gs, bes, ms, vs, sq,
                             b, cohalf * 128, ptile * 128, 31, 31, smem);
        else
            conv_body<false>(xh_s, wh_s, wl_s, bs, gs, bes, ms, vs, sq,
                             b, cohalf * 128, ptile * 128, 31, 31, smem);
    } else {
        const int j = i - 896;                 // 0..383
        const int cohalf = j & 1, sb = j >> 1; // sb 0..191
        const int scale = sb >> 6, b = sb & 63;
        const short* xh = (scale == 0) ? xhL : (scale == 1) ? xhM : xhS;
        float* out      = (scale == 0) ? lf : (scale == 1) ? mf : sf;
        const int H     = (scale == 0) ? 9 : (scale == 1) ? 7 : 5;
        conv_body<false>(xh, wh_t, wl_t, bt, gt, bet, mt, vt, out,
                         b, cohalf * 128, 0, H, H, smem);
    }
}

// ---------------------------------------------------------------------------
// corr v3 (R14-proven: transposed lane map, conflict-free). grid (64,64)
// ---------------------------------------------------------------------------
__global__ __launch_bounds__(256) void corr_kernel(
    const float* __restrict__ lf, const float* __restrict__ mf,
    const float* __restrict__ sf, const float* __restrict__ s,
    float* __restrict__ lc, float* __restrict__ mc, float* __restrict__ sc)
{
    const int b = blockIdx.y;
    const int wave = threadIdx.x >> 6, lane = threadIdx.x & 63;
    const int c = blockIdx.x * 4 + wave;
    const int bc = b * 256 + c;

    __shared__ __align__(16) float sp[4][33 * 36];
    __shared__ float tw[4][96];

    float* P = sp[wave];
    for (int i = lane; i < 33 * 36; i += 64) P[i] = 0.0f;
    if (lane < 49) tw[wave][lane]      = lf[(size_t)bc * 49 + lane];
    if (lane < 25) tw[wave][49 + lane] = mf[(size_t)bc * 25 + lane];
    if (lane < 9)  tw[wave][74 + lane] = sf[(size_t)bc * 9 + lane];
    for (int i = lane; i < 841; i += 64) {
        int y = i / 29, x = i - y * 29;
        P[(y + 2) * 36 + (x + 2)] = s[(size_t)bc * 841 + i];
    }
    __syncthreads();

    const int x = lane & 31;
    const int h = lane >> 5;

    // ---- lc: 7x7 kernel, 27x27 out, no offset ----
    {
        float t7[49];
        #pragma unroll
        for (int k = 0; k < 49; ++k) t7[k] = tw[wave][k];
        for (int pass = 0; pass < 4; ++pass) {
            const int ro = pass * 8 + h * 4;
            float a0 = 0, a1 = 0, a2 = 0, a3 = 0;
            #pragma unroll
            for (int ir = 0; ir < 10; ++ir) {
                int r = ro + ir; if (r > 32) r = 32;
                const float* rp = P + r * 36 + x;
                #pragma unroll
                for (int dx = 0; dx < 7; ++dx) {
                    float v = rp[dx];
                    if (ir <= 6)             a0 = fmaf(t7[ir * 7 + dx], v, a0);
                    if (ir >= 1 && ir <= 7)  a1 = fmaf(t7[(ir - 1) * 7 + dx], v, a1);
                    if (ir >= 2 && ir <= 8)  a2 = fmaf(t7[(ir - 2) * 7 + dx], v, a2);
                    if (ir >= 3)             a3 = fmaf(t7[(ir - 3) * 7 + dx], v, a3);
                }
            }
            if (x < 27) {
                size_t o = (size_t)bc * 729 + (size_t)ro * 27 + x;
                if (ro     < 27) lc[o]      = a0;
                if (ro + 1 < 27) lc[o + 27] = a1;
                if (ro + 2 < 27) lc[o + 54] = a2;
                if (ro + 3 < 27) lc[o + 81] = a3;
            }
        }
    }
    // ---- mc: 5x5 kernel, 25x25 out, +2 offset both dims ----
    {
        float t5[25];
        #pragma unroll
        for (int k = 0; k < 25; ++k) t5[k] = tw[wave][49 + k];
        for (int pass = 0; pass < 4; ++pass) {
            const int ro = pass * 8 + h * 4;
            float a0 = 0, a1 = 0, a2 = 0, a3 = 0;
            #pragma unroll
            for (int ir = 0; ir < 8; ++ir) {
                int r = ro + 2 + ir; if (r > 32) r = 32;
                const float* rp = P + r * 36 + x + 2;
                #pragma unroll
                for (int dx = 0; dx < 5; ++dx) {
                    float v = rp[dx];
                    if (ir <= 4)             a0 = fmaf(t5[ir * 5 + dx], v, a0);
                    if (ir >= 1 && ir <= 5)  a1 = fmaf(t5[(ir - 1) * 5 + dx], v, a1);
                    if (ir >= 2 && ir <= 6)  a2 = fmaf(t5[(ir - 2) * 5 + dx], v, a2);
                    if (ir >= 3)             a3 = fmaf(t5[(ir - 3) * 5 + dx], v, a3);
                }
            }
            if (x < 25) {
                size_t o = (size_t)bc * 625 + (size_t)ro * 25 + x;
                if (ro     < 25) mc[o]      = a0;
                if (ro + 1 < 25) mc[o + 25] = a1;
                if (ro + 2 < 25) mc[o + 50] = a2;
                if (ro + 3 < 25) mc[o + 75] = a3;
            }
        }
    }
    // ---- sc: 3x3 kernel, 27x27 out, +2 offset both dims ----
    {
        float t3[9];
        #pragma unroll
        for (int k = 0; k < 9; ++k) t3[k] = tw[wave][74 + k];
        for (int pass = 0; pass < 4; ++pass) {
            const int ro = pass * 8 + h * 4;
            float a0 = 0, a1 = 0, a2 = 0, a3 = 0;
            #pragma unroll
            for (int ir = 0; ir < 6; ++ir) {
                int r = ro + 2 + ir; if (r > 32) r = 32;
                const float* rp = P + r * 36 + x + 2;
                #pragma unroll
                for (int dx = 0; dx < 3; ++dx) {
                    float v = rp[dx];
                    if (ir <= 2)             a0 = fmaf(t3[ir * 3 + dx], v, a0);
                    if (ir >= 1 && ir <= 3)  a1 = fmaf(t3[(ir - 1) * 3 + dx], v, a1);
                    if (ir >= 2 && ir <= 4)  a2 = fmaf(t3[(ir - 2) * 3 + dx], v, a2);
                    if (ir >= 3)             a3 = fmaf(t3[(ir - 3) * 3 + dx], v, a3);
                }
            }
            if (x < 27) {
                size_t o = (size_t)bc * 729 + (size_t)ro * 27 + x;
                if (ro     < 27) sc[o]      = a0;
                if (ro + 1 < 27) sc[o + 27] = a1;
                if (ro + 2 < 27) sc[o + 54] = a2;
                if (ro + 3 < 27) sc[o + 81] = a3;
            }
        }
    }
}

// ---------------------------------------------------------------------------
// head v6 (R14 post-mortem: head latency/sync-bound at 2 blocks/CU, 60 KB
// LDS).  p-split 128 -> 64 per block: LDS ~46 KB (Ah 16K + Al 16K +
// Bh 64x42 + red 64x33) -> 3 blocks/CU if VGPR fits; 2176 blocks for queue
// depth.  acc[2][4] (32 VGPR, was 64).  B map: cp = tid>>5 (16 ch-pairs),
// pxq = tid&31, 2 p/thread -> 256 B contiguous per row, ~2-way LDS writes.
// grid (34, 64): bx 0..11 lc, 12..21 mc, 22..33 sc.
// ---------------------------------------------------------------------------
__global__ __launch_bounds__(512, 4) void head_mfma_kernel(
    const float* __restrict__ lc, const float* __restrict__ mc,
    const float* __restrict__ sc,
    const short* __restrict__ w1hT, const short* __restrict__ w1lT,
    const float* __restrict__ b1,
    const float* __restrict__ g1, const float* __restrict__ be1,
    const float* __restrict__ m1, const float* __restrict__ v1,
    const float* __restrict__ w2, const float* __restrict__ b2,
    float* __restrict__ out)
{
    const int bx = blockIdx.x;
    const float* X; int Np, ooff, p0;
    if (bx < 12)      { X = lc; Np = 729; ooff = 0;     p0 = bx * 64; }
    else if (bx < 22) { X = mc; Np = 625; ooff = 46656; p0 = (bx - 12) * 64; }
    else              { X = sc; Np = 729; ooff = 86656; p0 = (bx - 22) * 64; }

    const int b  = blockIdx.y;
    const int tid = threadIdx.x;
    const int wave = tid >> 6, lane = tid & 63;   // wave 0..7
    const int l15 = lane & 15, quad = lane >> 4;

    __shared__ __align__(16) short Ah[256 * 32], Al[256 * 32];
    __shared__ __align__(16) short Bh[64 * 42];
    __shared__ float red[64 * 33];

    floatx4 acc[2][4];
    #pragma unroll
    for (int m = 0; m < 2; ++m)
        #pragma unroll
        for (int n = 0; n < 4; ++n) acc[m][n] = (floatx4){0.f, 0.f, 0.f, 0.f};

    const int pxq = tid & 31;      // p-pair: p = pxq*2 + j  (0..63)
    const int cp  = tid >> 5;      // 0..15: channels (2cp, 2cp+1) of 32-chunk

    for (int k0 = 0; k0 < 256; k0 += 32) {
        {
            const int kc = k0 >> 5;
            const short* srcH = w1hT + kc * 8192 + wave * 1024 + lane * 8;
            const short* srcL = w1lT + kc * 8192 + wave * 1024 + lane * 8;
            dma16(Ah + wave * 1024,       srcH);
            dma16(Ah + wave * 1024 + 512, srcH + 512);
            dma16(Al + wave * 1024,       srcL);
            dma16(Al + wave * 1024 + 512, srcL + 512);
        }
        {
            const int pxl = pxq * 2;
            const int gp = p0 + pxl;
            const float* r0 = X + ((size_t)(b * 256) + k0 + 2 * cp) * Np + gp;
            const float* r1 = r0 + Np;
            #pragma unroll
            for (int j = 0; j < 2; ++j) {
                float u = (gp + j < Np) ? r0[j] : 0.0f;
                float v = (gp + j < Np) ? r1[j] : 0.0f;
                int o = (pxl + j) * 42 + 2 * cp;
                *(uint32_t*)(Bh + o) = bf16rne(u) | (bf16rne(v) << 16);
            }
        }
        __syncthreads();
        short8 amh[2], aml[2];
        #pragma unroll
        for (int m = 0; m < 2; ++m) {
            int ao = (wave * 2 + m) * 512 + lane * 8;   // lane-linear
            amh[m] = *(const short8*)(Ah + ao);
            aml[m] = *(const short8*)(Al + ao);
        }
        __builtin_amdgcn_s_setprio(1);
        #pragma unroll
        for (int n = 0; n < 4; ++n) {
            int bo = (n * 16 + l15) * 42 + quad * 8;
            short8 bh = *(const short8*)(Bh + bo);
            #pragma unroll
            for (int m = 0; m < 2; ++m) {
                acc[m][n] = __builtin_amdgcn_mfma_f32_16x16x32_bf16(amh[m], bh, acc[m][n], 0, 0, 0);
                acc[m][n] = __builtin_amdgcn_mfma_f32_16x16x32_bf16(aml[m], bh, acc[m][n], 0, 0, 0);
            }
        }
        __builtin_amdgcn_s_setprio(0);
        __syncthreads();
    }

    float Ac[8], Oc[8], Wc[8];
    #pragma unroll
    for (int m = 0; m < 2; ++m)
        #pragma unroll
        for (int reg = 0; reg < 4; ++reg) {
            int co = wave * 32 + m * 16 + quad * 4 + reg;
            float A = g1[co] * rsqrtf(v1[co] + 1e-5f);
            Ac[m * 4 + reg] = A;
            Oc[m * 4 + reg] = fmaf(b1[co] - m1[co], A, be1[co]);
            Wc[m * 4 + reg] = w2[co];
        }
    #pragma unroll
    for (int n = 0; n < 4; ++n) {
        float part = 0.0f;
        #pragma unroll
        for (int m = 0; m < 2; ++m)
            #pragma unroll
            for (int reg = 0; reg < 4; ++reg) {
                float y = fmaxf(fmaf(acc[m][n][reg], Ac[m * 4 + reg], Oc[m * 4 + reg]), 0.0f);
                part = fmaf(Wc[m * 4 + reg], y, part);
            }
        red[(n * 16 + l15) * 33 + wave * 4 + quad] = part;
    }
    __syncthreads();
    if (tid < 64) {
        float z = b2[0];
        #pragma unroll
        for (int k = 0; k < 32; ++k) z += red[tid * 33 + k];
        if (p0 + tid < Np)
            out[ooff + (size_t)b * Np + p0 + tid] = 1.0f / (1.0f + expf(-z));
    }
}

// ---------------------------------------------------------------------------
extern "C" void kernel_launch(void* const* d_in, const int* in_sizes, int n_in,
                              void* d_out, int out_size, void* d_ws, size_t ws_size,
                              hipStream_t stream)
{
    const float* large  = (const float*)d_in[0];
    const float* medium = (const float*)d_in[1];
    const float* small  = (const float*)d_in[2];
    const float* search = (const float*)d_in[3];
    const float* wt  = (const float*)d_in[4];
    const float* bt  = (const float*)d_in[5];
    const float* gt  = (const float*)d_in[6];
    const float* bet = (const float*)d_in[7];
    const float* mt  = (const float*)d_in[8];
    const float* vt  = (const float*)d_in[9];
    const float* wsc = (const float*)d_in[10];
    const float* bs  = (const float*)d_in[11];
    const float* gs  = (const float*)d_in[12];
    const float* bes = (const float*)d_in[13];
    const float* ms  = (const float*)d_in[14];
    const float* vs  = (const float*)d_in[15];
    const float* w1  = (const float*)d_in[16];
    const float* b1  = (const float*)d_in[17];
    const float* g1  = (const float*)d_in[18];
    const float* be1 = (const float*)d_in[19];
    const float* m1  = (const float*)d_in[20];
    const float* v1  = (const float*)d_in[21];
    const float* w2  = (const float*)d_in[22];
    const float* b2  = (const float*)d_in[23];

    float* ws = (float*)d_ws;
    size_t off = 0;
    float* lf = ws + off; off += (size_t)64 * 256 * 49;
    float* mf = ws + off; off += (size_t)64 * 256 * 25;
    float* sf = ws + off; off += (size_t)64 * 256 * 9;
    float* sq = ws + off; off += (size_t)64 * 256 * 841;
    float* lc = ws + off; off += (size_t)64 * 256 * 729;
    float* mc = ws + off; off += (size_t)64 * 256 * 625;
    float* sc = ws + off; off += (size_t)64 * 256 * 729;

    // Aliased prep buffers (dead before corr writes lc/mc/sc):
    short* xh_s = (short*)lc;
    short* base = (short*)sc;
    short* xh_L = base;
    short* xh_M = base + 2654208;
    short* xh_S = base + 4259840;
    short* wh_t = base + 5079040;
    short* wl_t = base + 5668864;
    short* wh_s = base + 6258688;
    short* wl_s = base + 6848512;
    // w1 packed buffers live in sq (dead after corr; written after corr):
    short* w1hT = (short*)sq;
    short* w1lT = (short*)sq + 65536;

    dim3 blk(256);
    prep_all<<<dim3(5376), blk, 0, stream>>>(
        wt, wh_t, wl_t, wsc, wh_s, wl_s,
        search, xh_s, large, xh_L,
        medium, xh_M, small, xh_S);

    conv_mfma_all<<<dim3(1280), blk, 0, stream>>>(
        xh_s, wh_s, wl_s, bs, gs, bes, ms, vs, sq,
        xh_L, xh_M, xh_S, wh_t, wl_t,
        bt, gt, bet, mt, vt, lf, mf, sf);

    corr_kernel<<<dim3(64, 64), blk, 0, stream>>>(lf, mf, sf, sq, lc, mc, sc);

    // pack w1 into (now dead) sq region, then fused merged heads
    prep_w1<<<dim3(64), blk, 0, stream>>>(w1, w1hT, w1lT);

    head_mfma_kernel<<<dim3(34, 64), dim3(512), 0, stream>>>(
        lc, mc, sc, w1hT, w1lT, b1, g1, be1, m1, v1, w2, b2, (float*)d_out);
}

// Round 16
// 462.832 us; speedup vs baseline: 1.0083x; 1.0083x over previous
//
#include <hip/hip_runtime.h>
#include <math.h>
#include <stdint.h>

typedef __attribute__((ext_vector_type(8))) short short8;
typedef __attribute__((ext_vector_type(4))) float floatx4;

// fp32 -> (bf16 hi | bf16 lo) packed u32.  hi = RNE(x), lo = RNE(x - hi).
__device__ __forceinline__ uint32_t pack_hilo(float x) {
    uint32_t u = __float_as_uint(x);
    uint32_t hi = (u + 0x7FFFu + ((u >> 16) & 1u)) & 0xFFFF0000u;
    float r = x - __uint_as_float(hi);
    uint32_t v = __float_as_uint(r);
    uint32_t lo = ((v + 0x7FFFu + ((v >> 16) & 1u)) >> 16) & 0xFFFFu;
    return hi | lo;
}

// fp32 -> bf16 (RNE), low 16 bits of result.
__device__ __forceinline__ uint32_t bf16rne(float x) {
    uint32_t u = __float_as_uint(x);
    return ((u + 0x7FFFu + ((u >> 16) & 1u)) >> 16) & 0xFFFFu;
}

// async global->LDS DMA, 16 B per lane; lds dest must be wave-uniform base.
__device__ __forceinline__ void dma16(short* lds, const short* g) {
    __builtin_amdgcn_global_load_lds(
        (const __attribute__((address_space(1))) unsigned int*)g,
        (__attribute__((address_space(3))) unsigned int*)lds,
        16, 0, 0);
}

// ---------------------------------------------------------------------------
// Merged prep: conv weights (blocks 0..255) + all activations (256..5375).
// Activations store bf16-hi ONLY (2-term scheme).
// ---------------------------------------------------------------------------
__global__ __launch_bounds__(256) void prep_all(
    const float* __restrict__ wA, short* __restrict__ whA, short* __restrict__ wlA,
    const float* __restrict__ wB, short* __restrict__ whB, short* __restrict__ wlB,
    const float* __restrict__ xs, short* __restrict__ xhS,
    const float* __restrict__ xL, short* __restrict__ xhL,
    const float* __restrict__ xM, short* __restrict__ xhM,
    const float* __restrict__ xSm, short* __restrict__ xhSm)
{
    const int blk = blockIdx.x;
    if (blk < 256) {
        // ---- weight prep: fetch-order layout.  Lane-linear A-fragments:
        // frag(tile, cob, lane) at ((tile)*16 + cob)*512 + lane*8  ----
        int bx = blk;
        const float* w; short *wh, *wl;
        if (bx < 128) { w = wA; wh = whA; wl = wlA; }
        else          { w = wB; wh = whB; wl = wlB; bx -= 128; }
        const int idx = bx * 256 + threadIdx.x;
        const int co = idx >> 7, jp = idx & 127;      // ci = 2*jp
        const int c4 = jp >> 4;                       // ci>>5
        const int g  = (jp >> 2) & 3;                 // (ci>>3)&3
        const int cw = 2 * (jp & 3);                  // ci&7
        const float* s0 = w + ((size_t)co * 256 + 2 * jp) * 9;
        #pragma unroll
        for (int r = 0; r < 9; ++r) {
            uint32_t q0 = pack_hilo(s0[r]);
            uint32_t q1 = pack_hilo(s0[9 + r]);
            size_t o = ((size_t)(r * 8 + c4) * 16 + (co >> 4)) * 512
                     + (size_t)(g * 16 + (co & 15)) * 8 + cw;
            *(uint32_t*)(wh + o) = (q0 >> 16) | (q1 & 0xFFFF0000u);
            *(uint32_t*)(wl + o) = (q0 & 0xFFFFu) | (q1 << 16);
        }
        return;
    }
    // ---- activation prep (bf16 hi only) ----
    const int i = blk - 256;            // 0..5119
    const int bx = i % 20;
    const int by = (i / 20) & 3;
    const int b  = i / 80;

    const float* x; short *xh; int HW, p0;
    if (bx < 16)      { x = xs;  xh = xhS;  HW = 961; p0 = bx * 64; }
    else if (bx < 18) { x = xL;  xh = xhL;  HW = 81;  p0 = (bx - 16) * 64; }
    else if (bx < 19) { x = xM;  xh = xhM;  HW = 49;  p0 = 0; }
    else              { x = xSm; xh = xhSm; HW = 25;  p0 = 0; }

    const int c0 = by * 64;
    const int tid = threadIdx.x;
    const int a = tid & 63, g = tid >> 6;
    __shared__ uint32_t t[64][65];
    #pragma unroll
    for (int ii = 0; ii < 16; ++ii) {
        int c = g + ii * 4;
        int p = p0 + a;
        float v = (p < HW) ? x[((size_t)(b * 256) + c0 + c) * HW + p] : 0.0f;
        t[c][a] = pack_hilo(v);
    }
    __syncthreads();
    const int j = tid & 31;
    const int gg = tid >> 5;
    #pragma unroll
    for (int ii = 0; ii < 8; ++ii) {
        int p = gg + ii * 8;
        if (p0 + p < HW) {
            uint32_t w0 = t[2 * j][p], w1 = t[2 * j + 1][p];
            size_t o = ((size_t)b * HW + p0 + p) * 256 + c0 + 2 * j;
            *(uint32_t*)(xh + o) = (w0 >> 16) | (w1 & 0xFFFF0000u);
        }
    }
}

// ---------------------------------------------------------------------------
// Prep w1 (256,256) fp32 -> granule-swizzled chunk-major hi/lo (lane-linear
// A-fragment reads in head).  grid (64).  Runs after corr (lives in dead sq).
// ---------------------------------------------------------------------------
__global__ __launch_bounds__(256) void prep_w1(
    const float* __restrict__ w1, short* __restrict__ w1hT, short* __restrict__ w1lT)
{
    const int idx = (blockIdx.x * 256 + threadIdx.x) * 4;
    const int co = idx >> 8, ci = idx & 255;
    const int pos = (ci >> 5) * 8192 + (co >> 4) * 512 + ((ci >> 3) & 3) * 128
                  + (co & 15) * 8 + (ci & 7);
    float4 v4 = *(const float4*)(w1 + (size_t)co * 256 + ci);
    uint32_t pa = pack_hilo(v4.x), pb = pack_hilo(v4.y);
    uint32_t pc = pack_hilo(v4.z), pd = pack_hilo(v4.w);
    uint2 uh, ul;
    uh.x = (pa >> 16) | (pb & 0xFFFF0000u);
    uh.y = (pc >> 16) | (pd & 0xFFFF0000u);
    ul.x = (pa & 0xFFFFu) | (pb << 16);
    ul.y = (pc & 0xFFFFu) | (pd << 16);
    *(uint2*)(w1hT + pos) = uh;
    *(uint2*)(w1lT + pos) = ul;
}

// ===========================================================================
// MFMA conv body v10b (R13/R14-proven: 2-term, K=64 phases, 4x8KB LDS, 72
// barriers, A direct global->VGPR, vmcnt(4) queue discipline).
// ===========================================================================
template<bool FULL>
__device__ __forceinline__ void conv_body(
    const short* __restrict__ xh,
    const short* __restrict__ wh, const short* __restrict__ wl,
    const float* __restrict__ bias,
    const float* __restrict__ gam, const float* __restrict__ bet,
    const float* __restrict__ mu,  const float* __restrict__ var,
    float* __restrict__ out,
    int b, int co0, int p0, int H, int W, short* smem)
{
    const int HW = H * W;
    const int Wo = W - 2, P = Wo * Wo;
    const int tid  = threadIdx.x;
    const int wave = tid >> 6, lane = tid & 63;
    const int l15  = lane & 15, quad = lane >> 4;

    int NT = 8;
    if (!FULL) {
        NT = (P - p0 + 15) >> 4;
        if (NT > 8) NT = 8;
    }

    // ---- A-fragment rolling global pointers (direct to VGPR) ----
    const int cob = (co0 >> 4) + wave * 2;
    const short* wA0 = wh + (size_t)cob * 512 + lane * 8;
    const short* wA2 = wl + (size_t)cob * 512 + lane * 8;

    // ---- X staging (R2): coalesced rows + granule XOR ----
    const int lrow = lane >> 2;
    const int lci  = ((lane & 3) ^ ((lane >> 3) & 3)) * 8;
    int pr0 = p0 + wave * 32 + lrow;      if (pr0 >= P) pr0 = 0;
    int pr1 = p0 + wave * 32 + 16 + lrow; if (pr1 >= P) pr1 = 0;
    const size_t bbase0 = ((size_t)b * HW + (pr0 / Wo) * W + (pr0 % Wo)) * 256 + lci;
    const size_t bbase1 = ((size_t)b * HW + (pr1 / Wo) * W + (pr1 % Wo)) * 256 + lci;

    const short* xs0 = xh + bbase0;
    const short* xs1 = xh + bbase1;
    const int rowadv = (W - 2) * 256 - 224;

    const int ldsw = wave * 1024;
    const int fBB = l15 * 32 + ((quad ^ ((l15 >> 1) & 3)) * 8); // XOR-swizzled B

    floatx4 acc[2][8];
    #pragma unroll
    for (int s = 0; s < 2; ++s)
        #pragma unroll
        for (int t = 0; t < 8; ++t) acc[s][t] = (floatx4){0.f, 0.f, 0.f, 0.f};

    // LDS: 4 buffers x 4096 shorts (Xh only) = 32 KB
    int jn = 0;
    auto issueX = [&](int q) {          // one K=32 chunk into buffer q
        short* base = smem + q * 4096;
        dma16(base + ldsw,               xs0);
        dma16(base + ldsw + 512,         xs1);
        ++jn;
        const int adv = (jn % 24 == 0) ? rowadv : 32;
        xs0 += adv; xs1 += adv;
    };

    issueX(0);   // chunk 0
    issueX(1);   // chunk 1

    for (int ph = 0; ph < 36; ++ph) {
        const int c0q = (2 * ph) & 3;   // buffer of first chunk: 0 or 2
        // A(pair ph) issued FIRST: older than X(pair ph+1) in the vmcnt queue.
        short8 a0h = *(const short8*)(wA0);
        short8 a1h = *(const short8*)(wA0 + 512);
        short8 a0l = *(const short8*)(wA2);
        short8 a1l = *(const short8*)(wA2 + 512);
        short8 c0h = *(const short8*)(wA0 + 8192);
        short8 c1h = *(const short8*)(wA0 + 8704);
        short8 c0l = *(const short8*)(wA2 + 8192);
        short8 c1l = *(const short8*)(wA2 + 8704);
        wA0 += 16384; wA2 += 16384;
        asm volatile("s_barrier" ::: "memory");            // pair p-1 compute done
        if (ph < 35) {
            issueX((c0q + 2) & 3);
            issueX((c0q + 3) & 3);
            asm volatile("s_waitcnt vmcnt(4)" ::: "memory"); // pair p + A done
        } else {
            asm volatile("s_waitcnt vmcnt(0)" ::: "memory");
        }
        asm volatile("s_barrier" ::: "memory");            // pair p visible
        const short* bq0 = smem + c0q * 4096;
        const short* bq1 = smem + ((c0q + 1) & 3) * 4096;
        __builtin_amdgcn_s_setprio(1);
        #pragma unroll
        for (int t = 0; t < 8; ++t) {
            if (FULL || t < NT) {
                short8 vh = *(const short8*)(bq0 + t * 512 + fBB);
                acc[0][t] = __builtin_amdgcn_mfma_f32_16x16x32_bf16(a0h, vh, acc[0][t], 0, 0, 0);
                acc[1][t] = __builtin_amdgcn_mfma_f32_16x16x32_bf16(a1h, vh, acc[1][t], 0, 0, 0);
                acc[0][t] = __builtin_amdgcn_mfma_f32_16x16x32_bf16(a0l, vh, acc[0][t], 0, 0, 0);
                acc[1][t] = __builtin_amdgcn_mfma_f32_16x16x32_bf16(a1l, vh, acc[1][t], 0, 0, 0);
            }
        }
        #pragma unroll
        for (int t = 0; t < 8; ++t) {
            if (FULL || t < NT) {
                short8 vh = *(const short8*)(bq1 + t * 512 + fBB);
                acc[0][t] = __builtin_amdgcn_mfma_f32_16x16x32_bf16(c0h, vh, acc[0][t], 0, 0, 0);
                acc[1][t] = __builtin_amdgcn_mfma_f32_16x16x32_bf16(c1h, vh, acc[1][t], 0, 0, 0);
                acc[0][t] = __builtin_amdgcn_mfma_f32_16x16x32_bf16(c0l, vh, acc[0][t], 0, 0, 0);
                acc[1][t] = __builtin_amdgcn_mfma_f32_16x16x32_bf16(c1l, vh, acc[1][t], 0, 0, 0);
            }
        }
        __builtin_amdgcn_s_setprio(0);
    }

    #pragma unroll
    for (int s = 0; s < 2; ++s) {
        const int cobase = co0 + wave * 32 + s * 16 + quad * 4;
        #pragma unroll
        for (int reg = 0; reg < 4; ++reg) {
            const int co = cobase + reg;
            const float A   = gam[co] * rsqrtf(var[co] + 1e-5f);
            const float OFF = fmaf(bias[co] - mu[co], A, bet[co]);
            float* orow = out + ((size_t)(b * 256 + co)) * P;
            #pragma unroll
            for (int t = 0; t < 8; ++t) {
                int px = p0 + t * 16 + l15;
                if ((FULL || t < NT) && px < P)
                    orow[px] = fmaxf(fmaf(acc[s][t][reg], A, OFF), 0.0f);
            }
        }
    }
}

// ---------------------------------------------------------------------------
// conv_mfma_all: search (blocks 0..895, XCD swizzle) + all 3 template scales
// (blocks 896..1279) in ONE dispatch.  32 KB LDS.
// ---------------------------------------------------------------------------
__global__ __launch_bounds__(256) void conv_mfma_all(
    const short* __restrict__ xh_s,
    const short* __restrict__ wh_s, const short* __restrict__ wl_s,
    const float* __restrict__ bs, const float* __restrict__ gs,
    const float* __restrict__ bes, const float* __restrict__ ms,
    const float* __restrict__ vs, float* __restrict__ sq,
    const short* __restrict__ xhL, const short* __restrict__ xhM,
    const short* __restrict__ xhS,
    const short* __restrict__ wh_t, const short* __restrict__ wl_t,
    const float* __restrict__ bt, const float* __restrict__ gt,
    const float* __restrict__ bet, const float* __restrict__ mt,
    const float* __restrict__ vt,
    float* __restrict__ lf, float* __restrict__ mf, float* __restrict__ sf)
{
    __shared__ __align__(16) short smem[16384];   // 4 x 4096-short X buffers
    const int i = blockIdx.x;
    if (i < 896) {
        const int xcd = i & 7, slot = i >> 3;
        const int bl = slot / 14, tile = slot - bl * 14;
        const int b = xcd * 8 + bl;
        const int cohalf = tile & 1, ptile = tile >> 1;
        if (ptile < 6)
            conv_body<true >(xh_s, wh_s, wl_s, bs, gs, bes, ms, vs, sq,
                             b, cohalf * 128, ptile * 128, 31, 31, smem);
        else
            conv_body<false>(xh_s, wh_s, wl_s, bs, gs, bes, ms, vs, sq,
                             b, cohalf * 128, ptile * 128, 31, 31, smem);
    } else {
        const int j = i - 896;                 // 0..383
        const int cohalf = j & 1, sb = j >> 1; // sb 0..191
        const int scale = sb >> 6, b = sb & 63;
        const short* xh = (scale == 0) ? xhL : (scale == 1) ? xhM : xhS;
        float* out      = (scale == 0) ? lf : (scale == 1) ? mf : sf;
        const int H     = (scale == 0) ? 9 : (scale == 1) ? 7 : 5;
        conv_body<false>(xh, wh_t, wl_t, bt, gt, bet, mt, vt, out,
                         b, cohalf * 128, 0, H, H, smem);
    }
}

// ---------------------------------------------------------------------------
// corr v3 (R14-proven: transposed lane map, conflict-free). grid (64,64)
// ---------------------------------------------------------------------------
__global__ __launch_bounds__(256) void corr_kernel(
    const float* __restrict__ lf, const float* __restrict__ mf,
    const float* __restrict__ sf, const float* __restrict__ s,
    float* __restrict__ lc, float* __restrict__ mc, float* __restrict__ sc)
{
    const int b = blockIdx.y;
    const int wave = threadIdx.x >> 6, lane = threadIdx.x & 63;
    const int c = blockIdx.x * 4 + wave;
    const int bc = b * 256 + c;

    __shared__ __align__(16) float sp[4][33 * 36];
    __shared__ float tw[4][96];

    float* P = sp[wave];
    for (int i = lane; i < 33 * 36; i += 64) P[i] = 0.0f;
    if (lane < 49) tw[wave][lane]      = lf[(size_t)bc * 49 + lane];
    if (lane < 25) tw[wave][49 + lane] = mf[(size_t)bc * 25 + lane];
    if (lane < 9)  tw[wave][74 + lane] = sf[(size_t)bc * 9 + lane];
    for (int i = lane; i < 841; i += 64) {
        int y = i / 29, x = i - y * 29;
        P[(y + 2) * 36 + (x + 2)] = s[(size_t)bc * 841 + i];
    }
    __syncthreads();

    const int x = lane & 31;
    const int h = lane >> 5;

    // ---- lc: 7x7 kernel, 27x27 out, no offset ----
    {
        float t7[49];
        #pragma unroll
        for (int k = 0; k < 49; ++k) t7[k] = tw[wave][k];
        for (int pass = 0; pass < 4; ++pass) {
            const int ro = pass * 8 + h * 4;
            float a0 = 0, a1 = 0, a2 = 0, a3 = 0;
            #pragma unroll
            for (int ir = 0; ir < 10; ++ir) {
                int r = ro + ir; if (r > 32) r = 32;
                const float* rp = P + r * 36 + x;
                #pragma unroll
                for (int dx = 0; dx < 7; ++dx) {
                    float v = rp[dx];
                    if (ir <= 6)             a0 = fmaf(t7[ir * 7 + dx], v, a0);
                    if (ir >= 1 && ir <= 7)  a1 = fmaf(t7[(ir - 1) * 7 + dx], v, a1);
                    if (ir >= 2 && ir <= 8)  a2 = fmaf(t7[(ir - 2) * 7 + dx], v, a2);
                    if (ir >= 3)             a3 = fmaf(t7[(ir - 3) * 7 + dx], v, a3);
                }
            }
            if (x < 27) {
                size_t o = (size_t)bc * 729 + (size_t)ro * 27 + x;
                if (ro     < 27) lc[o]      = a0;
                if (ro + 1 < 27) lc[o + 27] = a1;
                if (ro + 2 < 27) lc[o + 54] = a2;
                if (ro + 3 < 27) lc[o + 81] = a3;
            }
        }
    }
    // ---- mc: 5x5 kernel, 25x25 out, +2 offset both dims ----
    {
        float t5[25];
        #pragma unroll
        for (int k = 0; k < 25; ++k) t5[k] = tw[wave][49 + k];
        for (int pass = 0; pass < 4; ++pass) {
            const int ro = pass * 8 + h * 4;
            float a0 = 0, a1 = 0, a2 = 0, a3 = 0;
            #pragma unroll
            for (int ir = 0; ir < 8; ++ir) {
                int r = ro + 2 + ir; if (r > 32) r = 32;
                const float* rp = P + r * 36 + x + 2;
                #pragma unroll
                for (int dx = 0; dx < 5; ++dx) {
                    float v = rp[dx];
                    if (ir <= 4)             a0 = fmaf(t5[ir * 5 + dx], v, a0);
                    if (ir >= 1 && ir <= 5)  a1 = fmaf(t5[(ir - 1) * 5 + dx], v, a1);
                    if (ir >= 2 && ir <= 6)  a2 = fmaf(t5[(ir - 2) * 5 + dx], v, a2);
                    if (ir >= 3)             a3 = fmaf(t5[(ir - 3) * 5 + dx], v, a3);
                }
            }
            if (x < 25) {
                size_t o = (size_t)bc * 625 + (size_t)ro * 25 + x;
                if (ro     < 25) mc[o]      = a0;
                if (ro + 1 < 25) mc[o + 25] = a1;
                if (ro + 2 < 25) mc[o + 50] = a2;
                if (ro + 3 < 25) mc[o + 75] = a3;
            }
        }
    }
    // ---- sc: 3x3 kernel, 27x27 out, +2 offset both dims ----
    {
        float t3[9];
        #pragma unroll
        for (int k = 0; k < 9; ++k) t3[k] = tw[wave][74 + k];
        for (int pass = 0; pass < 4; ++pass) {
            const int ro = pass * 8 + h * 4;
            float a0 = 0, a1 = 0, a2 = 0, a3 = 0;
            #pragma unroll
            for (int ir = 0; ir < 6; ++ir) {
                int r = ro + 2 + ir; if (r > 32) r = 32;
                const float* rp = P + r * 36 + x + 2;
                #pragma unroll
                for (int dx = 0; dx < 3; ++dx) {
                    float v = rp[dx];
                    if (ir <= 2)             a0 = fmaf(t3[ir * 3 + dx], v, a0);
                    if (ir >= 1 && ir <= 3)  a1 = fmaf(t3[(ir - 1) * 3 + dx], v, a1);
                    if (ir >= 2 && ir <= 4)  a2 = fmaf(t3[(ir - 2) * 3 + dx], v, a2);
                    if (ir >= 3)             a3 = fmaf(t3[(ir - 3) * 3 + dx], v, a3);
                }
            }
            if (x < 27) {
                size_t o = (size_t)bc * 729 + (size_t)ro * 27 + x;
                if (ro     < 27) sc[o]      = a0;
                if (ro + 1 < 27) sc[o + 27] = a1;
                if (ro + 2 < 27) sc[o + 54] = a2;
                if (ro + 3 < 27) sc[o + 81] = a3;
            }
        }
    }
}

// ---------------------------------------------------------------------------
// head v7: R14's v5 (128p, grid 17, 2-term, 8 waves x 32co) with A-fragments
// loaded DIRECTLY global->VGPR (w1hT layout is lane-linear by construction;
// W1 is 256 KB L2-resident, shared by all 1088 blocks).  Removes Ah/Al LDS
// (63 -> ~28 KB), 8 dma16/iter, and the A-drain before the barrier; A-loads
// issue at the top of each k0 and complete under B staging.
// grid (17, 64).
// ---------------------------------------------------------------------------
__global__ __launch_bounds__(512, 4) void head_mfma_kernel(
    const float* __restrict__ lc, const float* __restrict__ mc,
    const float* __restrict__ sc,
    const short* __restrict__ w1hT, const short* __restrict__ w1lT,
    const float* __restrict__ b1,
    const float* __restrict__ g1, const float* __restrict__ be1,
    const float* __restrict__ m1, const float* __restrict__ v1,
    const float* __restrict__ w2, const float* __restrict__ b2,
    float* __restrict__ out)
{
    const int bx = blockIdx.x;
    const float* X; int Np, ooff, p0;
    if (bx < 6)       { X = lc; Np = 729; ooff = 0;     p0 = bx * 128; }
    else if (bx < 11) { X = mc; Np = 625; ooff = 46656; p0 = (bx - 6) * 128; }
    else              { X = sc; Np = 729; ooff = 86656; p0 = (bx - 11) * 128; }

    const int b  = blockIdx.y;
    const int tid = threadIdx.x;
    const int wave = tid >> 6, lane = tid & 63;   // wave 0..7
    const int l15 = lane & 15, quad = lane >> 4;

    __shared__ __align__(16) short Bh[128 * 42];
    __shared__ float red[128 * 33];

    floatx4 acc[2][8];
    #pragma unroll
    for (int m = 0; m < 2; ++m)
        #pragma unroll
        for (int n = 0; n < 8; ++n) acc[m][n] = (floatx4){0.f, 0.f, 0.f, 0.f};

    const int pxq = tid & 31;      // p-quad: p = pxq*4 + j  (0..127)
    const int cp  = tid >> 5;      // 0..15: channels (2cp, 2cp+1) of 32-chunk

    // A-fragment rolling global pointers (lane-linear w1hT/w1lT layout)
    const short* pAh = w1hT + (size_t)(wave * 2) * 512 + lane * 8;
    const short* pAl = w1lT + (size_t)(wave * 2) * 512 + lane * 8;

    for (int k0 = 0; k0 < 256; k0 += 32) {
        // A(k0) issued FIRST: completes under the B staging phase below.
        short8 amh[2], aml[2];
        #pragma unroll
        for (int m = 0; m < 2; ++m) {
            amh[m] = *(const short8*)(pAh + m * 512);
            aml[m] = *(const short8*)(pAl + m * 512);
        }
        pAh += 8192; pAl += 8192;
        {
            const int pxl = pxq * 4;
            const int gp = p0 + pxl;
            const float* r0 = X + ((size_t)(b * 256) + k0 + 2 * cp) * Np + gp;
            const float* r1 = r0 + Np;
            #pragma unroll
            for (int j = 0; j < 4; ++j) {
                float u = (gp + j < Np) ? r0[j] : 0.0f;
                float v = (gp + j < Np) ? r1[j] : 0.0f;
                int o = (pxl + j) * 42 + 2 * cp;
                *(uint32_t*)(Bh + o) = bf16rne(u) | (bf16rne(v) << 16);
            }
        }
        __syncthreads();
        __builtin_amdgcn_s_setprio(1);
        #pragma unroll
        for (int n = 0; n < 8; ++n) {
            int bo = (n * 16 + l15) * 42 + quad * 8;
            short8 bh = *(const short8*)(Bh + bo);
            #pragma unroll
            for (int m = 0; m < 2; ++m) {
                acc[m][n] = __builtin_amdgcn_mfma_f32_16x16x32_bf16(amh[m], bh, acc[m][n], 0, 0, 0);
                acc[m][n] = __builtin_amdgcn_mfma_f32_16x16x32_bf16(aml[m], bh, acc[m][n], 0, 0, 0);
            }
        }
        __builtin_amdgcn_s_setprio(0);
        __syncthreads();
    }

    float Ac[8], Oc[8], Wc[8];
    #pragma unroll
    for (int m = 0; m < 2; ++m)
        #pragma unroll
        for (int reg = 0; reg < 4; ++reg) {
            int co = wave * 32 + m * 16 + quad * 4 + reg;
            float A = g1[co] * rsqrtf(v1[co] + 1e-5f);
            Ac[m * 4 + reg] = A;
            Oc[m * 4 + reg] = fmaf(b1[co] - m1[co], A, be1[co]);
            Wc[m * 4 + reg] = w2[co];
        }
    #pragma unroll
    for (int n = 0; n < 8; ++n) {
        float part = 0.0f;
        #pragma unroll
        for (int m = 0; m < 2; ++m)
            #pragma unroll
            for (int reg = 0; reg < 4; ++reg) {
                float y = fmaxf(fmaf(acc[m][n][reg], Ac[m * 4 + reg], Oc[m * 4 + reg]), 0.0f);
                part = fmaf(Wc[m * 4 + reg], y, part);
            }
        red[(n * 16 + l15) * 33 + wave * 4 + quad] = part;
    }
    __syncthreads();
    if (tid < 128) {
        float z = b2[0];
        #pragma unroll
        for (int k = 0; k < 32; ++k) z += red[tid * 33 + k];
        if (p0 + tid < Np)
            out[ooff + (size_t)b * Np + p0 + tid] = 1.0f / (1.0f + expf(-z));
    }
}

// ---------------------------------------------------------------------------
extern "C" void kernel_launch(void* const* d_in, const int* in_sizes, int n_in,
                              void* d_out, int out_size, void* d_ws, size_t ws_size,
                              hipStream_t stream)
{
    const float* large  = (const float*)d_in[0];
    const float* medium = (const float*)d_in[1];
    const float* small  = (const float*)d_in[2];
    const float* search = (const float*)d_in[3];
    const float* wt  = (const float*)d_in[4];
    const float* bt  = (const float*)d_in[5];
    const float* gt  = (const float*)d_in[6];
    const float* bet = (const float*)d_in[7];
    const float* mt  = (const float*)d_in[8];
    const float* vt  = (const float*)d_in[9];
    const float* wsc = (const float*)d_in[10];
    const float* bs  = (const float*)d_in[11];
    const float* gs  = (const float*)d_in[12];
    const float* bes = (const float*)d_in[13];
    const float* ms  = (const float*)d_in[14];
    const float* vs  = (const float*)d_in[15];
    const float* w1  = (const float*)d_in[16];
    const float* b1  = (const float*)d_in[17];
    const float* g1  = (const float*)d_in[18];
    const float* be1 = (const float*)d_in[19];
    const float* m1  = (const float*)d_in[20];
    const float* v1  = (const float*)d_in[21];
    const float* w2  = (const float*)d_in[22];
    const float* b2  = (const float*)d_in[23];

    float* ws = (float*)d_ws;
    size_t off = 0;
    float* lf = ws + off; off += (size_t)64 * 256 * 49;
    float* mf = ws + off; off += (size_t)64 * 256 * 25;
    float* sf = ws + off; off += (size_t)64 * 256 * 9;
    float* sq = ws + off; off += (size_t)64 * 256 * 841;
    float* lc = ws + off; off += (size_t)64 * 256 * 729;
    float* mc = ws + off; off += (size_t)64 * 256 * 625;
    float* sc = ws + off; off += (size_t)64 * 256 * 729;

    // Aliased prep buffers (dead before corr writes lc/mc/sc):
    short* xh_s = (short*)lc;
    short* base = (short*)sc;
    short* xh_L = base;
    short* xh_M = base + 2654208;
    short* xh_S = base + 4259840;
    short* wh_t = base + 5079040;
    short* wl_t = base + 5668864;
    short* wh_s = base + 6258688;
    short* wl_s = base + 6848512;
    // w1 packed buffers live in sq (dead after corr; written after corr):
    short* w1hT = (short*)sq;
    short* w1lT = (short*)sq + 65536;

    dim3 blk(256);
    prep_all<<<dim3(5376), blk, 0, stream>>>(
        wt, wh_t, wl_t, wsc, wh_s, wl_s,
        search, xh_s, large, xh_L,
        medium, xh_M, small, xh_S);

    conv_mfma_all<<<dim3(1280), blk, 0, stream>>>(
        xh_s, wh_s, wl_s, bs, gs, bes, ms, vs, sq,
        xh_L, xh_M, xh_S, wh_t, wl_t,
        bt, gt, bet, mt, vt, lf, mf, sf);

    corr_kernel<<<dim3(64, 64), blk, 0, stream>>>(lf, mf, sf, sq, lc, mc, sc);

    // pack w1 into (now dead) sq region, then fused merged heads
    prep_w1<<<dim3(64), blk, 0, stream>>>(w1, w1hT, w1lT);

    head_mfma_kernel<<<dim3(17, 64), dim3(512), 0, stream>>>(
        lc, mc, sc, w1hT, w1lT, b1, g1, be1, m1, v1, w2, b2, (float*)d_out);
}

// Round 17
// 452.271 us; speedup vs baseline: 1.0319x; 1.0234x over previous
//
#include <hip/hip_runtime.h>
#include <math.h>
#include <stdint.h>

typedef __attribute__((ext_vector_type(8))) short short8;
typedef __attribute__((ext_vector_type(4))) float floatx4;

// fp32 -> (bf16 hi | bf16 lo) packed u32.  hi = RNE(x), lo = RNE(x - hi).
__device__ __forceinline__ uint32_t pack_hilo(float x) {
    uint32_t u = __float_as_uint(x);
    uint32_t hi = (u + 0x7FFFu + ((u >> 16) & 1u)) & 0xFFFF0000u;
    float r = x - __uint_as_float(hi);
    uint32_t v = __float_as_uint(r);
    uint32_t lo = ((v + 0x7FFFu + ((v >> 16) & 1u)) >> 16) & 0xFFFFu;
    return hi | lo;
}

// fp32 -> bf16 (RNE), low 16 bits of result.
__device__ __forceinline__ uint32_t bf16rne(float x) {
    uint32_t u = __float_as_uint(x);
    return ((u + 0x7FFFu + ((u >> 16) & 1u)) >> 16) & 0xFFFFu;
}

// async global->LDS DMA, 16 B per lane; lds dest must be wave-uniform base.
__device__ __forceinline__ void dma16(short* lds, const short* g) {
    __builtin_amdgcn_global_load_lds(
        (const __attribute__((address_space(1))) unsigned int*)g,
        (__attribute__((address_space(3))) unsigned int*)lds,
        16, 0, 0);
}

// ---------------------------------------------------------------------------
// Merged prep: conv weights (blocks 0..255) + activations (256..5375) +
// w1 packing (5376..5439; w1hT now in its own ws region — no sq alias, so
// it can run up front and the separate prep_w1 dispatch is eliminated).
// ---------------------------------------------------------------------------
__global__ __launch_bounds__(256) void prep_all(
    const float* __restrict__ wA, short* __restrict__ whA, short* __restrict__ wlA,
    const float* __restrict__ wB, short* __restrict__ whB, short* __restrict__ wlB,
    const float* __restrict__ xs, short* __restrict__ xhS,
    const float* __restrict__ xL, short* __restrict__ xhL,
    const float* __restrict__ xM, short* __restrict__ xhM,
    const float* __restrict__ xSm, short* __restrict__ xhSm,
    const float* __restrict__ w1, short* __restrict__ w1hT, short* __restrict__ w1lT)
{
    const int blk = blockIdx.x;
    if (blk < 256) {
        // ---- weight prep: fetch-order layout.  Lane-linear A-fragments:
        // frag(tile, cob, lane) at ((tile)*16 + cob)*512 + lane*8  ----
        int bx = blk;
        const float* w; short *wh, *wl;
        if (bx < 128) { w = wA; wh = whA; wl = wlA; }
        else          { w = wB; wh = whB; wl = wlB; bx -= 128; }
        const int idx = bx * 256 + threadIdx.x;
        const int co = idx >> 7, jp = idx & 127;      // ci = 2*jp
        const int c4 = jp >> 4;                       // ci>>5
        const int g  = (jp >> 2) & 3;                 // (ci>>3)&3
        const int cw = 2 * (jp & 3);                  // ci&7
        const float* s0 = w + ((size_t)co * 256 + 2 * jp) * 9;
        #pragma unroll
        for (int r = 0; r < 9; ++r) {
            uint32_t q0 = pack_hilo(s0[r]);
            uint32_t q1 = pack_hilo(s0[9 + r]);
            size_t o = ((size_t)(r * 8 + c4) * 16 + (co >> 4)) * 512
                     + (size_t)(g * 16 + (co & 15)) * 8 + cw;
            *(uint32_t*)(wh + o) = (q0 >> 16) | (q1 & 0xFFFF0000u);
            *(uint32_t*)(wl + o) = (q0 & 0xFFFFu) | (q1 << 16);
        }
        return;
    }
    if (blk >= 5376) {
        // ---- w1 prep: granule-swizzled chunk-major hi/lo ----
        const int idx = ((blk - 5376) * 256 + threadIdx.x) * 4;
        const int co = idx >> 8, ci = idx & 255;
        const int pos = (ci >> 5) * 8192 + (co >> 4) * 512 + ((ci >> 3) & 3) * 128
                      + (co & 15) * 8 + (ci & 7);
        float4 v4 = *(const float4*)(w1 + (size_t)co * 256 + ci);
        uint32_t pa = pack_hilo(v4.x), pb = pack_hilo(v4.y);
        uint32_t pc = pack_hilo(v4.z), pd = pack_hilo(v4.w);
        uint2 uh, ul;
        uh.x = (pa >> 16) | (pb & 0xFFFF0000u);
        uh.y = (pc >> 16) | (pd & 0xFFFF0000u);
        ul.x = (pa & 0xFFFFu) | (pb << 16);
        ul.y = (pc & 0xFFFFu) | (pd << 16);
        *(uint2*)(w1hT + pos) = uh;
        *(uint2*)(w1lT + pos) = ul;
        return;
    }
    // ---- activation prep (bf16 hi only) ----
    const int i = blk - 256;            // 0..5119
    const int bx = i % 20;
    const int by = (i / 20) & 3;
    const int b  = i / 80;

    const float* x; short *xh; int HW, p0;
    if (bx < 16)      { x = xs;  xh = xhS;  HW = 961; p0 = bx * 64; }
    else if (bx < 18) { x = xL;  xh = xhL;  HW = 81;  p0 = (bx - 16) * 64; }
    else if (bx < 19) { x = xM;  xh = xhM;  HW = 49;  p0 = 0; }
    else              { x = xSm; xh = xhSm; HW = 25;  p0 = 0; }

    const int c0 = by * 64;
    const int tid = threadIdx.x;
    const int a = tid & 63, g = tid >> 6;
    __shared__ uint32_t t[64][65];
    #pragma unroll
    for (int ii = 0; ii < 16; ++ii) {
        int c = g + ii * 4;
        int p = p0 + a;
        float v = (p < HW) ? x[((size_t)(b * 256) + c0 + c) * HW + p] : 0.0f;
        t[c][a] = pack_hilo(v);
    }
    __syncthreads();
    const int j = tid & 31;
    const int gg = tid >> 5;
    #pragma unroll
    for (int ii = 0; ii < 8; ++ii) {
        int p = gg + ii * 8;
        if (p0 + p < HW) {
            uint32_t w0 = t[2 * j][p], w1v = t[2 * j + 1][p];
            size_t o = ((size_t)b * HW + p0 + p) * 256 + c0 + 2 * j;
            *(uint32_t*)(xh + o) = (w0 >> 16) | (w1v & 0xFFFF0000u);
        }
    }
}

// ===========================================================================
// MFMA conv body v10b (R13/R14-proven: 2-term, K=64 phases, 4x8KB LDS, 72
// barriers, A direct global->VGPR, vmcnt(4) queue discipline).
// ===========================================================================
template<bool FULL>
__device__ __forceinline__ void conv_body(
    const short* __restrict__ xh,
    const short* __restrict__ wh, const short* __restrict__ wl,
    const float* __restrict__ bias,
    const float* __restrict__ gam, const float* __restrict__ bet,
    const float* __restrict__ mu,  const float* __restrict__ var,
    float* __restrict__ out,
    int b, int co0, int p0, int H, int W, short* smem)
{
    const int HW = H * W;
    const int Wo = W - 2, P = Wo * Wo;
    const int tid  = threadIdx.x;
    const int wave = tid >> 6, lane = tid & 63;
    const int l15  = lane & 15, quad = lane >> 4;

    int NT = 8;
    if (!FULL) {
        NT = (P - p0 + 15) >> 4;
        if (NT > 8) NT = 8;
    }

    // ---- A-fragment rolling global pointers (direct to VGPR) ----
    const int cob = (co0 >> 4) + wave * 2;
    const short* wA0 = wh + (size_t)cob * 512 + lane * 8;
    const short* wA2 = wl + (size_t)cob * 512 + lane * 8;

    // ---- X staging (R2): coalesced rows + granule XOR ----
    const int lrow = lane >> 2;
    const int lci  = ((lane & 3) ^ ((lane >> 3) & 3)) * 8;
    int pr0 = p0 + wave * 32 + lrow;      if (pr0 >= P) pr0 = 0;
    int pr1 = p0 + wave * 32 + 16 + lrow; if (pr1 >= P) pr1 = 0;
    const size_t bbase0 = ((size_t)b * HW + (pr0 / Wo) * W + (pr0 % Wo)) * 256 + lci;
    const size_t bbase1 = ((size_t)b * HW + (pr1 / Wo) * W + (pr1 % Wo)) * 256 + lci;

    const short* xs0 = xh + bbase0;
    const short* xs1 = xh + bbase1;
    const int rowadv = (W - 2) * 256 - 224;

    const int ldsw = wave * 1024;
    const int fBB = l15 * 32 + ((quad ^ ((l15 >> 1) & 3)) * 8); // XOR-swizzled B

    floatx4 acc[2][8];
    #pragma unroll
    for (int s = 0; s < 2; ++s)
        #pragma unroll
        for (int t = 0; t < 8; ++t) acc[s][t] = (floatx4){0.f, 0.f, 0.f, 0.f};

    // LDS: 4 buffers x 4096 shorts (Xh only) = 32 KB
    int jn = 0;
    auto issueX = [&](int q) {          // one K=32 chunk into buffer q
        short* base = smem + q * 4096;
        dma16(base + ldsw,               xs0);
        dma16(base + ldsw + 512,         xs1);
        ++jn;
        const int adv = (jn % 24 == 0) ? rowadv : 32;
        xs0 += adv; xs1 += adv;
    };

    issueX(0);   // chunk 0
    issueX(1);   // chunk 1

    for (int ph = 0; ph < 36; ++ph) {
        const int c0q = (2 * ph) & 3;   // buffer of first chunk: 0 or 2
        // A(pair ph) issued FIRST: older than X(pair ph+1) in the vmcnt queue.
        short8 a0h = *(const short8*)(wA0);
        short8 a1h = *(const short8*)(wA0 + 512);
        short8 a0l = *(const short8*)(wA2);
        short8 a1l = *(const short8*)(wA2 + 512);
        short8 c0h = *(const short8*)(wA0 + 8192);
        short8 c1h = *(const short8*)(wA0 + 8704);
        short8 c0l = *(const short8*)(wA2 + 8192);
        short8 c1l = *(const short8*)(wA2 + 8704);
        wA0 += 16384; wA2 += 16384;
        asm volatile("s_barrier" ::: "memory");            // pair p-1 compute done
        if (ph < 35) {
            issueX((c0q + 2) & 3);
            issueX((c0q + 3) & 3);
            asm volatile("s_waitcnt vmcnt(4)" ::: "memory"); // pair p + A done
        } else {
            asm volatile("s_waitcnt vmcnt(0)" ::: "memory");
        }
        asm volatile("s_barrier" ::: "memory");            // pair p visible
        const short* bq0 = smem + c0q * 4096;
        const short* bq1 = smem + ((c0q + 1) & 3) * 4096;
        __builtin_amdgcn_s_setprio(1);
        #pragma unroll
        for (int t = 0; t < 8; ++t) {
            if (FULL || t < NT) {
                short8 vh = *(const short8*)(bq0 + t * 512 + fBB);
                acc[0][t] = __builtin_amdgcn_mfma_f32_16x16x32_bf16(a0h, vh, acc[0][t], 0, 0, 0);
                acc[1][t] = __builtin_amdgcn_mfma_f32_16x16x32_bf16(a1h, vh, acc[1][t], 0, 0, 0);
                acc[0][t] = __builtin_amdgcn_mfma_f32_16x16x32_bf16(a0l, vh, acc[0][t], 0, 0, 0);
                acc[1][t] = __builtin_amdgcn_mfma_f32_16x16x32_bf16(a1l, vh, acc[1][t], 0, 0, 0);
            }
        }
        #pragma unroll
        for (int t = 0; t < 8; ++t) {
            if (FULL || t < NT) {
                short8 vh = *(const short8*)(bq1 + t * 512 + fBB);
                acc[0][t] = __builtin_amdgcn_mfma_f32_16x16x32_bf16(c0h, vh, acc[0][t], 0, 0, 0);
                acc[1][t] = __builtin_amdgcn_mfma_f32_16x16x32_bf16(c1h, vh, acc[1][t], 0, 0, 0);
                acc[0][t] = __builtin_amdgcn_mfma_f32_16x16x32_bf16(c0l, vh, acc[0][t], 0, 0, 0);
                acc[1][t] = __builtin_amdgcn_mfma_f32_16x16x32_bf16(c1l, vh, acc[1][t], 0, 0, 0);
            }
        }
        __builtin_amdgcn_s_setprio(0);
    }

    #pragma unroll
    for (int s = 0; s < 2; ++s) {
        const int cobase = co0 + wave * 32 + s * 16 + quad * 4;
        #pragma unroll
        for (int reg = 0; reg < 4; ++reg) {
            const int co = cobase + reg;
            const float A   = gam[co] * rsqrtf(var[co] + 1e-5f);
            const float OFF = fmaf(bias[co] - mu[co], A, bet[co]);
            float* orow = out + ((size_t)(b * 256 + co)) * P;
            #pragma unroll
            for (int t = 0; t < 8; ++t) {
                int px = p0 + t * 16 + l15;
                if ((FULL || t < NT) && px < P)
                    orow[px] = fmaxf(fmaf(acc[s][t][reg], A, OFF), 0.0f);
            }
        }
    }
}

// ---------------------------------------------------------------------------
// conv_mfma_all: search (blocks 0..895, XCD swizzle) + all 3 template scales
// (blocks 896..1279) in ONE dispatch.  32 KB LDS.
// ---------------------------------------------------------------------------
__global__ __launch_bounds__(256) void conv_mfma_all(
    const short* __restrict__ xh_s,
    const short* __restrict__ wh_s, const short* __restrict__ wl_s,
    const float* __restrict__ bs, const float* __restrict__ gs,
    const float* __restrict__ bes, const float* __restrict__ ms,
    const float* __restrict__ vs, float* __restrict__ sq,
    const short* __restrict__ xhL, const short* __restrict__ xhM,
    const short* __restrict__ xhS,
    const short* __restrict__ wh_t, const short* __restrict__ wl_t,
    const float* __restrict__ bt, const float* __restrict__ gt,
    const float* __restrict__ bet, const float* __restrict__ mt,
    const float* __restrict__ vt,
    float* __restrict__ lf, float* __restrict__ mf, float* __restrict__ sf)
{
    __shared__ __align__(16) short smem[16384];   // 4 x 4096-short X buffers
    const int i = blockIdx.x;
    if (i < 896) {
        const int xcd = i & 7, slot = i >> 3;
        const int bl = slot / 14, tile = slot - bl * 14;
        const int b = xcd * 8 + bl;
        const int cohalf = tile & 1, ptile = tile >> 1;
        if (ptile < 6)
            conv_body<true >(xh_s, wh_s, wl_s, bs, gs, bes, ms, vs, sq,
                             b, cohalf * 128, ptile * 128, 31, 31, smem);
        else
            conv_body<false>(xh_s, wh_s, wl_s, bs, gs, bes, ms, vs, sq,
                             b, cohalf * 128, ptile * 128, 31, 31, smem);
    } else {
        const int j = i - 896;                 // 0..383
        const int cohalf = j & 1, sb = j >> 1; // sb 0..191
        const int scale = sb >> 6, b = sb & 63;
        const short* xh = (scale == 0) ? xhL : (scale == 1) ? xhM : xhS;
        float* out      = (scale == 0) ? lf : (scale == 1) ? mf : sf;
        const int H     = (scale == 0) ? 9 : (scale == 1) ? 7 : 5;
        conv_body<false>(xh, wh_t, wl_t, bt, gt, bet, mt, vt, out,
                         b, cohalf * 128, 0, H, H, smem);
    }
}

// ---------------------------------------------------------------------------
// corr v3 (R14-proven: transposed lane map, conflict-free). grid (64,64)
// ---------------------------------------------------------------------------
__global__ __launch_bounds__(256) void corr_kernel(
    const float* __restrict__ lf, const float* __restrict__ mf,
    const float* __restrict__ sf, const float* __restrict__ s,
    float* __restrict__ lc, float* __restrict__ mc, float* __restrict__ sc)
{
    const int b = blockIdx.y;
    const int wave = threadIdx.x >> 6, lane = threadIdx.x & 63;
    const int c = blockIdx.x * 4 + wave;
    const int bc = b * 256 + c;

    __shared__ __align__(16) float sp[4][33 * 36];
    __shared__ float tw[4][96];

    float* P = sp[wave];
    for (int i = lane; i < 33 * 36; i += 64) P[i] = 0.0f;
    if (lane < 49) tw[wave][lane]      = lf[(size_t)bc * 49 + lane];
    if (lane < 25) tw[wave][49 + lane] = mf[(size_t)bc * 25 + lane];
    if (lane < 9)  tw[wave][74 + lane] = sf[(size_t)bc * 9 + lane];
    for (int i = lane; i < 841; i += 64) {
        int y = i / 29, x = i - y * 29;
        P[(y + 2) * 36 + (x + 2)] = s[(size_t)bc * 841 + i];
    }
    __syncthreads();

    const int x = lane & 31;
    const int h = lane >> 5;

    // ---- lc: 7x7 kernel, 27x27 out, no offset ----
    {
        float t7[49];
        #pragma unroll
        for (int k = 0; k < 49; ++k) t7[k] = tw[wave][k];
        for (int pass = 0; pass < 4; ++pass) {
            const int ro = pass * 8 + h * 4;
            float a0 = 0, a1 = 0, a2 = 0, a3 = 0;
            #pragma unroll
            for (int ir = 0; ir < 10; ++ir) {
                int r = ro + ir; if (r > 32) r = 32;
                const float* rp = P + r * 36 + x;
                #pragma unroll
                for (int dx = 0; dx < 7; ++dx) {
                    float v = rp[dx];
                    if (ir <= 6)             a0 = fmaf(t7[ir * 7 + dx], v, a0);
                    if (ir >= 1 && ir <= 7)  a1 = fmaf(t7[(ir - 1) * 7 + dx], v, a1);
                    if (ir >= 2 && ir <= 8)  a2 = fmaf(t7[(ir - 2) * 7 + dx], v, a2);
                    if (ir >= 3)             a3 = fmaf(t7[(ir - 3) * 7 + dx], v, a3);
                }
            }
            if (x < 27) {
                size_t o = (size_t)bc * 729 + (size_t)ro * 27 + x;
                if (ro     < 27) lc[o]      = a0;
                if (ro + 1 < 27) lc[o + 27] = a1;
                if (ro + 2 < 27) lc[o + 54] = a2;
                if (ro + 3 < 27) lc[o + 81] = a3;
            }
        }
    }
    // ---- mc: 5x5 kernel, 25x25 out, +2 offset both dims ----
    {
        float t5[25];
        #pragma unroll
        for (int k = 0; k < 25; ++k) t5[k] = tw[wave][49 + k];
        for (int pass = 0; pass < 4; ++pass) {
            const int ro = pass * 8 + h * 4;
            float a0 = 0, a1 = 0, a2 = 0, a3 = 0;
            #pragma unroll
            for (int ir = 0; ir < 8; ++ir) {
                int r = ro + 2 + ir; if (r > 32) r = 32;
                const float* rp = P + r * 36 + x + 2;
                #pragma unroll
                for (int dx = 0; dx < 5; ++dx) {
                    float v = rp[dx];
                    if (ir <= 4)             a0 = fmaf(t5[ir * 5 + dx], v, a0);
                    if (ir >= 1 && ir <= 5)  a1 = fmaf(t5[(ir - 1) * 5 + dx], v, a1);
                    if (ir >= 2 && ir <= 6)  a2 = fmaf(t5[(ir - 2) * 5 + dx], v, a2);
                    if (ir >= 3)             a3 = fmaf(t5[(ir - 3) * 5 + dx], v, a3);
                }
            }
            if (x < 25) {
                size_t o = (size_t)bc * 625 + (size_t)ro * 25 + x;
                if (ro     < 25) mc[o]      = a0;
                if (ro + 1 < 25) mc[o + 25] = a1;
                if (ro + 2 < 25) mc[o + 50] = a2;
                if (ro + 3 < 25) mc[o + 75] = a3;
            }
        }
    }
    // ---- sc: 3x3 kernel, 27x27 out, +2 offset both dims ----
    {
        float t3[9];
        #pragma unroll
        for (int k = 0; k < 9; ++k) t3[k] = tw[wave][74 + k];
        for (int pass = 0; pass < 4; ++pass) {
            const int ro = pass * 8 + h * 4;
            float a0 = 0, a1 = 0, a2 = 0, a3 = 0;
            #pragma unroll
            for (int ir = 0; ir < 6; ++ir) {
                int r = ro + 2 + ir; if (r > 32) r = 32;
                const float* rp = P + r * 36 + x + 2;
                #pragma unroll
                for (int dx = 0; dx < 3; ++dx) {
                    float v = rp[dx];
                    if (ir <= 2)             a0 = fmaf(t3[ir * 3 + dx], v, a0);
                    if (ir >= 1 && ir <= 3)  a1 = fmaf(t3[(ir - 1) * 3 + dx], v, a1);
                    if (ir >= 2 && ir <= 4)  a2 = fmaf(t3[(ir - 2) * 3 + dx], v, a2);
                    if (ir >= 3)             a3 = fmaf(t3[(ir - 3) * 3 + dx], v, a3);
                }
            }
            if (x < 27) {
                size_t o = (size_t)bc * 729 + (size_t)ro * 27 + x;
                if (ro     < 27) sc[o]      = a0;
                if (ro + 1 < 27) sc[o + 27] = a1;
                if (ro + 2 < 27) sc[o + 54] = a2;
                if (ro + 3 < 27) sc[o + 81] = a3;
            }
        }
    }
}

// ---------------------------------------------------------------------------
// head v5 (R14-proven best: 2-term, 8 waves x 32co, A via LDS dma, 4
// waves/SIMD).  R15 (p-split) and R16 (A-direct) both regressed; reverted.
// grid (17, 64).
// ---------------------------------------------------------------------------
__global__ __launch_bounds__(512, 4) void head_mfma_kernel(
    const float* __restrict__ lc, const float* __restrict__ mc,
    const float* __restrict__ sc,
    const short* __restrict__ w1hT, const short* __restrict__ w1lT,
    const float* __restrict__ b1,
    const float* __restrict__ g1, const float* __restrict__ be1,
    const float* __restrict__ m1, const float* __restrict__ v1,
    const float* __restrict__ w2, const float* __restrict__ b2,
    float* __restrict__ out)
{
    const int bx = blockIdx.x;
    const float* X; int Np, ooff, p0;
    if (bx < 6)       { X = lc; Np = 729; ooff = 0;     p0 = bx * 128; }
    else if (bx < 11) { X = mc; Np = 625; ooff = 46656; p0 = (bx - 6) * 128; }
    else              { X = sc; Np = 729; ooff = 86656; p0 = (bx - 11) * 128; }

    const int b  = blockIdx.y;
    const int tid = threadIdx.x;
    const int wave = tid >> 6, lane = tid & 63;   // wave 0..7
    const int l15 = lane & 15, quad = lane >> 4;

    __shared__ __align__(16) short Ah[256 * 32], Al[256 * 32];
    __shared__ __align__(16) short Bh[128 * 42];
    __shared__ float red[128 * 33];

    floatx4 acc[2][8];
    #pragma unroll
    for (int m = 0; m < 2; ++m)
        #pragma unroll
        for (int n = 0; n < 8; ++n) acc[m][n] = (floatx4){0.f, 0.f, 0.f, 0.f};

    const int pxq = tid & 31;      // p-quad: p = pxq*4 + j  (0..127)
    const int cp  = tid >> 5;      // 0..15: channels (2cp, 2cp+1) of 32-chunk

    for (int k0 = 0; k0 < 256; k0 += 32) {
        {
            const int kc = k0 >> 5;
            const short* srcH = w1hT + kc * 8192 + wave * 1024 + lane * 8;
            const short* srcL = w1lT + kc * 8192 + wave * 1024 + lane * 8;
            dma16(Ah + wave * 1024,       srcH);
            dma16(Ah + wave * 1024 + 512, srcH + 512);
            dma16(Al + wave * 1024,       srcL);
            dma16(Al + wave * 1024 + 512, srcL + 512);
        }
        {
            const int pxl = pxq * 4;
            const int gp = p0 + pxl;
            const float* r0 = X + ((size_t)(b * 256) + k0 + 2 * cp) * Np + gp;
            const float* r1 = r0 + Np;
            #pragma unroll
            for (int j = 0; j < 4; ++j) {
                float u = (gp + j < Np) ? r0[j] : 0.0f;
                float v = (gp + j < Np) ? r1[j] : 0.0f;
                int o = (pxl + j) * 42 + 2 * cp;
                *(uint32_t*)(Bh + o) = bf16rne(u) | (bf16rne(v) << 16);
            }
        }
        __syncthreads();
        short8 amh[2], aml[2];
        #pragma unroll
        for (int m = 0; m < 2; ++m) {
            int ao = (wave * 2 + m) * 512 + lane * 8;   // lane-linear
            amh[m] = *(const short8*)(Ah + ao);
            aml[m] = *(const short8*)(Al + ao);
        }
        __builtin_amdgcn_s_setprio(1);
        #pragma unroll
        for (int n = 0; n < 8; ++n) {
            int bo = (n * 16 + l15) * 42 + quad * 8;
            short8 bh = *(const short8*)(Bh + bo);
            #pragma unroll
            for (int m = 0; m < 2; ++m) {
                acc[m][n] = __builtin_amdgcn_mfma_f32_16x16x32_bf16(amh[m], bh, acc[m][n], 0, 0, 0);
                acc[m][n] = __builtin_amdgcn_mfma_f32_16x16x32_bf16(aml[m], bh, acc[m][n], 0, 0, 0);
            }
        }
        __builtin_amdgcn_s_setprio(0);
        __syncthreads();
    }

    float Ac[8], Oc[8], Wc[8];
    #pragma unroll
    for (int m = 0; m < 2; ++m)
        #pragma unroll
        for (int reg = 0; reg < 4; ++reg) {
            int co = wave * 32 + m * 16 + quad * 4 + reg;
            float A = g1[co] * rsqrtf(v1[co] + 1e-5f);
            Ac[m * 4 + reg] = A;
            Oc[m * 4 + reg] = fmaf(b1[co] - m1[co], A, be1[co]);
            Wc[m * 4 + reg] = w2[co];
        }
    #pragma unroll
    for (int n = 0; n < 8; ++n) {
        float part = 0.0f;
        #pragma unroll
        for (int m = 0; m < 2; ++m)
            #pragma unroll
            for (int reg = 0; reg < 4; ++reg) {
                float y = fmaxf(fmaf(acc[m][n][reg], Ac[m * 4 + reg], Oc[m * 4 + reg]), 0.0f);
                part = fmaf(Wc[m * 4 + reg], y, part);
            }
        red[(n * 16 + l15) * 33 + wave * 4 + quad] = part;
    }
    __syncthreads();
    if (tid < 128) {
        float z = b2[0];
        #pragma unroll
        for (int k = 0; k < 32; ++k) z += red[tid * 33 + k];
        if (p0 + tid < Np)
            out[ooff + (size_t)b * Np + p0 + tid] = 1.0f / (1.0f + expf(-z));
    }
}

// ---------------------------------------------------------------------------
extern "C" void kernel_launch(void* const* d_in, const int* in_sizes, int n_in,
                              void* d_out, int out_size, void* d_ws, size_t ws_size,
                              hipStream_t stream)
{
    const float* large  = (const float*)d_in[0];
    const float* medium = (const float*)d_in[1];
    const float* small  = (const float*)d_in[2];
    const float* search = (const float*)d_in[3];
    const float* wt  = (const float*)d_in[4];
    const float* bt  = (const float*)d_in[5];
    const float* gt  = (const float*)d_in[6];
    const float* bet = (const float*)d_in[7];
    const float* mt  = (const float*)d_in[8];
    const float* vt  = (const float*)d_in[9];
    const float* wsc = (const float*)d_in[10];
    const float* bs  = (const float*)d_in[11];
    const float* gs  = (const float*)d_in[12];
    const float* bes = (const float*)d_in[13];
    const float* ms  = (const float*)d_in[14];
    const float* vs  = (const float*)d_in[15];
    const float* w1  = (const float*)d_in[16];
    const float* b1  = (const float*)d_in[17];
    const float* g1  = (const float*)d_in[18];
    const float* be1 = (const float*)d_in[19];
    const float* m1  = (const float*)d_in[20];
    const float* v1  = (const float*)d_in[21];
    const float* w2  = (const float*)d_in[22];
    const float* b2  = (const float*)d_in[23];

    float* ws = (float*)d_ws;
    size_t off = 0;
    float* lf = ws + off; off += (size_t)64 * 256 * 49;
    float* mf = ws + off; off += (size_t)64 * 256 * 25;
    float* sf = ws + off; off += (size_t)64 * 256 * 9;
    float* sq = ws + off; off += (size_t)64 * 256 * 841;
    float* lc = ws + off; off += (size_t)64 * 256 * 729;
    float* mc = ws + off; off += (size_t)64 * 256 * 625;
    float* sc = ws + off; off += (size_t)64 * 256 * 729;
    // w1 packed buffers: own region (no aliasing -> packed in prep_all)
    short* w1hT = (short*)(ws + off); off += 32768;
    short* w1lT = (short*)(ws + off); off += 32768;

    // Aliased prep buffers (dead before corr writes lc/mc/sc):
    short* xh_s = (short*)lc;
    short* base = (short*)sc;
    short* xh_L = base;
    short* xh_M = base + 2654208;
    short* xh_S = base + 4259840;
    short* wh_t = base + 5079040;
    short* wl_t = base + 5668864;
    short* wh_s = base + 6258688;
    short* wl_s = base + 6848512;

    dim3 blk(256);
    prep_all<<<dim3(5440), blk, 0, stream>>>(
        wt, wh_t, wl_t, wsc, wh_s, wl_s,
        search, xh_s, large, xh_L,
        medium, xh_M, small, xh_S,
        w1, w1hT, w1lT);

    conv_mfma_all<<<dim3(1280), blk, 0, stream>>>(
        xh_s, wh_s, wl_s, bs, gs, bes, ms, vs, sq,
        xh_L, xh_M, xh_S, wh_t, wl_t,
        bt, gt, bet, mt, vt, lf, mf, sf);

    corr_kernel<<<dim3(64, 64), blk, 0, stream>>>(lf, mf, sf, sq, lc, mc, sc);

    head_mfma_kernel<<<dim3(17, 64), dim3(512), 0, stream>>>(
        lc, mc, sc, w1hT, w1lT, b1, g1, be1, m1, v1, w2, b2, (float*)d_out);
}

// Round 18
// 427.706 us; speedup vs baseline: 1.0911x; 1.0574x over previous
//
#include <hip/hip_runtime.h>
#include <math.h>
#include <stdint.h>

typedef __attribute__((ext_vector_type(8))) short short8;
typedef __attribute__((ext_vector_type(4))) float floatx4;

// fp32 -> (bf16 hi | bf16 lo) packed u32.  hi = RNE(x), lo = RNE(x - hi).
__device__ __forceinline__ uint32_t pack_hilo(float x) {
    uint32_t u = __float_as_uint(x);
    uint32_t hi = (u + 0x7FFFu + ((u >> 16) & 1u)) & 0xFFFF0000u;
    float r = x - __uint_as_float(hi);
    uint32_t v = __float_as_uint(r);
    uint32_t lo = ((v + 0x7FFFu + ((v >> 16) & 1u)) >> 16) & 0xFFFFu;
    return hi | lo;
}

// fp32 -> bf16 (RNE), low 16 bits of result.
__device__ __forceinline__ uint32_t bf16rne(float x) {
    uint32_t u = __float_as_uint(x);
    return ((u + 0x7FFFu + ((u >> 16) & 1u)) >> 16) & 0xFFFFu;
}

// async global->LDS DMA, 16 B per lane; lds dest must be wave-uniform base.
__device__ __forceinline__ void dma16(short* lds, const short* g) {
    __builtin_amdgcn_global_load_lds(
        (const __attribute__((address_space(1))) unsigned int*)g,
        (__attribute__((address_space(3))) unsigned int*)lds,
        16, 0, 0);
}

// ---------------------------------------------------------------------------
// Merged prep: conv weights (blocks 0..255) + activations (256..5375) +
// w1 packing (5376..5439).
// ---------------------------------------------------------------------------
__global__ __launch_bounds__(256) void prep_all(
    const float* __restrict__ wA, short* __restrict__ whA, short* __restrict__ wlA,
    const float* __restrict__ wB, short* __restrict__ whB, short* __restrict__ wlB,
    const float* __restrict__ xs, short* __restrict__ xhS,
    const float* __restrict__ xL, short* __restrict__ xhL,
    const float* __restrict__ xM, short* __restrict__ xhM,
    const float* __restrict__ xSm, short* __restrict__ xhSm,
    const float* __restrict__ w1, short* __restrict__ w1hT, short* __restrict__ w1lT)
{
    const int blk = blockIdx.x;
    if (blk < 256) {
        // ---- weight prep: fetch-order layout.  Lane-linear A-fragments:
        // frag(tile, cob, lane) at ((tile)*16 + cob)*512 + lane*8  ----
        int bx = blk;
        const float* w; short *wh, *wl;
        if (bx < 128) { w = wA; wh = whA; wl = wlA; }
        else          { w = wB; wh = whB; wl = wlB; bx -= 128; }
        const int idx = bx * 256 + threadIdx.x;
        const int co = idx >> 7, jp = idx & 127;      // ci = 2*jp
        const int c4 = jp >> 4;                       // ci>>5
        const int g  = (jp >> 2) & 3;                 // (ci>>3)&3
        const int cw = 2 * (jp & 3);                  // ci&7
        const float* s0 = w + ((size_t)co * 256 + 2 * jp) * 9;
        #pragma unroll
        for (int r = 0; r < 9; ++r) {
            uint32_t q0 = pack_hilo(s0[r]);
            uint32_t q1 = pack_hilo(s0[9 + r]);
            size_t o = ((size_t)(r * 8 + c4) * 16 + (co >> 4)) * 512
                     + (size_t)(g * 16 + (co & 15)) * 8 + cw;
            *(uint32_t*)(wh + o) = (q0 >> 16) | (q1 & 0xFFFF0000u);
            *(uint32_t*)(wl + o) = (q0 & 0xFFFFu) | (q1 << 16);
        }
        return;
    }
    if (blk >= 5376) {
        // ---- w1 prep: granule-swizzled chunk-major hi/lo ----
        const int idx = ((blk - 5376) * 256 + threadIdx.x) * 4;
        const int co = idx >> 8, ci = idx & 255;
        const int pos = (ci >> 5) * 8192 + (co >> 4) * 512 + ((ci >> 3) & 3) * 128
                      + (co & 15) * 8 + (ci & 7);
        float4 v4 = *(const float4*)(w1 + (size_t)co * 256 + ci);
        uint32_t pa = pack_hilo(v4.x), pb = pack_hilo(v4.y);
        uint32_t pc = pack_hilo(v4.z), pd = pack_hilo(v4.w);
        uint2 uh, ul;
        uh.x = (pa >> 16) | (pb & 0xFFFF0000u);
        uh.y = (pc >> 16) | (pd & 0xFFFF0000u);
        ul.x = (pa & 0xFFFFu) | (pb << 16);
        ul.y = (pc & 0xFFFFu) | (pd << 16);
        *(uint2*)(w1hT + pos) = uh;
        *(uint2*)(w1lT + pos) = ul;
        return;
    }
    // ---- activation prep (bf16 hi only) ----
    const int i = blk - 256;            // 0..5119
    const int bx = i % 20;
    const int by = (i / 20) & 3;
    const int b  = i / 80;

    const float* x; short *xh; int HW, p0;
    if (bx < 16)      { x = xs;  xh = xhS;  HW = 961; p0 = bx * 64; }
    else if (bx < 18) { x = xL;  xh = xhL;  HW = 81;  p0 = (bx - 16) * 64; }
    else if (bx < 19) { x = xM;  xh = xhM;  HW = 49;  p0 = 0; }
    else              { x = xSm; xh = xhSm; HW = 25;  p0 = 0; }

    const int c0 = by * 64;
    const int tid = threadIdx.x;
    const int a = tid & 63, g = tid >> 6;
    __shared__ uint32_t t[64][65];
    #pragma unroll
    for (int ii = 0; ii < 16; ++ii) {
        int c = g + ii * 4;
        int p = p0 + a;
        float v = (p < HW) ? x[((size_t)(b * 256) + c0 + c) * HW + p] : 0.0f;
        t[c][a] = pack_hilo(v);
    }
    __syncthreads();
    const int j = tid & 31;
    const int gg = tid >> 5;
    #pragma unroll
    for (int ii = 0; ii < 8; ++ii) {
        int p = gg + ii * 8;
        if (p0 + p < HW) {
            uint32_t w0 = t[2 * j][p], w1v = t[2 * j + 1][p];
            size_t o = ((size_t)b * HW + p0 + p) * 256 + c0 + 2 * j;
            *(uint32_t*)(xh + o) = (w0 >> 16) | (w1v & 0xFFFF0000u);
        }
    }
}

// ===========================================================================
// MFMA conv body v11: 1-TERM numerics probe (bf16 w x bf16 x — w_lo dropped).
// Error analysis: budget already carries ~4 independent 2^-9 contributions
// (x-rounding x2, corr-input, head-B); adding w-rounding grows total ~1.22x
// in quadrature -> predicted absmax ~0.01-0.016 vs passing 0.0078.
// MFMA/phase halves (64 -> 32/wave).  K=64 phases, 4x8KB LDS, 72 barriers,
// A direct global->VGPR; per phase: 4 A-loads FIRST, barrier, 4 next-pair X
// dmas, vmcnt(4) (drains A+X(cur), keeps X(next) in flight).
// ===========================================================================
template<bool FULL>
__device__ __forceinline__ void conv_body(
    const short* __restrict__ xh,
    const short* __restrict__ wh,
    const float* __restrict__ bias,
    const float* __restrict__ gam, const float* __restrict__ bet,
    const float* __restrict__ mu,  const float* __restrict__ var,
    float* __restrict__ out,
    int b, int co0, int p0, int H, int W, short* smem)
{
    const int HW = H * W;
    const int Wo = W - 2, P = Wo * Wo;
    const int tid  = threadIdx.x;
    const int wave = tid >> 6, lane = tid & 63;
    const int l15  = lane & 15, quad = lane >> 4;

    int NT = 8;
    if (!FULL) {
        NT = (P - p0 + 15) >> 4;
        if (NT > 8) NT = 8;
    }

    // ---- A-fragment rolling global pointers (direct to VGPR) ----
    const int cob = (co0 >> 4) + wave * 2;
    const short* wA0 = wh + (size_t)cob * 512 + lane * 8;

    // ---- X staging (R2): coalesced rows + granule XOR ----
    const int lrow = lane >> 2;
    const int lci  = ((lane & 3) ^ ((lane >> 3) & 3)) * 8;
    int pr0 = p0 + wave * 32 + lrow;      if (pr0 >= P) pr0 = 0;
    int pr1 = p0 + wave * 32 + 16 + lrow; if (pr1 >= P) pr1 = 0;
    const size_t bbase0 = ((size_t)b * HW + (pr0 / Wo) * W + (pr0 % Wo)) * 256 + lci;
    const size_t bbase1 = ((size_t)b * HW + (pr1 / Wo) * W + (pr1 % Wo)) * 256 + lci;

    const short* xs0 = xh + bbase0;
    const short* xs1 = xh + bbase1;
    const int rowadv = (W - 2) * 256 - 224;

    const int ldsw = wave * 1024;
    const int fBB = l15 * 32 + ((quad ^ ((l15 >> 1) & 3)) * 8); // XOR-swizzled B

    floatx4 acc[2][8];
    #pragma unroll
    for (int s = 0; s < 2; ++s)
        #pragma unroll
        for (int t = 0; t < 8; ++t) acc[s][t] = (floatx4){0.f, 0.f, 0.f, 0.f};

    // LDS: 4 buffers x 4096 shorts (Xh only) = 32 KB
    int jn = 0;
    auto issueX = [&](int q) {          // one K=32 chunk into buffer q
        short* base = smem + q * 4096;
        dma16(base + ldsw,               xs0);
        dma16(base + ldsw + 512,         xs1);
        ++jn;
        const int adv = (jn % 24 == 0) ? rowadv : 32;
        xs0 += adv; xs1 += adv;
    };

    issueX(0);   // chunk 0
    issueX(1);   // chunk 1

    for (int ph = 0; ph < 36; ++ph) {
        const int c0q = (2 * ph) & 3;   // buffer of first chunk: 0 or 2
        // A(pair ph) issued FIRST: older than X(pair ph+1) in the vmcnt queue.
        short8 a0h = *(const short8*)(wA0);
        short8 a1h = *(const short8*)(wA0 + 512);
        short8 c0h = *(const short8*)(wA0 + 8192);
        short8 c1h = *(const short8*)(wA0 + 8704);
        wA0 += 16384;
        asm volatile("s_barrier" ::: "memory");            // pair p-1 compute done
        if (ph < 35) {
            issueX((c0q + 2) & 3);
            issueX((c0q + 3) & 3);
            asm volatile("s_waitcnt vmcnt(4)" ::: "memory"); // pair p + A done
        } else {
            asm volatile("s_waitcnt vmcnt(0)" ::: "memory");
        }
        asm volatile("s_barrier" ::: "memory");            // pair p visible
        const short* bq0 = smem + c0q * 4096;
        const short* bq1 = smem + ((c0q + 1) & 3) * 4096;
        __builtin_amdgcn_s_setprio(1);
        #pragma unroll
        for (int t = 0; t < 8; ++t) {
            if (FULL || t < NT) {
                short8 vh = *(const short8*)(bq0 + t * 512 + fBB);
                acc[0][t] = __builtin_amdgcn_mfma_f32_16x16x32_bf16(a0h, vh, acc[0][t], 0, 0, 0);
                acc[1][t] = __builtin_amdgcn_mfma_f32_16x16x32_bf16(a1h, vh, acc[1][t], 0, 0, 0);
            }
        }
        #pragma unroll
        for (int t = 0; t < 8; ++t) {
            if (FULL || t < NT) {
                short8 vh = *(const short8*)(bq1 + t * 512 + fBB);
                acc[0][t] = __builtin_amdgcn_mfma_f32_16x16x32_bf16(c0h, vh, acc[0][t], 0, 0, 0);
                acc[1][t] = __builtin_amdgcn_mfma_f32_16x16x32_bf16(c1h, vh, acc[1][t], 0, 0, 0);
            }
        }
        __builtin_amdgcn_s_setprio(0);
    }

    #pragma unroll
    for (int s = 0; s < 2; ++s) {
        const int cobase = co0 + wave * 32 + s * 16 + quad * 4;
        #pragma unroll
        for (int reg = 0; reg < 4; ++reg) {
            const int co = cobase + reg;
            const float A   = gam[co] * rsqrtf(var[co] + 1e-5f);
            const float OFF = fmaf(bias[co] - mu[co], A, bet[co]);
            float* orow = out + ((size_t)(b * 256 + co)) * P;
            #pragma unroll
            for (int t = 0; t < 8; ++t) {
                int px = p0 + t * 16 + l15;
                if ((FULL || t < NT) && px < P)
                    orow[px] = fmaxf(fmaf(acc[s][t][reg], A, OFF), 0.0f);
            }
        }
    }
}

// ---------------------------------------------------------------------------
// conv_mfma_all: search (blocks 0..895, XCD swizzle) + all 3 template scales
// (blocks 896..1279) in ONE dispatch.  32 KB LDS.
// ---------------------------------------------------------------------------
__global__ __launch_bounds__(256) void conv_mfma_all(
    const short* __restrict__ xh_s,
    const short* __restrict__ wh_s,
    const float* __restrict__ bs, const float* __restrict__ gs,
    const float* __restrict__ bes, const float* __restrict__ ms,
    const float* __restrict__ vs, float* __restrict__ sq,
    const short* __restrict__ xhL, const short* __restrict__ xhM,
    const short* __restrict__ xhS,
    const short* __restrict__ wh_t,
    const float* __restrict__ bt, const float* __restrict__ gt,
    const float* __restrict__ bet, const float* __restrict__ mt,
    const float* __restrict__ vt,
    float* __restrict__ lf, float* __restrict__ mf, float* __restrict__ sf)
{
    __shared__ __align__(16) short smem[16384];   // 4 x 4096-short X buffers
    const int i = blockIdx.x;
    if (i < 896) {
        const int xcd = i & 7, slot = i >> 3;
        const int bl = slot / 14, tile = slot - bl * 14;
        const int b = xcd * 8 + bl;
        const int cohalf = tile & 1, ptile = tile >> 1;
        if (ptile < 6)
            conv_body<true >(xh_s, wh_s, bs, gs, bes, ms, vs, sq,
                             b, cohalf * 128, ptile * 128, 31, 31, smem);
        else
            conv_body<false>(xh_s, wh_s, bs, gs, bes, ms, vs, sq,
                             b, cohalf * 128, ptile * 128, 31, 31, smem);
    } else {
        const int j = i - 896;                 // 0..383
        const int cohalf = j & 1, sb = j >> 1; // sb 0..191
        const int scale = sb >> 6, b = sb & 63;
        const short* xh = (scale == 0) ? xhL : (scale == 1) ? xhM : xhS;
        float* out      = (scale == 0) ? lf : (scale == 1) ? mf : sf;
        const int H     = (scale == 0) ? 9 : (scale == 1) ? 7 : 5;
        conv_body<false>(xh, wh_t, bt, gt, bet, mt, vt, out,
                         b, cohalf * 128, 0, H, H, smem);
    }
}

// ---------------------------------------------------------------------------
// corr v3 (R14-proven: transposed lane map, conflict-free). grid (64,64)
// ---------------------------------------------------------------------------
__global__ __launch_bounds__(256) void corr_kernel(
    const float* __restrict__ lf, const float* __restrict__ mf,
    const float* __restrict__ sf, const float* __restrict__ s,
    float* __restrict__ lc, float* __restrict__ mc, float* __restrict__ sc)
{
    const int b = blockIdx.y;
    const int wave = threadIdx.x >> 6, lane = threadIdx.x & 63;
    const int c = blockIdx.x * 4 + wave;
    const int bc = b * 256 + c;

    __shared__ __align__(16) float sp[4][33 * 36];
    __shared__ float tw[4][96];

    float* P = sp[wave];
    for (int i = lane; i < 33 * 36; i += 64) P[i] = 0.0f;
    if (lane < 49) tw[wave][lane]      = lf[(size_t)bc * 49 + lane];
    if (lane < 25) tw[wave][49 + lane] = mf[(size_t)bc * 25 + lane];
    if (lane < 9)  tw[wave][74 + lane] = sf[(size_t)bc * 9 + lane];
    for (int i = lane; i < 841; i += 64) {
        int y = i / 29, x = i - y * 29;
        P[(y + 2) * 36 + (x + 2)] = s[(size_t)bc * 841 + i];
    }
    __syncthreads();

    const int x = lane & 31;
    const int h = lane >> 5;

    // ---- lc: 7x7 kernel, 27x27 out, no offset ----
    {
        float t7[49];
        #pragma unroll
        for (int k = 0; k < 49; ++k) t7[k] = tw[wave][k];
        for (int pass = 0; pass < 4; ++pass) {
            const int ro = pass * 8 + h * 4;
            float a0 = 0, a1 = 0, a2 = 0, a3 = 0;
            #pragma unroll
            for (int ir = 0; ir < 10; ++ir) {
                int r = ro + ir; if (r > 32) r = 32;
                const float* rp = P + r * 36 + x;
                #pragma unroll
                for (int dx = 0; dx < 7; ++dx) {
                    float v = rp[dx];
                    if (ir <= 6)             a0 = fmaf(t7[ir * 7 + dx], v, a0);
                    if (ir >= 1 && ir <= 7)  a1 = fmaf(t7[(ir - 1) * 7 + dx], v, a1);
                    if (ir >= 2 && ir <= 8)  a2 = fmaf(t7[(ir - 2) * 7 + dx], v, a2);
                    if (ir >= 3)             a3 = fmaf(t7[(ir - 3) * 7 + dx], v, a3);
                }
            }
            if (x < 27) {
                size_t o = (size_t)bc * 729 + (size_t)ro * 27 + x;
                if (ro     < 27) lc[o]      = a0;
                if (ro + 1 < 27) lc[o + 27] = a1;
                if (ro + 2 < 27) lc[o + 54] = a2;
                if (ro + 3 < 27) lc[o + 81] = a3;
            }
        }
    }
    // ---- mc: 5x5 kernel, 25x25 out, +2 offset both dims ----
    {
        float t5[25];
        #pragma unroll
        for (int k = 0; k < 25; ++k) t5[k] = tw[wave][49 + k];
        for (int pass = 0; pass < 4; ++pass) {
            const int ro = pass * 8 + h * 4;
            float a0 = 0, a1 = 0, a2 = 0, a3 = 0;
            #pragma unroll
            for (int ir = 0; ir < 8; ++ir) {
                int r = ro + 2 + ir; if (r > 32) r = 32;
                const float* rp = P + r * 36 + x + 2;
                #pragma unroll
                for (int dx = 0; dx < 5; ++dx) {
                    float v = rp[dx];
                    if (ir <= 4)             a0 = fmaf(t5[ir * 5 + dx], v, a0);
                    if (ir >= 1 && ir <= 5)  a1 = fmaf(t5[(ir - 1) * 5 + dx], v, a1);
                    if (ir >= 2 && ir <= 6)  a2 = fmaf(t5[(ir - 2) * 5 + dx], v, a2);
                    if (ir >= 3)             a3 = fmaf(t5[(ir - 3) * 5 + dx], v, a3);
                }
            }
            if (x < 25) {
                size_t o = (size_t)bc * 625 + (size_t)ro * 25 + x;
                if (ro     < 25) mc[o]      = a0;
                if (ro + 1 < 25) mc[o + 25] = a1;
                if (ro + 2 < 25) mc[o + 50] = a2;
                if (ro + 3 < 25) mc[o + 75] = a3;
            }
        }
    }
    // ---- sc: 3x3 kernel, 27x27 out, +2 offset both dims ----
    {
        float t3[9];
        #pragma unroll
        for (int k = 0; k < 9; ++k) t3[k] = tw[wave][74 + k];
        for (int pass = 0; pass < 4; ++pass) {
            const int ro = pass * 8 + h * 4;
            float a0 = 0, a1 = 0, a2 = 0, a3 = 0;
            #pragma unroll
            for (int ir = 0; ir < 6; ++ir) {
                int r = ro + 2 + ir; if (r > 32) r = 32;
                const float* rp = P + r * 36 + x + 2;
                #pragma unroll
                for (int dx = 0; dx < 3; ++dx) {
                    float v = rp[dx];
                    if (ir <= 2)             a0 = fmaf(t3[ir * 3 + dx], v, a0);
                    if (ir >= 1 && ir <= 3)  a1 = fmaf(t3[(ir - 1) * 3 + dx], v, a1);
                    if (ir >= 2 && ir <= 4)  a2 = fmaf(t3[(ir - 2) * 3 + dx], v, a2);
                    if (ir >= 3)             a3 = fmaf(t3[(ir - 3) * 3 + dx], v, a3);
                }
            }
            if (x < 27) {
                size_t o = (size_t)bc * 729 + (size_t)ro * 27 + x;
                if (ro     < 27) sc[o]      = a0;
                if (ro + 1 < 27) sc[o + 27] = a1;
                if (ro + 2 < 27) sc[o + 54] = a2;
                if (ro + 3 < 27) sc[o + 81] = a3;
            }
        }
    }
}

// ---------------------------------------------------------------------------
// head v5 (R14-proven best: 2-term, 8 waves x 32co, A via LDS dma).
// grid (17, 64).
// ---------------------------------------------------------------------------
__global__ __launch_bounds__(512, 4) void head_mfma_kernel(
    const float* __restrict__ lc, const float* __restrict__ mc,
    const float* __restrict__ sc,
    const short* __restrict__ w1hT, const short* __restrict__ w1lT,
    const float* __restrict__ b1,
    const float* __restrict__ g1, const float* __restrict__ be1,
    const float* __restrict__ m1, const float* __restrict__ v1,
    const float* __restrict__ w2, const float* __restrict__ b2,
    float* __restrict__ out)
{
    const int bx = blockIdx.x;
    const float* X; int Np, ooff, p0;
    if (bx < 6)       { X = lc; Np = 729; ooff = 0;     p0 = bx * 128; }
    else if (bx < 11) { X = mc; Np = 625; ooff = 46656; p0 = (bx - 6) * 128; }
    else              { X = sc; Np = 729; ooff = 86656; p0 = (bx - 11) * 128; }

    const int b  = blockIdx.y;
    const int tid = threadIdx.x;
    const int wave = tid >> 6, lane = tid & 63;   // wave 0..7
    const int l15 = lane & 15, quad = lane >> 4;

    __shared__ __align__(16) short Ah[256 * 32], Al[256 * 32];
    __shared__ __align__(16) short Bh[128 * 42];
    __shared__ float red[128 * 33];

    floatx4 acc[2][8];
    #pragma unroll
    for (int m = 0; m < 2; ++m)
        #pragma unroll
        for (int n = 0; n < 8; ++n) acc[m][n] = (floatx4){0.f, 0.f, 0.f, 0.f};

    const int pxq = tid & 31;      // p-quad: p = pxq*4 + j  (0..127)
    const int cp  = tid >> 5;      // 0..15: channels (2cp, 2cp+1) of 32-chunk

    for (int k0 = 0; k0 < 256; k0 += 32) {
        {
            const int kc = k0 >> 5;
            const short* srcH = w1hT + kc * 8192 + wave * 1024 + lane * 8;
            const short* srcL = w1lT + kc * 8192 + wave * 1024 + lane * 8;
            dma16(Ah + wave * 1024,       srcH);
            dma16(Ah + wave * 1024 + 512, srcH + 512);
            dma16(Al + wave * 1024,       srcL);
            dma16(Al + wave * 1024 + 512, srcL + 512);
        }
        {
            const int pxl = pxq * 4;
            const int gp = p0 + pxl;
            const float* r0 = X + ((size_t)(b * 256) + k0 + 2 * cp) * Np + gp;
            const float* r1 = r0 + Np;
            #pragma unroll
            for (int j = 0; j < 4; ++j) {
                float u = (gp + j < Np) ? r0[j] : 0.0f;
                float v = (gp + j < Np) ? r1[j] : 0.0f;
                int o = (pxl + j) * 42 + 2 * cp;
                *(uint32_t*)(Bh + o) = bf16rne(u) | (bf16rne(v) << 16);
            }
        }
        __syncthreads();
        short8 amh[2], aml[2];
        #pragma unroll
        for (int m = 0; m < 2; ++m) {
            int ao = (wave * 2 + m) * 512 + lane * 8;   // lane-linear
            amh[m] = *(const short8*)(Ah + ao);
            aml[m] = *(const short8*)(Al + ao);
        }
        __builtin_amdgcn_s_setprio(1);
        #pragma unroll
        for (int n = 0; n < 8; ++n) {
            int bo = (n * 16 + l15) * 42 + quad * 8;
            short8 bh = *(const short8*)(Bh + bo);
            #pragma unroll
            for (int m = 0; m < 2; ++m) {
                acc[m][n] = __builtin_amdgcn_mfma_f32_16x16x32_bf16(amh[m], bh, acc[m][n], 0, 0, 0);
                acc[m][n] = __builtin_amdgcn_mfma_f32_16x16x32_bf16(aml[m], bh, acc[m][n], 0, 0, 0);
            }
        }
        __builtin_amdgcn_s_setprio(0);
        __syncthreads();
    }

    float Ac[8], Oc[8], Wc[8];
    #pragma unroll
    for (int m = 0; m < 2; ++m)
        #pragma unroll
        for (int reg = 0; reg < 4; ++reg) {
            int co = wave * 32 + m * 16 + quad * 4 + reg;
            float A = g1[co] * rsqrtf(v1[co] + 1e-5f);
            Ac[m * 4 + reg] = A;
            Oc[m * 4 + reg] = fmaf(b1[co] - m1[co], A, be1[co]);
            Wc[m * 4 + reg] = w2[co];
        }
    #pragma unroll
    for (int n = 0; n < 8; ++n) {
        float part = 0.0f;
        #pragma unroll
        for (int m = 0; m < 2; ++m)
            #pragma unroll
            for (int reg = 0; reg < 4; ++reg) {
                float y = fmaxf(fmaf(acc[m][n][reg], Ac[m * 4 + reg], Oc[m * 4 + reg]), 0.0f);
                part = fmaf(Wc[m * 4 + reg], y, part);
            }
        red[(n * 16 + l15) * 33 + wave * 4 + quad] = part;
    }
    __syncthreads();
    if (tid < 128) {
        float z = b2[0];
        #pragma unroll
        for (int k = 0; k < 32; ++k) z += red[tid * 33 + k];
        if (p0 + tid < Np)
            out[ooff + (size_t)b * Np + p0 + tid] = 1.0f / (1.0f + expf(-z));
    }
}

// ---------------------------------------------------------------------------
extern "C" void kernel_launch(void* const* d_in, const int* in_sizes, int n_in,
                              void* d_out, int out_size, void* d_ws, size_t ws_size,
                              hipStream_t stream)
{
    const float* large  = (const float*)d_in[0];
    const float* medium = (const float*)d_in[1];
    const float* small  = (const float*)d_in[2];
    const float* search = (const float*)d_in[3];
    const float* wt  = (const float*)d_in[4];
    const float* bt  = (const float*)d_in[5];
    const float* gt  = (const float*)d_in[6];
    const float* bet = (const float*)d_in[7];
    const float* mt  = (const float*)d_in[8];
    const float* vt  = (const float*)d_in[9];
    const float* wsc = (const float*)d_in[10];
    const float* bs  = (const float*)d_in[11];
    const float* gs  = (const float*)d_in[12];
    const float* bes = (const float*)d_in[13];
    const float* ms  = (const float*)d_in[14];
    const float* vs  = (const float*)d_in[15];
    const float* w1  = (const float*)d_in[16];
    const float* b1  = (const float*)d_in[17];
    const float* g1  = (const float*)d_in[18];
    const float* be1 = (const float*)d_in[19];
    const float* m1  = (const float*)d_in[20];
    const float* v1  = (const float*)d_in[21];
    const float* w2  = (const float*)d_in[22];
    const float* b2  = (const float*)d_in[23];

    float* ws = (float*)d_ws;
    size_t off = 0;
    float* lf = ws + off; off += (size_t)64 * 256 * 49;
    float* mf = ws + off; off += (size_t)64 * 256 * 25;
    float* sf = ws + off; off += (size_t)64 * 256 * 9;
    float* sq = ws + off; off += (size_t)64 * 256 * 841;
    float* lc = ws + off; off += (size_t)64 * 256 * 729;
    float* mc = ws + off; off += (size_t)64 * 256 * 625;
    float* sc = ws + off; off += (size_t)64 * 256 * 729;
    // w1 packed buffers: own region (no aliasing -> packed in prep_all)
    short* w1hT = (short*)(ws + off); off += 32768;
    short* w1lT = (short*)(ws + off); off += 32768;

    // Aliased prep buffers (dead before corr writes lc/mc/sc):
    short* xh_s = (short*)lc;
    short* base = (short*)sc;
    short* xh_L = base;
    short* xh_M = base + 2654208;
    short* xh_S = base + 4259840;
    short* wh_t = base + 5079040;
    short* wl_t = base + 5668864;
    short* wh_s = base + 6258688;
    short* wl_s = base + 6848512;

    dim3 blk(256);
    prep_all<<<dim3(5440), blk, 0, stream>>>(
        wt, wh_t, wl_t, wsc, wh_s, wl_s,
        search, xh_s, large, xh_L,
        medium, xh_M, small, xh_S,
        w1, w1hT, w1lT);

    conv_mfma_all<<<dim3(1280), blk, 0, stream>>>(
        xh_s, wh_s, bs, gs, bes, ms, vs, sq,
        xh_L, xh_M, xh_S, wh_t,
        bt, gt, bet, mt, vt, lf, mf, sf);

    corr_kernel<<<dim3(64, 64), blk, 0, stream>>>(lf, mf, sf, sq, lc, mc, sc);

    head_mfma_kernel<<<dim3(17, 64), dim3(512), 0, stream>>>(
        lc, mc, sc, w1hT, w1lT, b1, g1, be1, m1, v1, w2, b2, (float*)d_out);
}

// Round 19
// 404.859 us; speedup vs baseline: 1.1527x; 1.0564x over previous
//
#include <hip/hip_runtime.h>
#include <math.h>
#include <stdint.h>

typedef __attribute__((ext_vector_type(8))) short short8;
typedef __attribute__((ext_vector_type(4))) float floatx4;

// fp32 -> (bf16 hi | bf16 lo) packed u32.  hi = RNE(x), lo = RNE(x - hi).
__device__ __forceinline__ uint32_t pack_hilo(float x) {
    uint32_t u = __float_as_uint(x);
    uint32_t hi = (u + 0x7FFFu + ((u >> 16) & 1u)) & 0xFFFF0000u;
    float r = x - __uint_as_float(hi);
    uint32_t v = __float_as_uint(r);
    uint32_t lo = ((v + 0x7FFFu + ((v >> 16) & 1u)) >> 16) & 0xFFFFu;
    return hi | lo;
}

// fp32 -> bf16 (RNE), low 16 bits of result.
__device__ __forceinline__ uint32_t bf16rne(float x) {
    uint32_t u = __float_as_uint(x);
    return ((u + 0x7FFFu + ((u >> 16) & 1u)) >> 16) & 0xFFFFu;
}

// async global->LDS DMA, 16 B per lane; lds dest must be wave-uniform base.
__device__ __forceinline__ void dma16(short* lds, const short* g) {
    __builtin_amdgcn_global_load_lds(
        (const __attribute__((address_space(1))) unsigned int*)g,
        (__attribute__((address_space(3))) unsigned int*)lds,
        16, 0, 0);
}

// ---------------------------------------------------------------------------
// Merged prep: conv weights (blocks 0..255) + activations (256..5375) +
// w1 packing (5376..5439).
// ---------------------------------------------------------------------------
__global__ __launch_bounds__(256) void prep_all(
    const float* __restrict__ wA, short* __restrict__ whA, short* __restrict__ wlA,
    const float* __restrict__ wB, short* __restrict__ whB, short* __restrict__ wlB,
    const float* __restrict__ xs, short* __restrict__ xhS,
    const float* __restrict__ xL, short* __restrict__ xhL,
    const float* __restrict__ xM, short* __restrict__ xhM,
    const float* __restrict__ xSm, short* __restrict__ xhSm,
    const float* __restrict__ w1, short* __restrict__ w1hT, short* __restrict__ w1lT)
{
    const int blk = blockIdx.x;
    if (blk < 256) {
        // ---- weight prep: fetch-order layout.  Lane-linear A-fragments:
        // frag(tile, cob, lane) at ((tile)*16 + cob)*512 + lane*8  ----
        int bx = blk;
        const float* w; short *wh, *wl;
        if (bx < 128) { w = wA; wh = whA; wl = wlA; }
        else          { w = wB; wh = whB; wl = wlB; bx -= 128; }
        const int idx = bx * 256 + threadIdx.x;
        const int co = idx >> 7, jp = idx & 127;      // ci = 2*jp
        const int c4 = jp >> 4;                       // ci>>5
        const int g  = (jp >> 2) & 3;                 // (ci>>3)&3
        const int cw = 2 * (jp & 3);                  // ci&7
        const float* s0 = w + ((size_t)co * 256 + 2 * jp) * 9;
        #pragma unroll
        for (int r = 0; r < 9; ++r) {
            uint32_t q0 = pack_hilo(s0[r]);
            uint32_t q1 = pack_hilo(s0[9 + r]);
            size_t o = ((size_t)(r * 8 + c4) * 16 + (co >> 4)) * 512
                     + (size_t)(g * 16 + (co & 15)) * 8 + cw;
            *(uint32_t*)(wh + o) = (q0 >> 16) | (q1 & 0xFFFF0000u);
            *(uint32_t*)(wl + o) = (q0 & 0xFFFFu) | (q1 << 16);
        }
        return;
    }
    if (blk >= 5376) {
        // ---- w1 prep: granule-swizzled chunk-major hi/lo ----
        const int idx = ((blk - 5376) * 256 + threadIdx.x) * 4;
        const int co = idx >> 8, ci = idx & 255;
        const int pos = (ci >> 5) * 8192 + (co >> 4) * 512 + ((ci >> 3) & 3) * 128
                      + (co & 15) * 8 + (ci & 7);
        float4 v4 = *(const float4*)(w1 + (size_t)co * 256 + ci);
        uint32_t pa = pack_hilo(v4.x), pb = pack_hilo(v4.y);
        uint32_t pc = pack_hilo(v4.z), pd = pack_hilo(v4.w);
        uint2 uh, ul;
        uh.x = (pa >> 16) | (pb & 0xFFFF0000u);
        uh.y = (pc >> 16) | (pd & 0xFFFF0000u);
        ul.x = (pa & 0xFFFFu) | (pb << 16);
        ul.y = (pc & 0xFFFFu) | (pd << 16);
        *(uint2*)(w1hT + pos) = uh;
        *(uint2*)(w1lT + pos) = ul;
        return;
    }
    // ---- activation prep (bf16 hi only) ----
    const int i = blk - 256;            // 0..5119
    const int bx = i % 20;
    const int by = (i / 20) & 3;
    const int b  = i / 80;

    const float* x; short *xh; int HW, p0;
    if (bx < 16)      { x = xs;  xh = xhS;  HW = 961; p0 = bx * 64; }
    else if (bx < 18) { x = xL;  xh = xhL;  HW = 81;  p0 = (bx - 16) * 64; }
    else if (bx < 19) { x = xM;  xh = xhM;  HW = 49;  p0 = 0; }
    else              { x = xSm; xh = xhSm; HW = 25;  p0 = 0; }

    const int c0 = by * 64;
    const int tid = threadIdx.x;
    const int a = tid & 63, g = tid >> 6;
    __shared__ uint32_t t[64][65];
    #pragma unroll
    for (int ii = 0; ii < 16; ++ii) {
        int c = g + ii * 4;
        int p = p0 + a;
        float v = (p < HW) ? x[((size_t)(b * 256) + c0 + c) * HW + p] : 0.0f;
        t[c][a] = pack_hilo(v);
    }
    __syncthreads();
    const int j = tid & 31;
    const int gg = tid >> 5;
    #pragma unroll
    for (int ii = 0; ii < 8; ++ii) {
        int p = gg + ii * 8;
        if (p0 + p < HW) {
            uint32_t w0 = t[2 * j][p], w1v = t[2 * j + 1][p];
            size_t o = ((size_t)b * HW + p0 + p) * 256 + c0 + 2 * j;
            *(uint32_t*)(xh + o) = (w0 >> 16) | (w1v & 0xFFFF0000u);
        }
    }
}

// ===========================================================================
// MFMA conv body v11 (R18-proven: 1-term bf16 w x bf16 x, K=64 phases,
// 4x8KB LDS, 72 barriers, A direct global->VGPR, vmcnt(4) discipline).
// ===========================================================================
template<bool FULL>
__device__ __forceinline__ void conv_body(
    const short* __restrict__ xh,
    const short* __restrict__ wh,
    const float* __restrict__ bias,
    const float* __restrict__ gam, const float* __restrict__ bet,
    const float* __restrict__ mu,  const float* __restrict__ var,
    float* __restrict__ out,
    int b, int co0, int p0, int H, int W, short* smem)
{
    const int HW = H * W;
    const int Wo = W - 2, P = Wo * Wo;
    const int tid  = threadIdx.x;
    const int wave = tid >> 6, lane = tid & 63;
    const int l15  = lane & 15, quad = lane >> 4;

    int NT = 8;
    if (!FULL) {
        NT = (P - p0 + 15) >> 4;
        if (NT > 8) NT = 8;
    }

    // ---- A-fragment rolling global pointers (direct to VGPR) ----
    const int cob = (co0 >> 4) + wave * 2;
    const short* wA0 = wh + (size_t)cob * 512 + lane * 8;

    // ---- X staging (R2): coalesced rows + granule XOR ----
    const int lrow = lane >> 2;
    const int lci  = ((lane & 3) ^ ((lane >> 3) & 3)) * 8;
    int pr0 = p0 + wave * 32 + lrow;      if (pr0 >= P) pr0 = 0;
    int pr1 = p0 + wave * 32 + 16 + lrow; if (pr1 >= P) pr1 = 0;
    const size_t bbase0 = ((size_t)b * HW + (pr0 / Wo) * W + (pr0 % Wo)) * 256 + lci;
    const size_t bbase1 = ((size_t)b * HW + (pr1 / Wo) * W + (pr1 % Wo)) * 256 + lci;

    const short* xs0 = xh + bbase0;
    const short* xs1 = xh + bbase1;
    const int rowadv = (W - 2) * 256 - 224;

    const int ldsw = wave * 1024;
    const int fBB = l15 * 32 + ((quad ^ ((l15 >> 1) & 3)) * 8); // XOR-swizzled B

    floatx4 acc[2][8];
    #pragma unroll
    for (int s = 0; s < 2; ++s)
        #pragma unroll
        for (int t = 0; t < 8; ++t) acc[s][t] = (floatx4){0.f, 0.f, 0.f, 0.f};

    // LDS: 4 buffers x 4096 shorts (Xh only) = 32 KB
    int jn = 0;
    auto issueX = [&](int q) {          // one K=32 chunk into buffer q
        short* base = smem + q * 4096;
        dma16(base + ldsw,               xs0);
        dma16(base + ldsw + 512,         xs1);
        ++jn;
        const int adv = (jn % 24 == 0) ? rowadv : 32;
        xs0 += adv; xs1 += adv;
    };

    issueX(0);   // chunk 0
    issueX(1);   // chunk 1

    for (int ph = 0; ph < 36; ++ph) {
        const int c0q = (2 * ph) & 3;   // buffer of first chunk: 0 or 2
        // A(pair ph) issued FIRST: older than X(pair ph+1) in the vmcnt queue.
        short8 a0h = *(const short8*)(wA0);
        short8 a1h = *(const short8*)(wA0 + 512);
        short8 c0h = *(const short8*)(wA0 + 8192);
        short8 c1h = *(const short8*)(wA0 + 8704);
        wA0 += 16384;
        asm volatile("s_barrier" ::: "memory");            // pair p-1 compute done
        if (ph < 35) {
            issueX((c0q + 2) & 3);
            issueX((c0q + 3) & 3);
            asm volatile("s_waitcnt vmcnt(4)" ::: "memory"); // pair p + A done
        } else {
            asm volatile("s_waitcnt vmcnt(0)" ::: "memory");
        }
        asm volatile("s_barrier" ::: "memory");            // pair p visible
        const short* bq0 = smem + c0q * 4096;
        const short* bq1 = smem + ((c0q + 1) & 3) * 4096;
        __builtin_amdgcn_s_setprio(1);
        #pragma unroll
        for (int t = 0; t < 8; ++t) {
            if (FULL || t < NT) {
                short8 vh = *(const short8*)(bq0 + t * 512 + fBB);
                acc[0][t] = __builtin_amdgcn_mfma_f32_16x16x32_bf16(a0h, vh, acc[0][t], 0, 0, 0);
                acc[1][t] = __builtin_amdgcn_mfma_f32_16x16x32_bf16(a1h, vh, acc[1][t], 0, 0, 0);
            }
        }
        #pragma unroll
        for (int t = 0; t < 8; ++t) {
            if (FULL || t < NT) {
                short8 vh = *(const short8*)(bq1 + t * 512 + fBB);
                acc[0][t] = __builtin_amdgcn_mfma_f32_16x16x32_bf16(c0h, vh, acc[0][t], 0, 0, 0);
                acc[1][t] = __builtin_amdgcn_mfma_f32_16x16x32_bf16(c1h, vh, acc[1][t], 0, 0, 0);
            }
        }
        __builtin_amdgcn_s_setprio(0);
    }

    #pragma unroll
    for (int s = 0; s < 2; ++s) {
        const int cobase = co0 + wave * 32 + s * 16 + quad * 4;
        #pragma unroll
        for (int reg = 0; reg < 4; ++reg) {
            const int co = cobase + reg;
            const float A   = gam[co] * rsqrtf(var[co] + 1e-5f);
            const float OFF = fmaf(bias[co] - mu[co], A, bet[co]);
            float* orow = out + ((size_t)(b * 256 + co)) * P;
            #pragma unroll
            for (int t = 0; t < 8; ++t) {
                int px = p0 + t * 16 + l15;
                if ((FULL || t < NT) && px < P)
                    orow[px] = fmaxf(fmaf(acc[s][t][reg], A, OFF), 0.0f);
            }
        }
    }
}

// ---------------------------------------------------------------------------
// conv_mfma_all: search (blocks 0..895, XCD swizzle) + all 3 template scales
// (blocks 896..1279) in ONE dispatch.  32 KB LDS.
// ---------------------------------------------------------------------------
__global__ __launch_bounds__(256) void conv_mfma_all(
    const short* __restrict__ xh_s,
    const short* __restrict__ wh_s,
    const float* __restrict__ bs, const float* __restrict__ gs,
    const float* __restrict__ bes, const float* __restrict__ ms,
    const float* __restrict__ vs, float* __restrict__ sq,
    const short* __restrict__ xhL, const short* __restrict__ xhM,
    const short* __restrict__ xhS,
    const short* __restrict__ wh_t,
    const float* __restrict__ bt, const float* __restrict__ gt,
    const float* __restrict__ bet, const float* __restrict__ mt,
    const float* __restrict__ vt,
    float* __restrict__ lf, float* __restrict__ mf, float* __restrict__ sf)
{
    __shared__ __align__(16) short smem[16384];   // 4 x 4096-short X buffers
    const int i = blockIdx.x;
    if (i < 896) {
        const int xcd = i & 7, slot = i >> 3;
        const int bl = slot / 14, tile = slot - bl * 14;
        const int b = xcd * 8 + bl;
        const int cohalf = tile & 1, ptile = tile >> 1;
        if (ptile < 6)
            conv_body<true >(xh_s, wh_s, bs, gs, bes, ms, vs, sq,
                             b, cohalf * 128, ptile * 128, 31, 31, smem);
        else
            conv_body<false>(xh_s, wh_s, bs, gs, bes, ms, vs, sq,
                             b, cohalf * 128, ptile * 128, 31, 31, smem);
    } else {
        const int j = i - 896;                 // 0..383
        const int cohalf = j & 1, sb = j >> 1; // sb 0..191
        const int scale = sb >> 6, b = sb & 63;
        const short* xh = (scale == 0) ? xhL : (scale == 1) ? xhM : xhS;
        float* out      = (scale == 0) ? lf : (scale == 1) ? mf : sf;
        const int H     = (scale == 0) ? 9 : (scale == 1) ? 7 : 5;
        conv_body<false>(xh, wh_t, bt, gt, bet, mt, vt, out,
                         b, cohalf * 128, 0, H, H, smem);
    }
}

// ---------------------------------------------------------------------------
// corr v4: R14's transposed lane map + BF16 OUTPUT.  Head rounds lc/mc/sc to
// bf16 in its B-staging anyway, so storing bf16 here is BIT-IDENTICAL for
// the final result while halving corr-write + head-read HBM traffic.
// grid (64,64).
// ---------------------------------------------------------------------------
__global__ __launch_bounds__(256) void corr_kernel(
    const float* __restrict__ lf, const float* __restrict__ mf,
    const float* __restrict__ sf, const float* __restrict__ s,
    short* __restrict__ lc, short* __restrict__ mc, short* __restrict__ sc)
{
    const int b = blockIdx.y;
    const int wave = threadIdx.x >> 6, lane = threadIdx.x & 63;
    const int c = blockIdx.x * 4 + wave;
    const int bc = b * 256 + c;

    __shared__ __align__(16) float sp[4][33 * 36];
    __shared__ float tw[4][96];

    float* P = sp[wave];
    for (int i = lane; i < 33 * 36; i += 64) P[i] = 0.0f;
    if (lane < 49) tw[wave][lane]      = lf[(size_t)bc * 49 + lane];
    if (lane < 25) tw[wave][49 + lane] = mf[(size_t)bc * 25 + lane];
    if (lane < 9)  tw[wave][74 + lane] = sf[(size_t)bc * 9 + lane];
    for (int i = lane; i < 841; i += 64) {
        int y = i / 29, x = i - y * 29;
        P[(y + 2) * 36 + (x + 2)] = s[(size_t)bc * 841 + i];
    }
    __syncthreads();

    const int x = lane & 31;
    const int h = lane >> 5;

    // ---- lc: 7x7 kernel, 27x27 out, no offset ----
    {
        float t7[49];
        #pragma unroll
        for (int k = 0; k < 49; ++k) t7[k] = tw[wave][k];
        for (int pass = 0; pass < 4; ++pass) {
            const int ro = pass * 8 + h * 4;
            float a0 = 0, a1 = 0, a2 = 0, a3 = 0;
            #pragma unroll
            for (int ir = 0; ir < 10; ++ir) {
                int r = ro + ir; if (r > 32) r = 32;
                const float* rp = P + r * 36 + x;
                #pragma unroll
                for (int dx = 0; dx < 7; ++dx) {
                    float v = rp[dx];
                    if (ir <= 6)             a0 = fmaf(t7[ir * 7 + dx], v, a0);
                    if (ir >= 1 && ir <= 7)  a1 = fmaf(t7[(ir - 1) * 7 + dx], v, a1);
                    if (ir >= 2 && ir <= 8)  a2 = fmaf(t7[(ir - 2) * 7 + dx], v, a2);
                    if (ir >= 3)             a3 = fmaf(t7[(ir - 3) * 7 + dx], v, a3);
                }
            }
            if (x < 27) {
                size_t o = (size_t)bc * 729 + (size_t)ro * 27 + x;
                if (ro     < 27) lc[o]      = (short)bf16rne(a0);
                if (ro + 1 < 27) lc[o + 27] = (short)bf16rne(a1);
                if (ro + 2 < 27) lc[o + 54] = (short)bf16rne(a2);
                if (ro + 3 < 27) lc[o + 81] = (short)bf16rne(a3);
            }
        }
    }
    // ---- mc: 5x5 kernel, 25x25 out, +2 offset both dims ----
    {
        float t5[25];
        #pragma unroll
        for (int k = 0; k < 25; ++k) t5[k] = tw[wave][49 + k];
        for (int pass = 0; pass < 4; ++pass) {
            const int ro = pass * 8 + h * 4;
            float a0 = 0, a1 = 0, a2 = 0, a3 = 0;
            #pragma unroll
            for (int ir = 0; ir < 8; ++ir) {
                int r = ro + 2 + ir; if (r > 32) r = 32;
                const float* rp = P + r * 36 + x + 2;
                #pragma unroll
                for (int dx = 0; dx < 5; ++dx) {
                    float v = rp[dx];
                    if (ir <= 4)             a0 = fmaf(t5[ir * 5 + dx], v, a0);
                    if (ir >= 1 && ir <= 5)  a1 = fmaf(t5[(ir - 1) * 5 + dx], v, a1);
                    if (ir >= 2 && ir <= 6)  a2 = fmaf(t5[(ir - 2) * 5 + dx], v, a2);
                    if (ir >= 3)             a3 = fmaf(t5[(ir - 3) * 5 + dx], v, a3);
                }
            }
            if (x < 25) {
                size_t o = (size_t)bc * 625 + (size_t)ro * 25 + x;
                if (ro     < 25) mc[o]      = (short)bf16rne(a0);
                if (ro + 1 < 25) mc[o + 25] = (short)bf16rne(a1);
                if (ro + 2 < 25) mc[o + 50] = (short)bf16rne(a2);
                if (ro + 3 < 25) mc[o + 75] = (short)bf16rne(a3);
            }
        }
    }
    // ---- sc: 3x3 kernel, 27x27 out, +2 offset both dims ----
    {
        float t3[9];
        #pragma unroll
        for (int k = 0; k < 9; ++k) t3[k] = tw[wave][74 + k];
        for (int pass = 0; pass < 4; ++pass) {
            const int ro = pass * 8 + h * 4;
            float a0 = 0, a1 = 0, a2 = 0, a3 = 0;
            #pragma unroll
            for (int ir = 0; ir < 6; ++ir) {
                int r = ro + 2 + ir; if (r > 32) r = 32;
                const float* rp = P + r * 36 + x + 2;
                #pragma unroll
                for (int dx = 0; dx < 3; ++dx) {
                    float v = rp[dx];
                    if (ir <= 2)             a0 = fmaf(t3[ir * 3 + dx], v, a0);
                    if (ir >= 1 && ir <= 3)  a1 = fmaf(t3[(ir - 1) * 3 + dx], v, a1);
                    if (ir >= 2 && ir <= 4)  a2 = fmaf(t3[(ir - 2) * 3 + dx], v, a2);
                    if (ir >= 3)             a3 = fmaf(t3[(ir - 3) * 3 + dx], v, a3);
                }
            }
            if (x < 27) {
                size_t o = (size_t)bc * 729 + (size_t)ro * 27 + x;
                if (ro     < 27) sc[o]      = (short)bf16rne(a0);
                if (ro + 1 < 27) sc[o + 27] = (short)bf16rne(a1);
                if (ro + 2 < 27) sc[o + 54] = (short)bf16rne(a2);
                if (ro + 3 < 27) sc[o + 81] = (short)bf16rne(a3);
            }
        }
    }
}

// ---------------------------------------------------------------------------
// head v5b: R14 structure; B inputs now bf16 shorts (no conversion needed —
// values identical to what bf16rne produced before).  grid (17, 64).
// ---------------------------------------------------------------------------
__global__ __launch_bounds__(512, 4) void head_mfma_kernel(
    const short* __restrict__ lc, const short* __restrict__ mc,
    const short* __restrict__ sc,
    const short* __restrict__ w1hT, const short* __restrict__ w1lT,
    const float* __restrict__ b1,
    const float* __restrict__ g1, const float* __restrict__ be1,
    const float* __restrict__ m1, const float* __restrict__ v1,
    const float* __restrict__ w2, const float* __restrict__ b2,
    float* __restrict__ out)
{
    const int bx = blockIdx.x;
    const short* X; int Np, ooff, p0;
    if (bx < 6)       { X = lc; Np = 729; ooff = 0;     p0 = bx * 128; }
    else if (bx < 11) { X = mc; Np = 625; ooff = 46656; p0 = (bx - 6) * 128; }
    else              { X = sc; Np = 729; ooff = 86656; p0 = (bx - 11) * 128; }

    const int b  = blockIdx.y;
    const int tid = threadIdx.x;
    const int wave = tid >> 6, lane = tid & 63;   // wave 0..7
    const int l15 = lane & 15, quad = lane >> 4;

    __shared__ __align__(16) short Ah[256 * 32], Al[256 * 32];
    __shared__ __align__(16) short Bh[128 * 42];
    __shared__ float red[128 * 33];

    floatx4 acc[2][8];
    #pragma unroll
    for (int m = 0; m < 2; ++m)
        #pragma unroll
        for (int n = 0; n < 8; ++n) acc[m][n] = (floatx4){0.f, 0.f, 0.f, 0.f};

    const int pxq = tid & 31;      // p-quad: p = pxq*4 + j  (0..127)
    const int cp  = tid >> 5;      // 0..15: channels (2cp, 2cp+1) of 32-chunk

    for (int k0 = 0; k0 < 256; k0 += 32) {
        {
            const int kc = k0 >> 5;
            const short* srcH = w1hT + kc * 8192 + wave * 1024 + lane * 8;
            const short* srcL = w1lT + kc * 8192 + wave * 1024 + lane * 8;
            dma16(Ah + wave * 1024,       srcH);
            dma16(Ah + wave * 1024 + 512, srcH + 512);
            dma16(Al + wave * 1024,       srcL);
            dma16(Al + wave * 1024 + 512, srcL + 512);
        }
        {
            const int pxl = pxq * 4;
            const int gp = p0 + pxl;
            const short* r0 = X + ((size_t)(b * 256) + k0 + 2 * cp) * Np + gp;
            const short* r1 = r0 + Np;
            #pragma unroll
            for (int j = 0; j < 4; ++j) {
                uint32_t u = (gp + j < Np) ? (uint32_t)(uint16_t)r0[j] : 0u;
                uint32_t v = (gp + j < Np) ? (uint32_t)(uint16_t)r1[j] : 0u;
                int o = (pxl + j) * 42 + 2 * cp;
                *(uint32_t*)(Bh + o) = u | (v << 16);
            }
        }
        __syncthreads();
        short8 amh[2], aml[2];
        #pragma unroll
        for (int m = 0; m < 2; ++m) {
            int ao = (wave * 2 + m) * 512 + lane * 8;   // lane-linear
            amh[m] = *(const short8*)(Ah + ao);
            aml[m] = *(const short8*)(Al + ao);
        }
        __builtin_amdgcn_s_setprio(1);
        #pragma unroll
        for (int n = 0; n < 8; ++n) {
            int bo = (n * 16 + l15) * 42 + quad * 8;
            short8 bh = *(const short8*)(Bh + bo);
            #pragma unroll
            for (int m = 0; m < 2; ++m) {
                acc[m][n] = __builtin_amdgcn_mfma_f32_16x16x32_bf16(amh[m], bh, acc[m][n], 0, 0, 0);
                acc[m][n] = __builtin_amdgcn_mfma_f32_16x16x32_bf16(aml[m], bh, acc[m][n], 0, 0, 0);
            }
        }
        __builtin_amdgcn_s_setprio(0);
        __syncthreads();
    }

    float Ac[8], Oc[8], Wc[8];
    #pragma unroll
    for (int m = 0; m < 2; ++m)
        #pragma unroll
        for (int reg = 0; reg < 4; ++reg) {
            int co = wave * 32 + m * 16 + quad * 4 + reg;
            float A = g1[co] * rsqrtf(v1[co] + 1e-5f);
            Ac[m * 4 + reg] = A;
            Oc[m * 4 + reg] = fmaf(b1[co] - m1[co], A, be1[co]);
            Wc[m * 4 + reg] = w2[co];
        }
    #pragma unroll
    for (int n = 0; n < 8; ++n) {
        float part = 0.0f;
        #pragma unroll
        for (int m = 0; m < 2; ++m)
            #pragma unroll
            for (int reg = 0; reg < 4; ++reg) {
                float y = fmaxf(fmaf(acc[m][n][reg], Ac[m * 4 + reg], Oc[m * 4 + reg]), 0.0f);
                part = fmaf(Wc[m * 4 + reg], y, part);
            }
        red[(n * 16 + l15) * 33 + wave * 4 + quad] = part;
    }
    __syncthreads();
    if (tid < 128) {
        float z = b2[0];
        #pragma unroll
        for (int k = 0; k < 32; ++k) z += red[tid * 33 + k];
        if (p0 + tid < Np)
            out[ooff + (size_t)b * Np + p0 + tid] = 1.0f / (1.0f + expf(-z));
    }
}

// ---------------------------------------------------------------------------
extern "C" void kernel_launch(void* const* d_in, const int* in_sizes, int n_in,
                              void* d_out, int out_size, void* d_ws, size_t ws_size,
                              hipStream_t stream)
{
    const float* large  = (const float*)d_in[0];
    const float* medium = (const float*)d_in[1];
    const float* small  = (const float*)d_in[2];
    const float* search = (const float*)d_in[3];
    const float* wt  = (const float*)d_in[4];
    const float* bt  = (const float*)d_in[5];
    const float* gt  = (const float*)d_in[6];
    const float* bet = (const float*)d_in[7];
    const float* mt  = (const float*)d_in[8];
    const float* vt  = (const float*)d_in[9];
    const float* wsc = (const float*)d_in[10];
    const float* bs  = (const float*)d_in[11];
    const float* gs  = (const float*)d_in[12];
    const float* bes = (const float*)d_in[13];
    const float* ms  = (const float*)d_in[14];
    const float* vs  = (const float*)d_in[15];
    const float* w1  = (const float*)d_in[16];
    const float* b1  = (const float*)d_in[17];
    const float* g1  = (const float*)d_in[18];
    const float* be1 = (const float*)d_in[19];
    const float* m1  = (const float*)d_in[20];
    const float* v1  = (const float*)d_in[21];
    const float* w2  = (const float*)d_in[22];
    const float* b2  = (const float*)d_in[23];

    float* ws = (float*)d_ws;
    size_t off = 0;
    float* lf = ws + off; off += (size_t)64 * 256 * 49;
    float* mf = ws + off; off += (size_t)64 * 256 * 25;
    float* sf = ws + off; off += (size_t)64 * 256 * 9;
    float* sq = ws + off; off += (size_t)64 * 256 * 841;
    // lc/mc/sc now bf16 (regions keep fp32-sized reservations for aliasing)
    short* lc = (short*)(ws + off); off += (size_t)64 * 256 * 729;
    short* mc = (short*)(ws + off); off += (size_t)64 * 256 * 625;
    short* sc = (short*)(ws + off); off += (size_t)64 * 256 * 729;
    // w1 packed buffers: own region (no aliasing -> packed in prep_all)
    short* w1hT = (short*)(ws + off); off += 32768;
    short* w1lT = (short*)(ws + off); off += 32768;

    // Aliased prep buffers (dead before corr writes lc/mc/sc):
    short* xh_s = (short*)lc;
    short* base = (short*)sc;
    short* xh_L = base;
    short* xh_M = base + 2654208;
    short* xh_S = base + 4259840;
    short* wh_t = base + 5079040;
    short* wl_t = base + 5668864;
    short* wh_s = base + 6258688;
    short* wl_s = base + 6848512;

    dim3 blk(256);
    prep_all<<<dim3(5440), blk, 0, stream>>>(
        wt, wh_t, wl_t, wsc, wh_s, wl_s,
        search, xh_s, large, xh_L,
        medium, xh_M, small, xh_S,
        w1, w1hT, w1lT);

    conv_mfma_all<<<dim3(1280), blk, 0, stream>>>(
        xh_s, wh_s, bs, gs, bes, ms, vs, sq,
        xh_L, xh_M, xh_S, wh_t,
        bt, gt, bet, mt, vt, lf, mf, sf);

    corr_kernel<<<dim3(64, 64), blk, 0, stream>>>(lf, mf, sf, sq, lc, mc, sc);

    head_mfma_kernel<<<dim3(17, 64), dim3(512), 0, stream>>>(
        lc, mc, sc, w1hT, w1lT, b1, g1, be1, m1, v1, w2, b2, (float*)d_out);
}

// Round 20
// 400.790 us; speedup vs baseline: 1.1644x; 1.0102x over previous
//
#include <hip/hip_runtime.h>
#include <math.h>
#include <stdint.h>

typedef __attribute__((ext_vector_type(8))) short short8;
typedef __attribute__((ext_vector_type(4))) float floatx4;

// fp32 -> (bf16 hi | bf16 lo) packed u32.  hi = RNE(x), lo = RNE(x - hi).
__device__ __forceinline__ uint32_t pack_hilo(float x) {
    uint32_t u = __float_as_uint(x);
    uint32_t hi = (u + 0x7FFFu + ((u >> 16) & 1u)) & 0xFFFF0000u;
    float r = x - __uint_as_float(hi);
    uint32_t v = __float_as_uint(r);
    uint32_t lo = ((v + 0x7FFFu + ((v >> 16) & 1u)) >> 16) & 0xFFFFu;
    return hi | lo;
}

// fp32 -> bf16 (RNE), low 16 bits of result.
__device__ __forceinline__ uint32_t bf16rne(float x) {
    uint32_t u = __float_as_uint(x);
    return ((u + 0x7FFFu + ((u >> 16) & 1u)) >> 16) & 0xFFFFu;
}

// async global->LDS DMA, 16 B per lane; lds dest must be wave-uniform base.
__device__ __forceinline__ void dma16(short* lds, const short* g) {
    __builtin_amdgcn_global_load_lds(
        (const __attribute__((address_space(1))) unsigned int*)g,
        (__attribute__((address_space(3))) unsigned int*)lds,
        16, 0, 0);
}

// ---------------------------------------------------------------------------
// Merged prep: conv weights (blocks 0..255) + activations (256..5375) +
// w1 packing (5376..5439).
// ---------------------------------------------------------------------------
__global__ __launch_bounds__(256) void prep_all(
    const float* __restrict__ wA, short* __restrict__ whA, short* __restrict__ wlA,
    const float* __restrict__ wB, short* __restrict__ whB, short* __restrict__ wlB,
    const float* __restrict__ xs, short* __restrict__ xhS,
    const float* __restrict__ xL, short* __restrict__ xhL,
    const float* __restrict__ xM, short* __restrict__ xhM,
    const float* __restrict__ xSm, short* __restrict__ xhSm,
    const float* __restrict__ w1, short* __restrict__ w1hT, short* __restrict__ w1lT)
{
    const int blk = blockIdx.x;
    if (blk < 256) {
        // ---- weight prep: fetch-order layout.  Lane-linear A-fragments:
        // frag(tile, cob, lane) at ((tile)*16 + cob)*512 + lane*8  ----
        int bx = blk;
        const float* w; short *wh, *wl;
        if (bx < 128) { w = wA; wh = whA; wl = wlA; }
        else          { w = wB; wh = whB; wl = wlB; bx -= 128; }
        const int idx = bx * 256 + threadIdx.x;
        const int co = idx >> 7, jp = idx & 127;      // ci = 2*jp
        const int c4 = jp >> 4;                       // ci>>5
        const int g  = (jp >> 2) & 3;                 // (ci>>3)&3
        const int cw = 2 * (jp & 3);                  // ci&7
        const float* s0 = w + ((size_t)co * 256 + 2 * jp) * 9;
        #pragma unroll
        for (int r = 0; r < 9; ++r) {
            uint32_t q0 = pack_hilo(s0[r]);
            uint32_t q1 = pack_hilo(s0[9 + r]);
            size_t o = ((size_t)(r * 8 + c4) * 16 + (co >> 4)) * 512
                     + (size_t)(g * 16 + (co & 15)) * 8 + cw;
            *(uint32_t*)(wh + o) = (q0 >> 16) | (q1 & 0xFFFF0000u);
            *(uint32_t*)(wl + o) = (q0 & 0xFFFFu) | (q1 << 16);
        }
        return;
    }
    if (blk >= 5376) {
        // ---- w1 prep: granule-swizzled chunk-major hi/lo ----
        const int idx = ((blk - 5376) * 256 + threadIdx.x) * 4;
        const int co = idx >> 8, ci = idx & 255;
        const int pos = (ci >> 5) * 8192 + (co >> 4) * 512 + ((ci >> 3) & 3) * 128
                      + (co & 15) * 8 + (ci & 7);
        float4 v4 = *(const float4*)(w1 + (size_t)co * 256 + ci);
        uint32_t pa = pack_hilo(v4.x), pb = pack_hilo(v4.y);
        uint32_t pc = pack_hilo(v4.z), pd = pack_hilo(v4.w);
        uint2 uh, ul;
        uh.x = (pa >> 16) | (pb & 0xFFFF0000u);
        uh.y = (pc >> 16) | (pd & 0xFFFF0000u);
        ul.x = (pa & 0xFFFFu) | (pb << 16);
        ul.y = (pc & 0xFFFFu) | (pd << 16);
        *(uint2*)(w1hT + pos) = uh;
        *(uint2*)(w1lT + pos) = ul;
        return;
    }
    // ---- activation prep (bf16 hi only) ----
    const int i = blk - 256;            // 0..5119
    const int bx = i % 20;
    const int by = (i / 20) & 3;
    const int b  = i / 80;

    const float* x; short *xh; int HW, p0;
    if (bx < 16)      { x = xs;  xh = xhS;  HW = 961; p0 = bx * 64; }
    else if (bx < 18) { x = xL;  xh = xhL;  HW = 81;  p0 = (bx - 16) * 64; }
    else if (bx < 19) { x = xM;  xh = xhM;  HW = 49;  p0 = 0; }
    else              { x = xSm; xh = xhSm; HW = 25;  p0 = 0; }

    const int c0 = by * 64;
    const int tid = threadIdx.x;
    const int a = tid & 63, g = tid >> 6;
    __shared__ uint32_t t[64][65];
    #pragma unroll
    for (int ii = 0; ii < 16; ++ii) {
        int c = g + ii * 4;
        int p = p0 + a;
        float v = (p < HW) ? x[((size_t)(b * 256) + c0 + c) * HW + p] : 0.0f;
        t[c][a] = pack_hilo(v);
    }
    __syncthreads();
    const int j = tid & 31;
    const int gg = tid >> 5;
    #pragma unroll
    for (int ii = 0; ii < 8; ++ii) {
        int p = gg + ii * 8;
        if (p0 + p < HW) {
            uint32_t w0 = t[2 * j][p], w1v = t[2 * j + 1][p];
            size_t o = ((size_t)b * HW + p0 + p) * 256 + c0 + 2 * j;
            *(uint32_t*)(xh + o) = (w0 >> 16) | (w1v & 0xFFFF0000u);
        }
    }
}

// ===========================================================================
// MFMA conv body v12 (R19 post-mortem: LDS B-reads are the binding pipe —
// all 4 waves read identical 8 KB/chunk under the co-only split).
//  * FULL tiles: 2co x 2p wave split — each wave owns 64co x 64p; B-reads
//    halve (4 KB/chunk/wave), A-tiles/wave double (direct-global, L2-hot).
//    Accumulation order per output unchanged -> bit-identical results.
//  * Partial/template tiles: R18 path verbatim (co-only split; avoids
//    wp=1 waves idling when NT <= 4).
//  * 1-term bf16, K=64 phases, 4x8KB LDS, 72 barriers, vmcnt(4) discipline
//    (A-loads issue BEFORE barrier -> older than X(next); vmcnt(4) drains
//    A + X(cur), keeps X(next) in flight).
// ===========================================================================
template<bool FULL>
__device__ __forceinline__ void conv_body(
    const short* __restrict__ xh,
    const short* __restrict__ wh,
    const float* __restrict__ bias,
    const float* __restrict__ gam, const float* __restrict__ bet,
    const float* __restrict__ mu,  const float* __restrict__ var,
    float* __restrict__ out,
    int b, int co0, int p0, int H, int W, short* smem)
{
    const int HW = H * W;
    const int Wo = W - 2, P = Wo * Wo;
    const int tid  = threadIdx.x;
    const int wave = tid >> 6, lane = tid & 63;
    const int l15  = lane & 15, quad = lane >> 4;

    constexpr int NC = FULL ? 4 : 2;   // co-tiles per wave
    constexpr int NP = FULL ? 4 : 8;   // p-tiles per wave
    const int wc = FULL ? (wave & 1) : wave;
    const int wp = FULL ? (wave >> 1) : 0;

    int NT = 8;
    if (!FULL) {
        NT = (P - p0 + 15) >> 4;
        if (NT > 8) NT = 8;
    }

    // ---- A-fragment rolling global pointers (direct to VGPR) ----
    const int cob = (co0 >> 4) + wc * NC;
    const short* wA0 = wh + (size_t)cob * 512 + lane * 8;

    // ---- X staging (R2): coalesced rows + granule XOR (per-wave quarter) ----
    const int lrow = lane >> 2;
    const int lci  = ((lane & 3) ^ ((lane >> 3) & 3)) * 8;
    int pr0 = p0 + wave * 32 + lrow;      if (pr0 >= P) pr0 = 0;
    int pr1 = p0 + wave * 32 + 16 + lrow; if (pr1 >= P) pr1 = 0;
    const size_t bbase0 = ((size_t)b * HW + (pr0 / Wo) * W + (pr0 % Wo)) * 256 + lci;
    const size_t bbase1 = ((size_t)b * HW + (pr1 / Wo) * W + (pr1 % Wo)) * 256 + lci;

    const short* xs0 = xh + bbase0;
    const short* xs1 = xh + bbase1;
    const int rowadv = (W - 2) * 256 - 224;

    const int ldsw = wave * 1024;
    const int fBB = l15 * 32 + ((quad ^ ((l15 >> 1) & 3)) * 8); // XOR-swizzled B

    floatx4 acc[NC][NP];
    #pragma unroll
    for (int m = 0; m < NC; ++m)
        #pragma unroll
        for (int t = 0; t < NP; ++t) acc[m][t] = (floatx4){0.f, 0.f, 0.f, 0.f};

    // LDS: 4 buffers x 4096 shorts (Xh only) = 32 KB
    int jn = 0;
    auto issueX = [&](int q) {          // one K=32 chunk into buffer q
        short* base = smem + q * 4096;
        dma16(base + ldsw,               xs0);
        dma16(base + ldsw + 512,         xs1);
        ++jn;
        const int adv = (jn % 24 == 0) ? rowadv : 32;
        xs0 += adv; xs1 += adv;
    };

    issueX(0);   // chunk 0
    issueX(1);   // chunk 1

    for (int ph = 0; ph < 36; ++ph) {
        const int c0q = (2 * ph) & 3;   // buffer of first chunk: 0 or 2
        // A(pair ph) issued FIRST: older than X(pair ph+1) in the vmcnt queue.
        short8 a0[NC], a1[NC];
        #pragma unroll
        for (int m = 0; m < NC; ++m) {
            a0[m] = *(const short8*)(wA0 + m * 512);
            a1[m] = *(const short8*)(wA0 + 8192 + m * 512);
        }
        wA0 += 16384;
        asm volatile("s_barrier" ::: "memory");            // pair p-1 compute done
        if (ph < 35) {
            issueX((c0q + 2) & 3);
            issueX((c0q + 3) & 3);
            asm volatile("s_waitcnt vmcnt(4)" ::: "memory"); // pair p + A done
        } else {
            asm volatile("s_waitcnt vmcnt(0)" ::: "memory");
        }
        asm volatile("s_barrier" ::: "memory");            // pair p visible
        const short* bq0 = smem + c0q * 4096;
        const short* bq1 = smem + ((c0q + 1) & 3) * 4096;
        __builtin_amdgcn_s_setprio(1);
        #pragma unroll
        for (int tt = 0; tt < NP; ++tt) {
            if (FULL || tt < NT) {
                const int tg = wp * 4 + tt;
                short8 vh = *(const short8*)(bq0 + tg * 512 + fBB);
                #pragma unroll
                for (int m = 0; m < NC; ++m)
                    acc[m][tt] = __builtin_amdgcn_mfma_f32_16x16x32_bf16(a0[m], vh, acc[m][tt], 0, 0, 0);
            }
        }
        #pragma unroll
        for (int tt = 0; tt < NP; ++tt) {
            if (FULL || tt < NT) {
                const int tg = wp * 4 + tt;
                short8 vh = *(const short8*)(bq1 + tg * 512 + fBB);
                #pragma unroll
                for (int m = 0; m < NC; ++m)
                    acc[m][tt] = __builtin_amdgcn_mfma_f32_16x16x32_bf16(a1[m], vh, acc[m][tt], 0, 0, 0);
            }
        }
        __builtin_amdgcn_s_setprio(0);
    }

    #pragma unroll
    for (int m = 0; m < NC; ++m) {
        const int cobase = co0 + wc * (NC * 16) + m * 16 + quad * 4;
        #pragma unroll
        for (int reg = 0; reg < 4; ++reg) {
            const int co = cobase + reg;
            const float A   = gam[co] * rsqrtf(var[co] + 1e-5f);
            const float OFF = fmaf(bias[co] - mu[co], A, bet[co]);
            float* orow = out + ((size_t)(b * 256 + co)) * P;
            #pragma unroll
            for (int tt = 0; tt < NP; ++tt) {
                int px = p0 + (wp * 4 + tt) * 16 + l15;
                if ((FULL || tt < NT) && px < P)
                    orow[px] = fmaxf(fmaf(acc[m][tt][reg], A, OFF), 0.0f);
            }
        }
    }
}

// ---------------------------------------------------------------------------
// conv_mfma_all: search (blocks 0..895, XCD swizzle) + all 3 template scales
// (blocks 896..1279) in ONE dispatch.  32 KB LDS.
// ---------------------------------------------------------------------------
__global__ __launch_bounds__(256) void conv_mfma_all(
    const short* __restrict__ xh_s,
    const short* __restrict__ wh_s,
    const float* __restrict__ bs, const float* __restrict__ gs,
    const float* __restrict__ bes, const float* __restrict__ ms,
    const float* __restrict__ vs, float* __restrict__ sq,
    const short* __restrict__ xhL, const short* __restrict__ xhM,
    const short* __restrict__ xhS,
    const short* __restrict__ wh_t,
    const float* __restrict__ bt, const float* __restrict__ gt,
    const float* __restrict__ bet, const float* __restrict__ mt,
    const float* __restrict__ vt,
    float* __restrict__ lf, float* __restrict__ mf, float* __restrict__ sf)
{
    __shared__ __align__(16) short smem[16384];   // 4 x 4096-short X buffers
    const int i = blockIdx.x;
    if (i < 896) {
        const int xcd = i & 7, slot = i >> 3;
        const int bl = slot / 14, tile = slot - bl * 14;
        const int b = xcd * 8 + bl;
        const int cohalf = tile & 1, ptile = tile >> 1;
        if (ptile < 6)
            conv_body<true >(xh_s, wh_s, bs, gs, bes, ms, vs, sq,
                             b, cohalf * 128, ptile * 128, 31, 31, smem);
        else
            conv_body<false>(xh_s, wh_s, bs, gs, bes, ms, vs, sq,
                             b, cohalf * 128, ptile * 128, 31, 31, smem);
    } else {
        const int j = i - 896;                 // 0..383
        const int cohalf = j & 1, sb = j >> 1; // sb 0..191
        const int scale = sb >> 6, b = sb & 63;
        const short* xh = (scale == 0) ? xhL : (scale == 1) ? xhM : xhS;
        float* out      = (scale == 0) ? lf : (scale == 1) ? mf : sf;
        const int H     = (scale == 0) ? 9 : (scale == 1) ? 7 : 5;
        conv_body<false>(xh, wh_t, bt, gt, bet, mt, vt, out,
                         b, cohalf * 128, 0, H, H, smem);
    }
}

// ---------------------------------------------------------------------------
// corr v4 (R19-proven: transposed lane map + bf16 output). grid (64,64)
// ---------------------------------------------------------------------------
__global__ __launch_bounds__(256) void corr_kernel(
    const float* __restrict__ lf, const float* __restrict__ mf,
    const float* __restrict__ sf, const float* __restrict__ s,
    short* __restrict__ lc, short* __restrict__ mc, short* __restrict__ sc)
{
    const int b = blockIdx.y;
    const int wave = threadIdx.x >> 6, lane = threadIdx.x & 63;
    const int c = blockIdx.x * 4 + wave;
    const int bc = b * 256 + c;

    __shared__ __align__(16) float sp[4][33 * 36];
    __shared__ float tw[4][96];

    float* P = sp[wave];
    for (int i = lane; i < 33 * 36; i += 64) P[i] = 0.0f;
    if (lane < 49) tw[wave][lane]      = lf[(size_t)bc * 49 + lane];
    if (lane < 25) tw[wave][49 + lane] = mf[(size_t)bc * 25 + lane];
    if (lane < 9)  tw[wave][74 + lane] = sf[(size_t)bc * 9 + lane];
    for (int i = lane; i < 841; i += 64) {
        int y = i / 29, x = i - y * 29;
        P[(y + 2) * 36 + (x + 2)] = s[(size_t)bc * 841 + i];
    }
    __syncthreads();

    const int x = lane & 31;
    const int h = lane >> 5;

    // ---- lc: 7x7 kernel, 27x27 out, no offset ----
    {
        float t7[49];
        #pragma unroll
        for (int k = 0; k < 49; ++k) t7[k] = tw[wave][k];
        for (int pass = 0; pass < 4; ++pass) {
            const int ro = pass * 8 + h * 4;
            float a0 = 0, a1 = 0, a2 = 0, a3 = 0;
            #pragma unroll
            for (int ir = 0; ir < 10; ++ir) {
                int r = ro + ir; if (r > 32) r = 32;
                const float* rp = P + r * 36 + x;
                #pragma unroll
                for (int dx = 0; dx < 7; ++dx) {
                    float v = rp[dx];
                    if (ir <= 6)             a0 = fmaf(t7[ir * 7 + dx], v, a0);
                    if (ir >= 1 && ir <= 7)  a1 = fmaf(t7[(ir - 1) * 7 + dx], v, a1);
                    if (ir >= 2 && ir <= 8)  a2 = fmaf(t7[(ir - 2) * 7 + dx], v, a2);
                    if (ir >= 3)             a3 = fmaf(t7[(ir - 3) * 7 + dx], v, a3);
                }
            }
            if (x < 27) {
                size_t o = (size_t)bc * 729 + (size_t)ro * 27 + x;
                if (ro     < 27) lc[o]      = (short)bf16rne(a0);
                if (ro + 1 < 27) lc[o + 27] = (short)bf16rne(a1);
                if (ro + 2 < 27) lc[o + 54] = (short)bf16rne(a2);
                if (ro + 3 < 27) lc[o + 81] = (short)bf16rne(a3);
            }
        }
    }
    // ---- mc: 5x5 kernel, 25x25 out, +2 offset both dims ----
    {
        float t5[25];
        #pragma unroll
        for (int k = 0; k < 25; ++k) t5[k] = tw[wave][49 + k];
        for (int pass = 0; pass < 4; ++pass) {
            const int ro = pass * 8 + h * 4;
            float a0 = 0, a1 = 0, a2 = 0, a3 = 0;
            #pragma unroll
            for (int ir = 0; ir < 8; ++ir) {
                int r = ro + 2 + ir; if (r > 32) r = 32;
                const float* rp = P + r * 36 + x + 2;
                #pragma unroll
                for (int dx = 0; dx < 5; ++dx) {
                    float v = rp[dx];
                    if (ir <= 4)             a0 = fmaf(t5[ir * 5 + dx], v, a0);
                    if (ir >= 1 && ir <= 5)  a1 = fmaf(t5[(ir - 1) * 5 + dx], v, a1);
                    if (ir >= 2 && ir <= 6)  a2 = fmaf(t5[(ir - 2) * 5 + dx], v, a2);
                    if (ir >= 3)             a3 = fmaf(t5[(ir - 3) * 5 + dx], v, a3);
                }
            }
            if (x < 25) {
                size_t o = (size_t)bc * 625 + (size_t)ro * 25 + x;
                if (ro     < 25) mc[o]      = (short)bf16rne(a0);
                if (ro + 1 < 25) mc[o + 25] = (short)bf16rne(a1);
                if (ro + 2 < 25) mc[o + 50] = (short)bf16rne(a2);
                if (ro + 3 < 25) mc[o + 75] = (short)bf16rne(a3);
            }
        }
    }
    // ---- sc: 3x3 kernel, 27x27 out, +2 offset both dims ----
    {
        float t3[9];
        #pragma unroll
        for (int k = 0; k < 9; ++k) t3[k] = tw[wave][74 + k];
        for (int pass = 0; pass < 4; ++pass) {
            const int ro = pass * 8 + h * 4;
            float a0 = 0, a1 = 0, a2 = 0, a3 = 0;
            #pragma unroll
            for (int ir = 0; ir < 6; ++ir) {
                int r = ro + 2 + ir; if (r > 32) r = 32;
                const float* rp = P + r * 36 + x + 2;
                #pragma unroll
                for (int dx = 0; dx < 3; ++dx) {
                    float v = rp[dx];
                    if (ir <= 2)             a0 = fmaf(t3[ir * 3 + dx], v, a0);
                    if (ir >= 1 && ir <= 3)  a1 = fmaf(t3[(ir - 1) * 3 + dx], v, a1);
                    if (ir >= 2 && ir <= 4)  a2 = fmaf(t3[(ir - 2) * 3 + dx], v, a2);
                    if (ir >= 3)             a3 = fmaf(t3[(ir - 3) * 3 + dx], v, a3);
                }
            }
            if (x < 27) {
                size_t o = (size_t)bc * 729 + (size_t)ro * 27 + x;
                if (ro     < 27) sc[o]      = (short)bf16rne(a0);
                if (ro + 1 < 27) sc[o + 27] = (short)bf16rne(a1);
                if (ro + 2 < 27) sc[o + 54] = (short)bf16rne(a2);
                if (ro + 3 < 27) sc[o + 81] = (short)bf16rne(a3);
            }
        }
    }
}

// ---------------------------------------------------------------------------
// head v5b (R19-proven: R14 structure, bf16 B inputs). grid (17, 64).
// ---------------------------------------------------------------------------
__global__ __launch_bounds__(512, 4) void head_mfma_kernel(
    const short* __restrict__ lc, const short* __restrict__ mc,
    const short* __restrict__ sc,
    const short* __restrict__ w1hT, const short* __restrict__ w1lT,
    const float* __restrict__ b1,
    const float* __restrict__ g1, const float* __restrict__ be1,
    const float* __restrict__ m1, const float* __restrict__ v1,
    const float* __restrict__ w2, const float* __restrict__ b2,
    float* __restrict__ out)
{
    const int bx = blockIdx.x;
    const short* X; int Np, ooff, p0;
    if (bx < 6)       { X = lc; Np = 729; ooff = 0;     p0 = bx * 128; }
    else if (bx < 11) { X = mc; Np = 625; ooff = 46656; p0 = (bx - 6) * 128; }
    else              { X = sc; Np = 729; ooff = 86656; p0 = (bx - 11) * 128; }

    const int b  = blockIdx.y;
    const int tid = threadIdx.x;
    const int wave = tid >> 6, lane = tid & 63;   // wave 0..7
    const int l15 = lane & 15, quad = lane >> 4;

    __shared__ __align__(16) short Ah[256 * 32], Al[256 * 32];
    __shared__ __align__(16) short Bh[128 * 42];
    __shared__ float red[128 * 33];

    floatx4 acc[2][8];
    #pragma unroll
    for (int m = 0; m < 2; ++m)
        #pragma unroll
        for (int n = 0; n < 8; ++n) acc[m][n] = (floatx4){0.f, 0.f, 0.f, 0.f};

    const int pxq = tid & 31;      // p-quad: p = pxq*4 + j  (0..127)
    const int cp  = tid >> 5;      // 0..15: channels (2cp, 2cp+1) of 32-chunk

    for (int k0 = 0; k0 < 256; k0 += 32) {
        {
            const int kc = k0 >> 5;
            const short* srcH = w1hT + kc * 8192 + wave * 1024 + lane * 8;
            const short* srcL = w1lT + kc * 8192 + wave * 1024 + lane * 8;
            dma16(Ah + wave * 1024,       srcH);
            dma16(Ah + wave * 1024 + 512, srcH + 512);
            dma16(Al + wave * 1024,       srcL);
            dma16(Al + wave * 1024 + 512, srcL + 512);
        }
        {
            const int pxl = pxq * 4;
            const int gp = p0 + pxl;
            const short* r0 = X + ((size_t)(b * 256) + k0 + 2 * cp) * Np + gp;
            const short* r1 = r0 + Np;
            #pragma unroll
            for (int j = 0; j < 4; ++j) {
                uint32_t u = (gp + j < Np) ? (uint32_t)(uint16_t)r0[j] : 0u;
                uint32_t v = (gp + j < Np) ? (uint32_t)(uint16_t)r1[j] : 0u;
                int o = (pxl + j) * 42 + 2 * cp;
                *(uint32_t*)(Bh + o) = u | (v << 16);
            }
        }
        __syncthreads();
        short8 amh[2], aml[2];
        #pragma unroll
        for (int m = 0; m < 2; ++m) {
            int ao = (wave * 2 + m) * 512 + lane * 8;   // lane-linear
            amh[m] = *(const short8*)(Ah + ao);
            aml[m] = *(const short8*)(Al + ao);
        }
        __builtin_amdgcn_s_setprio(1);
        #pragma unroll
        for (int n = 0; n < 8; ++n) {
            int bo = (n * 16 + l15) * 42 + quad * 8;
            short8 bh = *(const short8*)(Bh + bo);
            #pragma unroll
            for (int m = 0; m < 2; ++m) {
                acc[m][n] = __builtin_amdgcn_mfma_f32_16x16x32_bf16(amh[m], bh, acc[m][n], 0, 0, 0);
                acc[m][n] = __builtin_amdgcn_mfma_f32_16x16x32_bf16(aml[m], bh, acc[m][n], 0, 0, 0);
            }
        }
        __builtin_amdgcn_s_setprio(0);
        __syncthreads();
    }

    float Ac[8], Oc[8], Wc[8];
    #pragma unroll
    for (int m = 0; m < 2; ++m)
        #pragma unroll
        for (int reg = 0; reg < 4; ++reg) {
            int co = wave * 32 + m * 16 + quad * 4 + reg;
            float A = g1[co] * rsqrtf(v1[co] + 1e-5f);
            Ac[m * 4 + reg] = A;
            Oc[m * 4 + reg] = fmaf(b1[co] - m1[co], A, be1[co]);
            Wc[m * 4 + reg] = w2[co];
        }
    #pragma unroll
    for (int n = 0; n < 8; ++n) {
        float part = 0.0f;
        #pragma unroll
        for (int m = 0; m < 2; ++m)
            #pragma unroll
            for (int reg = 0; reg < 4; ++reg) {
                float y = fmaxf(fmaf(acc[m][n][reg], Ac[m * 4 + reg], Oc[m * 4 + reg]), 0.0f);
                part = fmaf(Wc[m * 4 + reg], y, part);
            }
        red[(n * 16 + l15) * 33 + wave * 4 + quad] = part;
    }
    __syncthreads();
    if (tid < 128) {
        float z = b2[0];
        #pragma unroll
        for (int k = 0; k < 32; ++k) z += red[tid * 33 + k];
        if (p0 + tid < Np)
            out[ooff + (size_t)b * Np + p0 + tid] = 1.0f / (1.0f + expf(-z));
    }
}

// ---------------------------------------------------------------------------
extern "C" void kernel_launch(void* const* d_in, const int* in_sizes, int n_in,
                              void* d_out, int out_size, void* d_ws, size_t ws_size,
                              hipStream_t stream)
{
    const float* large  = (const float*)d_in[0];
    const float* medium = (const float*)d_in[1];
    const float* small  = (const float*)d_in[2];
    const float* search = (const float*)d_in[3];
    const float* wt  = (const float*)d_in[4];
    const float* bt  = (const float*)d_in[5];
    const float* gt  = (const float*)d_in[6];
    const float* bet = (const float*)d_in[7];
    const float* mt  = (const float*)d_in[8];
    const float* vt  = (const float*)d_in[9];
    const float* wsc = (const float*)d_in[10];
    const float* bs  = (const float*)d_in[11];
    const float* gs  = (const float*)d_in[12];
    const float* bes = (const float*)d_in[13];
    const float* ms  = (const float*)d_in[14];
    const float* vs  = (const float*)d_in[15];
    const float* w1  = (const float*)d_in[16];
    const float* b1  = (const float*)d_in[17];
    const float* g1  = (const float*)d_in[18];
    const float* be1 = (const float*)d_in[19];
    const float* m1  = (const float*)d_in[20];
    const float* v1  = (const float*)d_in[21];
    const float* w2  = (const float*)d_in[22];
    const float* b2  = (const float*)d_in[23];

    float* ws = (float*)d_ws;
    size_t off = 0;
    float* lf = ws + off; off += (size_t)64 * 256 * 49;
    float* mf = ws + off; off += (size_t)64 * 256 * 25;
    float* sf = ws + off; off += (size_t)64 * 256 * 9;
    float* sq = ws + off; off += (size_t)64 * 256 * 841;
    // lc/mc/sc bf16 (regions keep fp32-sized reservations for aliasing)
    short* lc = (short*)(ws + off); off += (size_t)64 * 256 * 729;
    short* mc = (short*)(ws + off); off += (size_t)64 * 256 * 625;
    short* sc = (short*)(ws + off); off += (size_t)64 * 256 * 729;
    // w1 packed buffers: own region (no aliasing -> packed in prep_all)
    short* w1hT = (short*)(ws + off); off += 32768;
    short* w1lT = (short*)(ws + off); off += 32768;

    // Aliased prep buffers (dead before corr writes lc/mc/sc):
    short* xh_s = (short*)lc;
    short* base = (short*)sc;
    short* xh_L = base;
    short* xh_M = base + 2654208;
    short* xh_S = base + 4259840;
    short* wh_t = base + 5079040;
    short* wl_t = base + 5668864;
    short* wh_s = base + 6258688;
    short* wl_s = base + 6848512;

    dim3 blk(256);
    prep_all<<<dim3(5440), blk, 0, stream>>>(
        wt, wh_t, wl_t, wsc, wh_s, wl_s,
        search, xh_s, large, xh_L,
        medium, xh_M, small, xh_S,
        w1, w1hT, w1lT);

    conv_mfma_all<<<dim3(1280), blk, 0, stream>>>(
        xh_s, wh_s, bs, gs, bes, ms, vs, sq,
        xh_L, xh_M, xh_S, wh_t,
        bt, gt, bet, mt, vt, lf, mf, sf);

    corr_kernel<<<dim3(64, 64), blk, 0, stream>>>(lf, mf, sf, sq, lc, mc, sc);

    head_mfma_kernel<<<dim3(17, 64), dim3(512), 0, stream>>>(
        lc, mc, sc, w1hT, w1lT, b1, g1, be1, m1, v1, w2, b2, (float*)d_out);
}

// Round 21
// 396.235 us; speedup vs baseline: 1.1778x; 1.0115x over previous
//
#include <hip/hip_runtime.h>
#include <math.h>
#include <stdint.h>

typedef __attribute__((ext_vector_type(8))) short short8;
typedef __attribute__((ext_vector_type(4))) float floatx4;

// fp32 -> (bf16 hi | bf16 lo) packed u32.  hi = RNE(x), lo = RNE(x - hi).
__device__ __forceinline__ uint32_t pack_hilo(float x) {
    uint32_t u = __float_as_uint(x);
    uint32_t hi = (u + 0x7FFFu + ((u >> 16) & 1u)) & 0xFFFF0000u;
    float r = x - __uint_as_float(hi);
    uint32_t v = __float_as_uint(r);
    uint32_t lo = ((v + 0x7FFFu + ((v >> 16) & 1u)) >> 16) & 0xFFFFu;
    return hi | lo;
}

// fp32 -> bf16 (RNE), low 16 bits of result.
__device__ __forceinline__ uint32_t bf16rne(float x) {
    uint32_t u = __float_as_uint(x);
    return ((u + 0x7FFFu + ((u >> 16) & 1u)) >> 16) & 0xFFFFu;
}

// async global->LDS DMA, 16 B per lane; lds dest must be wave-uniform base.
__device__ __forceinline__ void dma16(short* lds, const short* g) {
    __builtin_amdgcn_global_load_lds(
        (const __attribute__((address_space(1))) unsigned int*)g,
        (__attribute__((address_space(3))) unsigned int*)lds,
        16, 0, 0);
}

// ---------------------------------------------------------------------------
// Merged prep: conv weights (blocks 0..255) + activations (256..5375) +
// w1 packing (5376..5439).
// ---------------------------------------------------------------------------
__global__ __launch_bounds__(256) void prep_all(
    const float* __restrict__ wA, short* __restrict__ whA, short* __restrict__ wlA,
    const float* __restrict__ wB, short* __restrict__ whB, short* __restrict__ wlB,
    const float* __restrict__ xs, short* __restrict__ xhS,
    const float* __restrict__ xL, short* __restrict__ xhL,
    const float* __restrict__ xM, short* __restrict__ xhM,
    const float* __restrict__ xSm, short* __restrict__ xhSm,
    const float* __restrict__ w1, short* __restrict__ w1hT, short* __restrict__ w1lT)
{
    const int blk = blockIdx.x;
    if (blk < 256) {
        // ---- weight prep: fetch-order layout.  Lane-linear A-fragments:
        // frag(tile, cob, lane) at ((tile)*16 + cob)*512 + lane*8  ----
        int bx = blk;
        const float* w; short *wh, *wl;
        if (bx < 128) { w = wA; wh = whA; wl = wlA; }
        else          { w = wB; wh = whB; wl = wlB; bx -= 128; }
        const int idx = bx * 256 + threadIdx.x;
        const int co = idx >> 7, jp = idx & 127;      // ci = 2*jp
        const int c4 = jp >> 4;                       // ci>>5
        const int g  = (jp >> 2) & 3;                 // (ci>>3)&3
        const int cw = 2 * (jp & 3);                  // ci&7
        const float* s0 = w + ((size_t)co * 256 + 2 * jp) * 9;
        #pragma unroll
        for (int r = 0; r < 9; ++r) {
            uint32_t q0 = pack_hilo(s0[r]);
            uint32_t q1 = pack_hilo(s0[9 + r]);
            size_t o = ((size_t)(r * 8 + c4) * 16 + (co >> 4)) * 512
                     + (size_t)(g * 16 + (co & 15)) * 8 + cw;
            *(uint32_t*)(wh + o) = (q0 >> 16) | (q1 & 0xFFFF0000u);
            *(uint32_t*)(wl + o) = (q0 & 0xFFFFu) | (q1 << 16);
        }
        return;
    }
    if (blk >= 5376) {
        // ---- w1 prep: granule-swizzled chunk-major hi/lo ----
        const int idx = ((blk - 5376) * 256 + threadIdx.x) * 4;
        const int co = idx >> 8, ci = idx & 255;
        const int pos = (ci >> 5) * 8192 + (co >> 4) * 512 + ((ci >> 3) & 3) * 128
                      + (co & 15) * 8 + (ci & 7);
        float4 v4 = *(const float4*)(w1 + (size_t)co * 256 + ci);
        uint32_t pa = pack_hilo(v4.x), pb = pack_hilo(v4.y);
        uint32_t pc = pack_hilo(v4.z), pd = pack_hilo(v4.w);
        uint2 uh, ul;
        uh.x = (pa >> 16) | (pb & 0xFFFF0000u);
        uh.y = (pc >> 16) | (pd & 0xFFFF0000u);
        ul.x = (pa & 0xFFFFu) | (pb << 16);
        ul.y = (pc & 0xFFFFu) | (pd << 16);
        *(uint2*)(w1hT + pos) = uh;
        *(uint2*)(w1lT + pos) = ul;
        return;
    }
    // ---- activation prep (bf16 hi only) ----
    const int i = blk - 256;            // 0..5119
    const int bx = i % 20;
    const int by = (i / 20) & 3;
    const int b  = i / 80;

    const float* x; short *xh; int HW, p0;
    if (bx < 16)      { x = xs;  xh = xhS;  HW = 961; p0 = bx * 64; }
    else if (bx < 18) { x = xL;  xh = xhL;  HW = 81;  p0 = (bx - 16) * 64; }
    else if (bx < 19) { x = xM;  xh = xhM;  HW = 49;  p0 = 0; }
    else              { x = xSm; xh = xhSm; HW = 25;  p0 = 0; }

    const int c0 = by * 64;
    const int tid = threadIdx.x;
    const int a = tid & 63, g = tid >> 6;
    __shared__ uint32_t t[64][65];
    #pragma unroll
    for (int ii = 0; ii < 16; ++ii) {
        int c = g + ii * 4;
        int p = p0 + a;
        float v = (p < HW) ? x[((size_t)(b * 256) + c0 + c) * HW + p] : 0.0f;
        t[c][a] = pack_hilo(v);
    }
    __syncthreads();
    const int j = tid & 31;
    const int gg = tid >> 5;
    #pragma unroll
    for (int ii = 0; ii < 8; ++ii) {
        int p = gg + ii * 8;
        if (p0 + p < HW) {
            uint32_t w0 = t[2 * j][p], w1v = t[2 * j + 1][p];
            size_t o = ((size_t)b * HW + p0 + p) * 256 + c0 + 2 * j;
            *(uint32_t*)(xh + o) = (w0 >> 16) | (w1v & 0xFFFF0000u);
        }
    }
}

// ===========================================================================
// MFMA conv body v11 (R18/R19-proven BEST: 1-term bf16 w x bf16 x, K=64
// phases, 4x8KB LDS, 72 barriers, A direct global->VGPR, vmcnt(4)
// discipline).  R20's 2co x 2p split regressed (doubled A L2-traffic
// outweighed halved B LDS-reads) — reverted.
// ===========================================================================
template<bool FULL>
__device__ __forceinline__ void conv_body(
    const short* __restrict__ xh,
    const short* __restrict__ wh,
    const float* __restrict__ bias,
    const float* __restrict__ gam, const float* __restrict__ bet,
    const float* __restrict__ mu,  const float* __restrict__ var,
    float* __restrict__ out,
    int b, int co0, int p0, int H, int W, short* smem)
{
    const int HW = H * W;
    const int Wo = W - 2, P = Wo * Wo;
    const int tid  = threadIdx.x;
    const int wave = tid >> 6, lane = tid & 63;
    const int l15  = lane & 15, quad = lane >> 4;

    int NT = 8;
    if (!FULL) {
        NT = (P - p0 + 15) >> 4;
        if (NT > 8) NT = 8;
    }

    // ---- A-fragment rolling global pointers (direct to VGPR) ----
    const int cob = (co0 >> 4) + wave * 2;
    const short* wA0 = wh + (size_t)cob * 512 + lane * 8;

    // ---- X staging (R2): coalesced rows + granule XOR ----
    const int lrow = lane >> 2;
    const int lci  = ((lane & 3) ^ ((lane >> 3) & 3)) * 8;
    int pr0 = p0 + wave * 32 + lrow;      if (pr0 >= P) pr0 = 0;
    int pr1 = p0 + wave * 32 + 16 + lrow; if (pr1 >= P) pr1 = 0;
    const size_t bbase0 = ((size_t)b * HW + (pr0 / Wo) * W + (pr0 % Wo)) * 256 + lci;
    const size_t bbase1 = ((size_t)b * HW + (pr1 / Wo) * W + (pr1 % Wo)) * 256 + lci;

    const short* xs0 = xh + bbase0;
    const short* xs1 = xh + bbase1;
    const int rowadv = (W - 2) * 256 - 224;

    const int ldsw = wave * 1024;
    const int fBB = l15 * 32 + ((quad ^ ((l15 >> 1) & 3)) * 8); // XOR-swizzled B

    floatx4 acc[2][8];
    #pragma unroll
    for (int s = 0; s < 2; ++s)
        #pragma unroll
        for (int t = 0; t < 8; ++t) acc[s][t] = (floatx4){0.f, 0.f, 0.f, 0.f};

    // LDS: 4 buffers x 4096 shorts (Xh only) = 32 KB
    int jn = 0;
    auto issueX = [&](int q) {          // one K=32 chunk into buffer q
        short* base = smem + q * 4096;
        dma16(base + ldsw,               xs0);
        dma16(base + ldsw + 512,         xs1);
        ++jn;
        const int adv = (jn % 24 == 0) ? rowadv : 32;
        xs0 += adv; xs1 += adv;
    };

    issueX(0);   // chunk 0
    issueX(1);   // chunk 1

    for (int ph = 0; ph < 36; ++ph) {
        const int c0q = (2 * ph) & 3;   // buffer of first chunk: 0 or 2
        // A(pair ph) issued FIRST: older than X(pair ph+1) in the vmcnt queue.
        short8 a0h = *(const short8*)(wA0);
        short8 a1h = *(const short8*)(wA0 + 512);
        short8 c0h = *(const short8*)(wA0 + 8192);
        short8 c1h = *(const short8*)(wA0 + 8704);
        wA0 += 16384;
        asm volatile("s_barrier" ::: "memory");            // pair p-1 compute done
        if (ph < 35) {
            issueX((c0q + 2) & 3);
            issueX((c0q + 3) & 3);
            asm volatile("s_waitcnt vmcnt(4)" ::: "memory"); // pair p + A done
        } else {
            asm volatile("s_waitcnt vmcnt(0)" ::: "memory");
        }
        asm volatile("s_barrier" ::: "memory");            // pair p visible
        const short* bq0 = smem + c0q * 4096;
        const short* bq1 = smem + ((c0q + 1) & 3) * 4096;
        __builtin_amdgcn_s_setprio(1);
        #pragma unroll
        for (int t = 0; t < 8; ++t) {
            if (FULL || t < NT) {
                short8 vh = *(const short8*)(bq0 + t * 512 + fBB);
                acc[0][t] = __builtin_amdgcn_mfma_f32_16x16x32_bf16(a0h, vh, acc[0][t], 0, 0, 0);
                acc[1][t] = __builtin_amdgcn_mfma_f32_16x16x32_bf16(a1h, vh, acc[1][t], 0, 0, 0);
            }
        }
        #pragma unroll
        for (int t = 0; t < 8; ++t) {
            if (FULL || t < NT) {
                short8 vh = *(const short8*)(bq1 + t * 512 + fBB);
                acc[0][t] = __builtin_amdgcn_mfma_f32_16x16x32_bf16(c0h, vh, acc[0][t], 0, 0, 0);
                acc[1][t] = __builtin_amdgcn_mfma_f32_16x16x32_bf16(c1h, vh, acc[1][t], 0, 0, 0);
            }
        }
        __builtin_amdgcn_s_setprio(0);
    }

    #pragma unroll
    for (int s = 0; s < 2; ++s) {
        const int cobase = co0 + wave * 32 + s * 16 + quad * 4;
        #pragma unroll
        for (int reg = 0; reg < 4; ++reg) {
            const int co = cobase + reg;
            const float A   = gam[co] * rsqrtf(var[co] + 1e-5f);
            const float OFF = fmaf(bias[co] - mu[co], A, bet[co]);
            float* orow = out + ((size_t)(b * 256 + co)) * P;
            #pragma unroll
            for (int t = 0; t < 8; ++t) {
                int px = p0 + t * 16 + l15;
                if ((FULL || t < NT) && px < P)
                    orow[px] = fmaxf(fmaf(acc[s][t][reg], A, OFF), 0.0f);
            }
        }
    }
}

// ---------------------------------------------------------------------------
// conv_mfma_all: search (blocks 0..895, XCD swizzle) + all 3 template scales
// (blocks 896..1279) in ONE dispatch.  32 KB LDS.
// ---------------------------------------------------------------------------
__global__ __launch_bounds__(256) void conv_mfma_all(
    const short* __restrict__ xh_s,
    const short* __restrict__ wh_s,
    const float* __restrict__ bs, const float* __restrict__ gs,
    const float* __restrict__ bes, const float* __restrict__ ms,
    const float* __restrict__ vs, float* __restrict__ sq,
    const short* __restrict__ xhL, const short* __restrict__ xhM,
    const short* __restrict__ xhS,
    const short* __restrict__ wh_t,
    const float* __restrict__ bt, const float* __restrict__ gt,
    const float* __restrict__ bet, const float* __restrict__ mt,
    const float* __restrict__ vt,
    float* __restrict__ lf, float* __restrict__ mf, float* __restrict__ sf)
{
    __shared__ __align__(16) short smem[16384];   // 4 x 4096-short X buffers
    const int i = blockIdx.x;
    if (i < 896) {
        const int xcd = i & 7, slot = i >> 3;
        const int bl = slot / 14, tile = slot - bl * 14;
        const int b = xcd * 8 + bl;
        const int cohalf = tile & 1, ptile = tile >> 1;
        if (ptile < 6)
            conv_body<true >(xh_s, wh_s, bs, gs, bes, ms, vs, sq,
                             b, cohalf * 128, ptile * 128, 31, 31, smem);
        else
            conv_body<false>(xh_s, wh_s, bs, gs, bes, ms, vs, sq,
                             b, cohalf * 128, ptile * 128, 31, 31, smem);
    } else {
        const int j = i - 896;                 // 0..383
        const int cohalf = j & 1, sb = j >> 1; // sb 0..191
        const int scale = sb >> 6, b = sb & 63;
        const short* xh = (scale == 0) ? xhL : (scale == 1) ? xhM : xhS;
        float* out      = (scale == 0) ? lf : (scale == 1) ? mf : sf;
        const int H     = (scale == 0) ? 9 : (scale == 1) ? 7 : 5;
        conv_body<false>(xh, wh_t, bt, gt, bet, mt, vt, out,
                         b, cohalf * 128, 0, H, H, smem);
    }
}

// ---------------------------------------------------------------------------
// corr v4 (R19-proven: transposed lane map + bf16 output). grid (64,64)
// ---------------------------------------------------------------------------
__global__ __launch_bounds__(256) void corr_kernel(
    const float* __restrict__ lf, const float* __restrict__ mf,
    const float* __restrict__ sf, const float* __restrict__ s,
    short* __restrict__ lc, short* __restrict__ mc, short* __restrict__ sc)
{
    const int b = blockIdx.y;
    const int wave = threadIdx.x >> 6, lane = threadIdx.x & 63;
    const int c = blockIdx.x * 4 + wave;
    const int bc = b * 256 + c;

    __shared__ __align__(16) float sp[4][33 * 36];
    __shared__ float tw[4][96];

    float* P = sp[wave];
    for (int i = lane; i < 33 * 36; i += 64) P[i] = 0.0f;
    if (lane < 49) tw[wave][lane]      = lf[(size_t)bc * 49 + lane];
    if (lane < 25) tw[wave][49 + lane] = mf[(size_t)bc * 25 + lane];
    if (lane < 9)  tw[wave][74 + lane] = sf[(size_t)bc * 9 + lane];
    for (int i = lane; i < 841; i += 64) {
        int y = i / 29, x = i - y * 29;
        P[(y + 2) * 36 + (x + 2)] = s[(size_t)bc * 841 + i];
    }
    __syncthreads();

    const int x = lane & 31;
    const int h = lane >> 5;

    // ---- lc: 7x7 kernel, 27x27 out, no offset ----
    {
        float t7[49];
        #pragma unroll
        for (int k = 0; k < 49; ++k) t7[k] = tw[wave][k];
        for (int pass = 0; pass < 4; ++pass) {
            const int ro = pass * 8 + h * 4;
            float a0 = 0, a1 = 0, a2 = 0, a3 = 0;
            #pragma unroll
            for (int ir = 0; ir < 10; ++ir) {
                int r = ro + ir; if (r > 32) r = 32;
                const float* rp = P + r * 36 + x;
                #pragma unroll
                for (int dx = 0; dx < 7; ++dx) {
                    float v = rp[dx];
                    if (ir <= 6)             a0 = fmaf(t7[ir * 7 + dx], v, a0);
                    if (ir >= 1 && ir <= 7)  a1 = fmaf(t7[(ir - 1) * 7 + dx], v, a1);
                    if (ir >= 2 && ir <= 8)  a2 = fmaf(t7[(ir - 2) * 7 + dx], v, a2);
                    if (ir >= 3)             a3 = fmaf(t7[(ir - 3) * 7 + dx], v, a3);
                }
            }
            if (x < 27) {
                size_t o = (size_t)bc * 729 + (size_t)ro * 27 + x;
                if (ro     < 27) lc[o]      = (short)bf16rne(a0);
                if (ro + 1 < 27) lc[o + 27] = (short)bf16rne(a1);
                if (ro + 2 < 27) lc[o + 54] = (short)bf16rne(a2);
                if (ro + 3 < 27) lc[o + 81] = (short)bf16rne(a3);
            }
        }
    }
    // ---- mc: 5x5 kernel, 25x25 out, +2 offset both dims ----
    {
        float t5[25];
        #pragma unroll
        for (int k = 0; k < 25; ++k) t5[k] = tw[wave][49 + k];
        for (int pass = 0; pass < 4; ++pass) {
            const int ro = pass * 8 + h * 4;
            float a0 = 0, a1 = 0, a2 = 0, a3 = 0;
            #pragma unroll
            for (int ir = 0; ir < 8; ++ir) {
                int r = ro + 2 + ir; if (r > 32) r = 32;
                const float* rp = P + r * 36 + x + 2;
                #pragma unroll
                for (int dx = 0; dx < 5; ++dx) {
                    float v = rp[dx];
                    if (ir <= 4)             a0 = fmaf(t5[ir * 5 + dx], v, a0);
                    if (ir >= 1 && ir <= 5)  a1 = fmaf(t5[(ir - 1) * 5 + dx], v, a1);
                    if (ir >= 2 && ir <= 6)  a2 = fmaf(t5[(ir - 2) * 5 + dx], v, a2);
                    if (ir >= 3)             a3 = fmaf(t5[(ir - 3) * 5 + dx], v, a3);
                }
            }
            if (x < 25) {
                size_t o = (size_t)bc * 625 + (size_t)ro * 25 + x;
                if (ro     < 25) mc[o]      = (short)bf16rne(a0);
                if (ro + 1 < 25) mc[o + 25] = (short)bf16rne(a1);
                if (ro + 2 < 25) mc[o + 50] = (short)bf16rne(a2);
                if (ro + 3 < 25) mc[o + 75] = (short)bf16rne(a3);
            }
        }
    }
    // ---- sc: 3x3 kernel, 27x27 out, +2 offset both dims ----
    {
        float t3[9];
        #pragma unroll
        for (int k = 0; k < 9; ++k) t3[k] = tw[wave][74 + k];
        for (int pass = 0; pass < 4; ++pass) {
            const int ro = pass * 8 + h * 4;
            float a0 = 0, a1 = 0, a2 = 0, a3 = 0;
            #pragma unroll
            for (int ir = 0; ir < 6; ++ir) {
                int r = ro + 2 + ir; if (r > 32) r = 32;
                const float* rp = P + r * 36 + x + 2;
                #pragma unroll
                for (int dx = 0; dx < 3; ++dx) {
                    float v = rp[dx];
                    if (ir <= 2)             a0 = fmaf(t3[ir * 3 + dx], v, a0);
                    if (ir >= 1 && ir <= 3)  a1 = fmaf(t3[(ir - 1) * 3 + dx], v, a1);
                    if (ir >= 2 && ir <= 4)  a2 = fmaf(t3[(ir - 2) * 3 + dx], v, a2);
                    if (ir >= 3)             a3 = fmaf(t3[(ir - 3) * 3 + dx], v, a3);
                }
            }
            if (x < 27) {
                size_t o = (size_t)bc * 729 + (size_t)ro * 27 + x;
                if (ro     < 27) sc[o]      = (short)bf16rne(a0);
                if (ro + 1 < 27) sc[o + 27] = (short)bf16rne(a1);
                if (ro + 2 < 27) sc[o + 54] = (short)bf16rne(a2);
                if (ro + 3 < 27) sc[o + 81] = (short)bf16rne(a3);
            }
        }
    }
}

// ---------------------------------------------------------------------------
// head v5b (R19-proven: R14 structure, bf16 B inputs). grid (17, 64).
// ---------------------------------------------------------------------------
__global__ __launch_bounds__(512, 4) void head_mfma_kernel(
    const short* __restrict__ lc, const short* __restrict__ mc,
    const short* __restrict__ sc,
    const short* __restrict__ w1hT, const short* __restrict__ w1lT,
    const float* __restrict__ b1,
    const float* __restrict__ g1, const float* __restrict__ be1,
    const float* __restrict__ m1, const float* __restrict__ v1,
    const float* __restrict__ w2, const float* __restrict__ b2,
    float* __restrict__ out)
{
    const int bx = blockIdx.x;
    const short* X; int Np, ooff, p0;
    if (bx < 6)       { X = lc; Np = 729; ooff = 0;     p0 = bx * 128; }
    else if (bx < 11) { X = mc; Np = 625; ooff = 46656; p0 = (bx - 6) * 128; }
    else              { X = sc; Np = 729; ooff = 86656; p0 = (bx - 11) * 128; }

    const int b  = blockIdx.y;
    const int tid = threadIdx.x;
    const int wave = tid >> 6, lane = tid & 63;   // wave 0..7
    const int l15 = lane & 15, quad = lane >> 4;

    __shared__ __align__(16) short Ah[256 * 32], Al[256 * 32];
    __shared__ __align__(16) short Bh[128 * 42];
    __shared__ float red[128 * 33];

    floatx4 acc[2][8];
    #pragma unroll
    for (int m = 0; m < 2; ++m)
        #pragma unroll
        for (int n = 0; n < 8; ++n) acc[m][n] = (floatx4){0.f, 0.f, 0.f, 0.f};

    const int pxq = tid & 31;      // p-quad: p = pxq*4 + j  (0..127)
    const int cp  = tid >> 5;      // 0..15: channels (2cp, 2cp+1) of 32-chunk

    for (int k0 = 0; k0 < 256; k0 += 32) {
        {
            const int kc = k0 >> 5;
            const short* srcH = w1hT + kc * 8192 + wave * 1024 + lane * 8;
            const short* srcL = w1lT + kc * 8192 + wave * 1024 + lane * 8;
            dma16(Ah + wave * 1024,       srcH);
            dma16(Ah + wave * 1024 + 512, srcH + 512);
            dma16(Al + wave * 1024,       srcL);
            dma16(Al + wave * 1024 + 512, srcL + 512);
        }
        {
            const int pxl = pxq * 4;
            const int gp = p0 + pxl;
            const short* r0 = X + ((size_t)(b * 256) + k0 + 2 * cp) * Np + gp;
            const short* r1 = r0 + Np;
            #pragma unroll
            for (int j = 0; j < 4; ++j) {
                uint32_t u = (gp + j < Np) ? (uint32_t)(uint16_t)r0[j] : 0u;
                uint32_t v = (gp + j < Np) ? (uint32_t)(uint16_t)r1[j] : 0u;
                int o = (pxl + j) * 42 + 2 * cp;
                *(uint32_t*)(Bh + o) = u | (v << 16);
            }
        }
        __syncthreads();
        short8 amh[2], aml[2];
        #pragma unroll
        for (int m = 0; m < 2; ++m) {
            int ao = (wave * 2 + m) * 512 + lane * 8;   // lane-linear
            amh[m] = *(const short8*)(Ah + ao);
            aml[m] = *(const short8*)(Al + ao);
        }
        __builtin_amdgcn_s_setprio(1);
        #pragma unroll
        for (int n = 0; n < 8; ++n) {
            int bo = (n * 16 + l15) * 42 + quad * 8;
            short8 bh = *(const short8*)(Bh + bo);
            #pragma unroll
            for (int m = 0; m < 2; ++m) {
                acc[m][n] = __builtin_amdgcn_mfma_f32_16x16x32_bf16(amh[m], bh, acc[m][n], 0, 0, 0);
                acc[m][n] = __builtin_amdgcn_mfma_f32_16x16x32_bf16(aml[m], bh, acc[m][n], 0, 0, 0);
            }
        }
        __builtin_amdgcn_s_setprio(0);
        __syncthreads();
    }

    float Ac[8], Oc[8], Wc[8];
    #pragma unroll
    for (int m = 0; m < 2; ++m)
        #pragma unroll
        for (int reg = 0; reg < 4; ++reg) {
            int co = wave * 32 + m * 16 + quad * 4 + reg;
            float A = g1[co] * rsqrtf(v1[co] + 1e-5f);
            Ac[m * 4 + reg] = A;
            Oc[m * 4 + reg] = fmaf(b1[co] - m1[co], A, be1[co]);
            Wc[m * 4 + reg] = w2[co];
        }
    #pragma unroll
    for (int n = 0; n < 8; ++n) {
        float part = 0.0f;
        #pragma unroll
        for (int m = 0; m < 2; ++m)
            #pragma unroll
            for (int reg = 0; reg < 4; ++reg) {
                float y = fmaxf(fmaf(acc[m][n][reg], Ac[m * 4 + reg], Oc[m * 4 + reg]), 0.0f);
                part = fmaf(Wc[m * 4 + reg], y, part);
            }
        red[(n * 16 + l15) * 33 + wave * 4 + quad] = part;
    }
    __syncthreads();
    if (tid < 128) {
        float z = b2[0];
        #pragma unroll
        for (int k = 0; k < 32; ++k) z += red[tid * 33 + k];
        if (p0 + tid < Np)
            out[ooff + (size_t)b * Np + p0 + tid] = 1.0f / (1.0f + expf(-z));
    }
}

// ---------------------------------------------------------------------------
extern "C" void kernel_launch(void* const* d_in, const int* in_sizes, int n_in,
                              void* d_out, int out_size, void* d_ws, size_t ws_size,
                              hipStream_t stream)
{
    const float* large  = (const float*)d_in[0];
    const float* medium = (const float*)d_in[1];
    const float* small  = (const float*)d_in[2];
    const float* search = (const float*)d_in[3];
    const float* wt  = (const float*)d_in[4];
    const float* bt  = (const float*)d_in[5];
    const float* gt  = (const float*)d_in[6];
    const float* bet = (const float*)d_in[7];
    const float* mt  = (const float*)d_in[8];
    const float* vt  = (const float*)d_in[9];
    const float* wsc = (const float*)d_in[10];
    const float* bs  = (const float*)d_in[11];
    const float* gs  = (const float*)d_in[12];
    const float* bes = (const float*)d_in[13];
    const float* ms  = (const float*)d_in[14];
    const float* vs  = (const float*)d_in[15];
    const float* w1  = (const float*)d_in[16];
    const float* b1  = (const float*)d_in[17];
    const float* g1  = (const float*)d_in[18];
    const float* be1 = (const float*)d_in[19];
    const float* m1  = (const float*)d_in[20];
    const float* v1  = (const float*)d_in[21];
    const float* w2  = (const float*)d_in[22];
    const float* b2  = (const float*)d_in[23];

    float* ws = (float*)d_ws;
    size_t off = 0;
    float* lf = ws + off; off += (size_t)64 * 256 * 49;
    float* mf = ws + off; off += (size_t)64 * 256 * 25;
    float* sf = ws + off; off += (size_t)64 * 256 * 9;
    float* sq = ws + off; off += (size_t)64 * 256 * 841;
    // lc/mc/sc bf16 (regions keep fp32-sized reservations for aliasing)
    short* lc = (short*)(ws + off); off += (size_t)64 * 256 * 729;
    short* mc = (short*)(ws + off); off += (size_t)64 * 256 * 625;
    short* sc = (short*)(ws + off); off += (size_t)64 * 256 * 729;
    // w1 packed buffers: own region (no aliasing -> packed in prep_all)
    short* w1hT = (short*)(ws + off); off += 32768;
    short* w1lT = (short*)(ws + off); off += 32768;

    // Aliased prep buffers (dead before corr writes lc/mc/sc):
    short* xh_s = (short*)lc;
    short* base = (short*)sc;
    short* xh_L = base;
    short* xh_M = base + 2654208;
    short* xh_S = base + 4259840;
    short* wh_t = base + 5079040;
    short* wl_t = base + 5668864;
    short* wh_s = base + 6258688;
    short* wl_s = base + 6848512;

    dim3 blk(256);
    prep_all<<<dim3(5440), blk, 0, stream>>>(
        wt, wh_t, wl_t, wsc, wh_s, wl_s,
        search, xh_s, large, xh_L,
        medium, xh_M, small, xh_S,
        w1, w1hT, w1lT);

    conv_mfma_all<<<dim3(1280), blk, 0, stream>>>(
        xh_s, wh_s, bs, gs, bes, ms, vs, sq,
        xh_L, xh_M, xh_S, wh_t,
        bt, gt, bet, mt, vt, lf, mf, sf);

    corr_kernel<<<dim3(64, 64), blk, 0, stream>>>(lf, mf, sf, sq, lc, mc, sc);

    head_mfma_kernel<<<dim3(17, 64), dim3(512), 0, stream>>>(
        lc, mc, sc, w1hT, w1lT, b1, g1, be1, m1, v1, w2, b2, (float*)d_out);
}

// Round 22
// 388.611 us; speedup vs baseline: 1.2009x; 1.0196x over previous
//
#include <hip/hip_runtime.h>
#include <math.h>
#include <stdint.h>

typedef __attribute__((ext_vector_type(8))) short short8;
typedef __attribute__((ext_vector_type(4))) float floatx4;

// fp32 -> (bf16 hi | bf16 lo) packed u32.  hi = RNE(x), lo = RNE(x - hi).
__device__ __forceinline__ uint32_t pack_hilo(float x) {
    uint32_t u = __float_as_uint(x);
    uint32_t hi = (u + 0x7FFFu + ((u >> 16) & 1u)) & 0xFFFF0000u;
    float r = x - __uint_as_float(hi);
    uint32_t v = __float_as_uint(r);
    uint32_t lo = ((v + 0x7FFFu + ((v >> 16) & 1u)) >> 16) & 0xFFFFu;
    return hi | lo;
}

// fp32 -> bf16 (RNE), low 16 bits of result.
__device__ __forceinline__ uint32_t bf16rne(float x) {
    uint32_t u = __float_as_uint(x);
    return ((u + 0x7FFFu + ((u >> 16) & 1u)) >> 16) & 0xFFFFu;
}

// async global->LDS DMA, 16 B per lane; lds dest must be wave-uniform base.
__device__ __forceinline__ void dma16(short* lds, const short* g) {
    __builtin_amdgcn_global_load_lds(
        (const __attribute__((address_space(1))) unsigned int*)g,
        (__attribute__((address_space(3))) unsigned int*)lds,
        16, 0, 0);
}

// ---------------------------------------------------------------------------
// Merged prep: conv weights (blocks 0..255) + activations (256..5375) +
// w1 packing (5376..5439).  w1 now bf16-hi ONLY (R22: head 1-term).
// ---------------------------------------------------------------------------
__global__ __launch_bounds__(256) void prep_all(
    const float* __restrict__ wA, short* __restrict__ whA, short* __restrict__ wlA,
    const float* __restrict__ wB, short* __restrict__ whB, short* __restrict__ wlB,
    const float* __restrict__ xs, short* __restrict__ xhS,
    const float* __restrict__ xL, short* __restrict__ xhL,
    const float* __restrict__ xM, short* __restrict__ xhM,
    const float* __restrict__ xSm, short* __restrict__ xhSm,
    const float* __restrict__ w1, short* __restrict__ w1hT)
{
    const int blk = blockIdx.x;
    if (blk < 256) {
        // ---- weight prep: fetch-order layout.  Lane-linear A-fragments:
        // frag(tile, cob, lane) at ((tile)*16 + cob)*512 + lane*8  ----
        int bx = blk;
        const float* w; short *wh, *wl;
        if (bx < 128) { w = wA; wh = whA; wl = wlA; }
        else          { w = wB; wh = whB; wl = wlB; bx -= 128; }
        const int idx = bx * 256 + threadIdx.x;
        const int co = idx >> 7, jp = idx & 127;      // ci = 2*jp
        const int c4 = jp >> 4;                       // ci>>5
        const int g  = (jp >> 2) & 3;                 // (ci>>3)&3
        const int cw = 2 * (jp & 3);                  // ci&7
        const float* s0 = w + ((size_t)co * 256 + 2 * jp) * 9;
        #pragma unroll
        for (int r = 0; r < 9; ++r) {
            uint32_t q0 = pack_hilo(s0[r]);
            uint32_t q1 = pack_hilo(s0[9 + r]);
            size_t o = ((size_t)(r * 8 + c4) * 16 + (co >> 4)) * 512
                     + (size_t)(g * 16 + (co & 15)) * 8 + cw;
            *(uint32_t*)(wh + o) = (q0 >> 16) | (q1 & 0xFFFF0000u);
            *(uint32_t*)(wl + o) = (q0 & 0xFFFFu) | (q1 << 16);
        }
        return;
    }
    if (blk >= 5376) {
        // ---- w1 prep: granule-swizzled chunk-major, bf16-hi only ----
        const int idx = ((blk - 5376) * 256 + threadIdx.x) * 4;
        const int co = idx >> 8, ci = idx & 255;
        const int pos = (ci >> 5) * 8192 + (co >> 4) * 512 + ((ci >> 3) & 3) * 128
                      + (co & 15) * 8 + (ci & 7);
        float4 v4 = *(const float4*)(w1 + (size_t)co * 256 + ci);
        uint2 uh;
        uh.x = bf16rne(v4.x) | (bf16rne(v4.y) << 16);
        uh.y = bf16rne(v4.z) | (bf16rne(v4.w) << 16);
        *(uint2*)(w1hT + pos) = uh;
        return;
    }
    // ---- activation prep (bf16 hi only) ----
    const int i = blk - 256;            // 0..5119
    const int bx = i % 20;
    const int by = (i / 20) & 3;
    const int b  = i / 80;

    const float* x; short *xh; int HW, p0;
    if (bx < 16)      { x = xs;  xh = xhS;  HW = 961; p0 = bx * 64; }
    else if (bx < 18) { x = xL;  xh = xhL;  HW = 81;  p0 = (bx - 16) * 64; }
    else if (bx < 19) { x = xM;  xh = xhM;  HW = 49;  p0 = 0; }
    else              { x = xSm; xh = xhSm; HW = 25;  p0 = 0; }

    const int c0 = by * 64;
    const int tid = threadIdx.x;
    const int a = tid & 63, g = tid >> 6;
    __shared__ uint32_t t[64][65];
    #pragma unroll
    for (int ii = 0; ii < 16; ++ii) {
        int c = g + ii * 4;
        int p = p0 + a;
        float v = (p < HW) ? x[((size_t)(b * 256) + c0 + c) * HW + p] : 0.0f;
        t[c][a] = pack_hilo(v);
    }
    __syncthreads();
    const int j = tid & 31;
    const int gg = tid >> 5;
    #pragma unroll
    for (int ii = 0; ii < 8; ++ii) {
        int p = gg + ii * 8;
        if (p0 + p < HW) {
            uint32_t w0 = t[2 * j][p], w1v = t[2 * j + 1][p];
            size_t o = ((size_t)b * HW + p0 + p) * 256 + c0 + 2 * j;
            *(uint32_t*)(xh + o) = (w0 >> 16) | (w1v & 0xFFFF0000u);
        }
    }
}

// ===========================================================================
// MFMA conv body v11 (R18/R19/R21-proven BEST: 1-term bf16 w x bf16 x, K=64
// phases, 4x8KB LDS, 72 barriers, A direct global->VGPR, vmcnt(4)
// discipline).
// ===========================================================================
template<bool FULL>
__device__ __forceinline__ void conv_body(
    const short* __restrict__ xh,
    const short* __restrict__ wh,
    const float* __restrict__ bias,
    const float* __restrict__ gam, const float* __restrict__ bet,
    const float* __restrict__ mu,  const float* __restrict__ var,
    float* __restrict__ out,
    int b, int co0, int p0, int H, int W, short* smem)
{
    const int HW = H * W;
    const int Wo = W - 2, P = Wo * Wo;
    const int tid  = threadIdx.x;
    const int wave = tid >> 6, lane = tid & 63;
    const int l15  = lane & 15, quad = lane >> 4;

    int NT = 8;
    if (!FULL) {
        NT = (P - p0 + 15) >> 4;
        if (NT > 8) NT = 8;
    }

    // ---- A-fragment rolling global pointers (direct to VGPR) ----
    const int cob = (co0 >> 4) + wave * 2;
    const short* wA0 = wh + (size_t)cob * 512 + lane * 8;

    // ---- X staging (R2): coalesced rows + granule XOR ----
    const int lrow = lane >> 2;
    const int lci  = ((lane & 3) ^ ((lane >> 3) & 3)) * 8;
    int pr0 = p0 + wave * 32 + lrow;      if (pr0 >= P) pr0 = 0;
    int pr1 = p0 + wave * 32 + 16 + lrow; if (pr1 >= P) pr1 = 0;
    const size_t bbase0 = ((size_t)b * HW + (pr0 / Wo) * W + (pr0 % Wo)) * 256 + lci;
    const size_t bbase1 = ((size_t)b * HW + (pr1 / Wo) * W + (pr1 % Wo)) * 256 + lci;

    const short* xs0 = xh + bbase0;
    const short* xs1 = xh + bbase1;
    const int rowadv = (W - 2) * 256 - 224;

    const int ldsw = wave * 1024;
    const int fBB = l15 * 32 + ((quad ^ ((l15 >> 1) & 3)) * 8); // XOR-swizzled B

    floatx4 acc[2][8];
    #pragma unroll
    for (int s = 0; s < 2; ++s)
        #pragma unroll
        for (int t = 0; t < 8; ++t) acc[s][t] = (floatx4){0.f, 0.f, 0.f, 0.f};

    // LDS: 4 buffers x 4096 shorts (Xh only) = 32 KB
    int jn = 0;
    auto issueX = [&](int q) {          // one K=32 chunk into buffer q
        short* base = smem + q * 4096;
        dma16(base + ldsw,               xs0);
        dma16(base + ldsw + 512,         xs1);
        ++jn;
        const int adv = (jn % 24 == 0) ? rowadv : 32;
        xs0 += adv; xs1 += adv;
    };

    issueX(0);   // chunk 0
    issueX(1);   // chunk 1

    for (int ph = 0; ph < 36; ++ph) {
        const int c0q = (2 * ph) & 3;   // buffer of first chunk: 0 or 2
        // A(pair ph) issued FIRST: older than X(pair ph+1) in the vmcnt queue.
        short8 a0h = *(const short8*)(wA0);
        short8 a1h = *(const short8*)(wA0 + 512);
        short8 c0h = *(const short8*)(wA0 + 8192);
        short8 c1h = *(const short8*)(wA0 + 8704);
        wA0 += 16384;
        asm volatile("s_barrier" ::: "memory");            // pair p-1 compute done
        if (ph < 35) {
            issueX((c0q + 2) & 3);
            issueX((c0q + 3) & 3);
            asm volatile("s_waitcnt vmcnt(4)" ::: "memory"); // pair p + A done
        } else {
            asm volatile("s_waitcnt vmcnt(0)" ::: "memory");
        }
        asm volatile("s_barrier" ::: "memory");            // pair p visible
        const short* bq0 = smem + c0q * 4096;
        const short* bq1 = smem + ((c0q + 1) & 3) * 4096;
        __builtin_amdgcn_s_setprio(1);
        #pragma unroll
        for (int t = 0; t < 8; ++t) {
            if (FULL || t < NT) {
                short8 vh = *(const short8*)(bq0 + t * 512 + fBB);
                acc[0][t] = __builtin_amdgcn_mfma_f32_16x16x32_bf16(a0h, vh, acc[0][t], 0, 0, 0);
                acc[1][t] = __builtin_amdgcn_mfma_f32_16x16x32_bf16(a1h, vh, acc[1][t], 0, 0, 0);
            }
        }
        #pragma unroll
        for (int t = 0; t < 8; ++t) {
            if (FULL || t < NT) {
                short8 vh = *(const short8*)(bq1 + t * 512 + fBB);
                acc[0][t] = __builtin_amdgcn_mfma_f32_16x16x32_bf16(c0h, vh, acc[0][t], 0, 0, 0);
                acc[1][t] = __builtin_amdgcn_mfma_f32_16x16x32_bf16(c1h, vh, acc[1][t], 0, 0, 0);
            }
        }
        __builtin_amdgcn_s_setprio(0);
    }

    #pragma unroll
    for (int s = 0; s < 2; ++s) {
        const int cobase = co0 + wave * 32 + s * 16 + quad * 4;
        #pragma unroll
        for (int reg = 0; reg < 4; ++reg) {
            const int co = cobase + reg;
            const float A   = gam[co] * rsqrtf(var[co] + 1e-5f);
            const float OFF = fmaf(bias[co] - mu[co], A, bet[co]);
            float* orow = out + ((size_t)(b * 256 + co)) * P;
            #pragma unroll
            for (int t = 0; t < 8; ++t) {
                int px = p0 + t * 16 + l15;
                if ((FULL || t < NT) && px < P)
                    orow[px] = fmaxf(fmaf(acc[s][t][reg], A, OFF), 0.0f);
            }
        }
    }
}

// ---------------------------------------------------------------------------
// conv_mfma_all: search (blocks 0..895, XCD swizzle) + all 3 template scales
// (blocks 896..1279) in ONE dispatch.  32 KB LDS.
// ---------------------------------------------------------------------------
__global__ __launch_bounds__(256) void conv_mfma_all(
    const short* __restrict__ xh_s,
    const short* __restrict__ wh_s,
    const float* __restrict__ bs, const float* __restrict__ gs,
    const float* __restrict__ bes, const float* __restrict__ ms,
    const float* __restrict__ vs, float* __restrict__ sq,
    const short* __restrict__ xhL, const short* __restrict__ xhM,
    const short* __restrict__ xhS,
    const short* __restrict__ wh_t,
    const float* __restrict__ bt, const float* __restrict__ gt,
    const float* __restrict__ bet, const float* __restrict__ mt,
    const float* __restrict__ vt,
    float* __restrict__ lf, float* __restrict__ mf, float* __restrict__ sf)
{
    __shared__ __align__(16) short smem[16384];   // 4 x 4096-short X buffers
    const int i = blockIdx.x;
    if (i < 896) {
        const int xcd = i & 7, slot = i >> 3;
        const int bl = slot / 14, tile = slot - bl * 14;
        const int b = xcd * 8 + bl;
        const int cohalf = tile & 1, ptile = tile >> 1;
        if (ptile < 6)
            conv_body<true >(xh_s, wh_s, bs, gs, bes, ms, vs, sq,
                             b, cohalf * 128, ptile * 128, 31, 31, smem);
        else
            conv_body<false>(xh_s, wh_s, bs, gs, bes, ms, vs, sq,
                             b, cohalf * 128, ptile * 128, 31, 31, smem);
    } else {
        const int j = i - 896;                 // 0..383
        const int cohalf = j & 1, sb = j >> 1; // sb 0..191
        const int scale = sb >> 6, b = sb & 63;
        const short* xh = (scale == 0) ? xhL : (scale == 1) ? xhM : xhS;
        float* out      = (scale == 0) ? lf : (scale == 1) ? mf : sf;
        const int H     = (scale == 0) ? 9 : (scale == 1) ? 7 : 5;
        conv_body<false>(xh, wh_t, bt, gt, bet, mt, vt, out,
                         b, cohalf * 128, 0, H, H, smem);
    }
}

// ---------------------------------------------------------------------------
// corr v4 (R19-proven: transposed lane map + bf16 output). grid (64,64)
// ---------------------------------------------------------------------------
__global__ __launch_bounds__(256) void corr_kernel(
    const float* __restrict__ lf, const float* __restrict__ mf,
    const float* __restrict__ sf, const float* __restrict__ s,
    short* __restrict__ lc, short* __restrict__ mc, short* __restrict__ sc)
{
    const int b = blockIdx.y;
    const int wave = threadIdx.x >> 6, lane = threadIdx.x & 63;
    const int c = blockIdx.x * 4 + wave;
    const int bc = b * 256 + c;

    __shared__ __align__(16) float sp[4][33 * 36];
    __shared__ float tw[4][96];

    float* P = sp[wave];
    for (int i = lane; i < 33 * 36; i += 64) P[i] = 0.0f;
    if (lane < 49) tw[wave][lane]      = lf[(size_t)bc * 49 + lane];
    if (lane < 25) tw[wave][49 + lane] = mf[(size_t)bc * 25 + lane];
    if (lane < 9)  tw[wave][74 + lane] = sf[(size_t)bc * 9 + lane];
    for (int i = lane; i < 841; i += 64) {
        int y = i / 29, x = i - y * 29;
        P[(y + 2) * 36 + (x + 2)] = s[(size_t)bc * 841 + i];
    }
    __syncthreads();

    const int x = lane & 31;
    const int h = lane >> 5;

    // ---- lc: 7x7 kernel, 27x27 out, no offset ----
    {
        float t7[49];
        #pragma unroll
        for (int k = 0; k < 49; ++k) t7[k] = tw[wave][k];
        for (int pass = 0; pass < 4; ++pass) {
            const int ro = pass * 8 + h * 4;
            float a0 = 0, a1 = 0, a2 = 0, a3 = 0;
            #pragma unroll
            for (int ir = 0; ir < 10; ++ir) {
                int r = ro + ir; if (r > 32) r = 32;
                const float* rp = P + r * 36 + x;
                #pragma unroll
                for (int dx = 0; dx < 7; ++dx) {
                    float v = rp[dx];
                    if (ir <= 6)             a0 = fmaf(t7[ir * 7 + dx], v, a0);
                    if (ir >= 1 && ir <= 7)  a1 = fmaf(t7[(ir - 1) * 7 + dx], v, a1);
                    if (ir >= 2 && ir <= 8)  a2 = fmaf(t7[(ir - 2) * 7 + dx], v, a2);
                    if (ir >= 3)             a3 = fmaf(t7[(ir - 3) * 7 + dx], v, a3);
                }
            }
            if (x < 27) {
                size_t o = (size_t)bc * 729 + (size_t)ro * 27 + x;
                if (ro     < 27) lc[o]      = (short)bf16rne(a0);
                if (ro + 1 < 27) lc[o + 27] = (short)bf16rne(a1);
                if (ro + 2 < 27) lc[o + 54] = (short)bf16rne(a2);
                if (ro + 3 < 27) lc[o + 81] = (short)bf16rne(a3);
            }
        }
    }
    // ---- mc: 5x5 kernel, 25x25 out, +2 offset both dims ----
    {
        float t5[25];
        #pragma unroll
        for (int k = 0; k < 25; ++k) t5[k] = tw[wave][49 + k];
        for (int pass = 0; pass < 4; ++pass) {
            const int ro = pass * 8 + h * 4;
            float a0 = 0, a1 = 0, a2 = 0, a3 = 0;
            #pragma unroll
            for (int ir = 0; ir < 8; ++ir) {
                int r = ro + 2 + ir; if (r > 32) r = 32;
                const float* rp = P + r * 36 + x + 2;
                #pragma unroll
                for (int dx = 0; dx < 5; ++dx) {
                    float v = rp[dx];
                    if (ir <= 4)             a0 = fmaf(t5[ir * 5 + dx], v, a0);
                    if (ir >= 1 && ir <= 5)  a1 = fmaf(t5[(ir - 1) * 5 + dx], v, a1);
                    if (ir >= 2 && ir <= 6)  a2 = fmaf(t5[(ir - 2) * 5 + dx], v, a2);
                    if (ir >= 3)             a3 = fmaf(t5[(ir - 3) * 5 + dx], v, a3);
                }
            }
            if (x < 25) {
                size_t o = (size_t)bc * 625 + (size_t)ro * 25 + x;
                if (ro     < 25) mc[o]      = (short)bf16rne(a0);
                if (ro + 1 < 25) mc[o + 25] = (short)bf16rne(a1);
                if (ro + 2 < 25) mc[o + 50] = (short)bf16rne(a2);
                if (ro + 3 < 25) mc[o + 75] = (short)bf16rne(a3);
            }
        }
    }
    // ---- sc: 3x3 kernel, 27x27 out, +2 offset both dims ----
    {
        float t3[9];
        #pragma unroll
        for (int k = 0; k < 9; ++k) t3[k] = tw[wave][74 + k];
        for (int pass = 0; pass < 4; ++pass) {
            const int ro = pass * 8 + h * 4;
            float a0 = 0, a1 = 0, a2 = 0, a3 = 0;
            #pragma unroll
            for (int ir = 0; ir < 6; ++ir) {
                int r = ro + 2 + ir; if (r > 32) r = 32;
                const float* rp = P + r * 36 + x + 2;
                #pragma unroll
                for (int dx = 0; dx < 3; ++dx) {
                    float v = rp[dx];
                    if (ir <= 2)             a0 = fmaf(t3[ir * 3 + dx], v, a0);
                    if (ir >= 1 && ir <= 3)  a1 = fmaf(t3[(ir - 1) * 3 + dx], v, a1);
                    if (ir >= 2 && ir <= 4)  a2 = fmaf(t3[(ir - 2) * 3 + dx], v, a2);
                    if (ir >= 3)             a3 = fmaf(t3[(ir - 3) * 3 + dx], v, a3);
                }
            }
            if (x < 27) {
                size_t o = (size_t)bc * 729 + (size_t)ro * 27 + x;
                if (ro     < 27) sc[o]      = (short)bf16rne(a0);
                if (ro + 1 < 27) sc[o + 27] = (short)bf16rne(a1);
                if (ro + 2 < 27) sc[o + 54] = (short)bf16rne(a2);
                if (ro + 3 < 27) sc[o + 81] = (short)bf16rne(a3);
            }
        }
    }
}

// ---------------------------------------------------------------------------
// head v7: R14/R19 structure with 1-TERM W1 (bf16-hi only — same numerics
// move R18 proved free in conv).  Per k0-iter: 2 A-DMAs (was 4), 16 MFMA
// (was 32), LDS 60 -> 44 KB.  B path, MFMA mapping, epilogue unchanged.
// grid (17, 64).
// ---------------------------------------------------------------------------
__global__ __launch_bounds__(512, 4) void head_mfma_kernel(
    const short* __restrict__ lc, const short* __restrict__ mc,
    const short* __restrict__ sc,
    const short* __restrict__ w1hT,
    const float* __restrict__ b1,
    const float* __restrict__ g1, const float* __restrict__ be1,
    const float* __restrict__ m1, const float* __restrict__ v1,
    const float* __restrict__ w2, const float* __restrict__ b2,
    float* __restrict__ out)
{
    const int bx = blockIdx.x;
    const short* X; int Np, ooff, p0;
    if (bx < 6)       { X = lc; Np = 729; ooff = 0;     p0 = bx * 128; }
    else if (bx < 11) { X = mc; Np = 625; ooff = 46656; p0 = (bx - 6) * 128; }
    else              { X = sc; Np = 729; ooff = 86656; p0 = (bx - 11) * 128; }

    const int b  = blockIdx.y;
    const int tid = threadIdx.x;
    const int wave = tid >> 6, lane = tid & 63;   // wave 0..7
    const int l15 = lane & 15, quad = lane >> 4;

    __shared__ __align__(16) short Ah[256 * 32];
    __shared__ __align__(16) short Bh[128 * 42];
    __shared__ float red[128 * 33];

    floatx4 acc[2][8];
    #pragma unroll
    for (int m = 0; m < 2; ++m)
        #pragma unroll
        for (int n = 0; n < 8; ++n) acc[m][n] = (floatx4){0.f, 0.f, 0.f, 0.f};

    const int pxq = tid & 31;      // p-quad: p = pxq*4 + j  (0..127)
    const int cp  = tid >> 5;      // 0..15: channels (2cp, 2cp+1) of 32-chunk

    for (int k0 = 0; k0 < 256; k0 += 32) {
        {
            const int kc = k0 >> 5;
            const short* srcH = w1hT + kc * 8192 + wave * 1024 + lane * 8;
            dma16(Ah + wave * 1024,       srcH);
            dma16(Ah + wave * 1024 + 512, srcH + 512);
        }
        {
            const int pxl = pxq * 4;
            const int gp = p0 + pxl;
            const short* r0 = X + ((size_t)(b * 256) + k0 + 2 * cp) * Np + gp;
            const short* r1 = r0 + Np;
            #pragma unroll
            for (int j = 0; j < 4; ++j) {
                uint32_t u = (gp + j < Np) ? (uint32_t)(uint16_t)r0[j] : 0u;
                uint32_t v = (gp + j < Np) ? (uint32_t)(uint16_t)r1[j] : 0u;
                int o = (pxl + j) * 42 + 2 * cp;
                *(uint32_t*)(Bh + o) = u | (v << 16);
            }
        }
        __syncthreads();
        short8 amh[2];
        #pragma unroll
        for (int m = 0; m < 2; ++m) {
            int ao = (wave * 2 + m) * 512 + lane * 8;   // lane-linear
            amh[m] = *(const short8*)(Ah + ao);
        }
        __builtin_amdgcn_s_setprio(1);
        #pragma unroll
        for (int n = 0; n < 8; ++n) {
            int bo = (n * 16 + l15) * 42 + quad * 8;
            short8 bh = *(const short8*)(Bh + bo);
            #pragma unroll
            for (int m = 0; m < 2; ++m) {
                acc[m][n] = __builtin_amdgcn_mfma_f32_16x16x32_bf16(amh[m], bh, acc[m][n], 0, 0, 0);
            }
        }
        __builtin_amdgcn_s_setprio(0);
        __syncthreads();
    }

    float Ac[8], Oc[8], Wc[8];
    #pragma unroll
    for (int m = 0; m < 2; ++m)
        #pragma unroll
        for (int reg = 0; reg < 4; ++reg) {
            int co = wave * 32 + m * 16 + quad * 4 + reg;
            float A = g1[co] * rsqrtf(v1[co] + 1e-5f);
            Ac[m * 4 + reg] = A;
            Oc[m * 4 + reg] = fmaf(b1[co] - m1[co], A, be1[co]);
            Wc[m * 4 + reg] = w2[co];
        }
    #pragma unroll
    for (int n = 0; n < 8; ++n) {
        float part = 0.0f;
        #pragma unroll
        for (int m = 0; m < 2; ++m)
            #pragma unroll
            for (int reg = 0; reg < 4; ++reg) {
                float y = fmaxf(fmaf(acc[m][n][reg], Ac[m * 4 + reg], Oc[m * 4 + reg]), 0.0f);
                part = fmaf(Wc[m * 4 + reg], y, part);
            }
        red[(n * 16 + l15) * 33 + wave * 4 + quad] = part;
    }
    __syncthreads();
    if (tid < 128) {
        float z = b2[0];
        #pragma unroll
        for (int k = 0; k < 32; ++k) z += red[tid * 33 + k];
        if (p0 + tid < Np)
            out[ooff + (size_t)b * Np + p0 + tid] = 1.0f / (1.0f + expf(-z));
    }
}

// ---------------------------------------------------------------------------
extern "C" void kernel_launch(void* const* d_in, const int* in_sizes, int n_in,
                              void* d_out, int out_size, void* d_ws, size_t ws_size,
                              hipStream_t stream)
{
    const float* large  = (const float*)d_in[0];
    const float* medium = (const float*)d_in[1];
    const float* small  = (const float*)d_in[2];
    const float* search = (const float*)d_in[3];
    const float* wt  = (const float*)d_in[4];
    const float* bt  = (const float*)d_in[5];
    const float* gt  = (const float*)d_in[6];
    const float* bet = (const float*)d_in[7];
    const float* mt  = (const float*)d_in[8];
    const float* vt  = (const float*)d_in[9];
    const float* wsc = (const float*)d_in[10];
    const float* bs  = (const float*)d_in[11];
    const float* gs  = (const float*)d_in[12];
    const float* bes = (const float*)d_in[13];
    const float* ms  = (const float*)d_in[14];
    const float* vs  = (const float*)d_in[15];
    const float* w1  = (const float*)d_in[16];
    const float* b1  = (const float*)d_in[17];
    const float* g1  = (const float*)d_in[18];
    const float* be1 = (const float*)d_in[19];
    const float* m1  = (const float*)d_in[20];
    const float* v1  = (const float*)d_in[21];
    const float* w2  = (const float*)d_in[22];
    const float* b2  = (const float*)d_in[23];

    float* ws = (float*)d_ws;
    size_t off = 0;
    float* lf = ws + off; off += (size_t)64 * 256 * 49;
    float* mf = ws + off; off += (size_t)64 * 256 * 25;
    float* sf = ws + off; off += (size_t)64 * 256 * 9;
    float* sq = ws + off; off += (size_t)64 * 256 * 841;
    // lc/mc/sc bf16 (regions keep fp32-sized reservations for aliasing)
    short* lc = (short*)(ws + off); off += (size_t)64 * 256 * 729;
    short* mc = (short*)(ws + off); off += (size_t)64 * 256 * 625;
    short* sc = (short*)(ws + off); off += (size_t)64 * 256 * 729;
    // w1 packed buffer: own region (no aliasing -> packed in prep_all)
    short* w1hT = (short*)(ws + off); off += 32768;

    // Aliased prep buffers (dead before corr writes lc/mc/sc):
    short* xh_s = (short*)lc;
    short* base = (short*)sc;
    short* xh_L = base;
    short* xh_M = base + 2654208;
    short* xh_S = base + 4259840;
    short* wh_t = base + 5079040;
    short* wl_t = base + 5668864;
    short* wh_s = base + 6258688;
    short* wl_s = base + 6848512;

    dim3 blk(256);
    prep_all<<<dim3(5440), blk, 0, stream>>>(
        wt, wh_t, wl_t, wsc, wh_s, wl_s,
        search, xh_s, large, xh_L,
        medium, xh_M, small, xh_S,
        w1, w1hT);

    conv_mfma_all<<<dim3(1280), blk, 0, stream>>>(
        xh_s, wh_s, bs, gs, bes, ms, vs, sq,
        xh_L, xh_M, xh_S, wh_t,
        bt, gt, bet, mt, vt, lf, mf, sf);

    corr_kernel<<<dim3(64, 64), blk, 0, stream>>>(lf, mf, sf, sq, lc, mc, sc);

    head_mfma_kernel<<<dim3(17, 64), dim3(512), 0, stream>>>(
        lc, mc, sc, w1hT, b1, g1, be1, m1, v1, w2, b2, (float*)d_out);
}

// Round 23
// 382.735 us; speedup vs baseline: 1.2193x; 1.0154x over previous
//
#include <hip/hip_runtime.h>
#include <math.h>
#include <stdint.h>

typedef __attribute__((ext_vector_type(8))) short short8;
typedef __attribute__((ext_vector_type(4))) float floatx4;

// fp32 -> (bf16 hi | bf16 lo) packed u32.  hi = RNE(x), lo = RNE(x - hi).
__device__ __forceinline__ uint32_t pack_hilo(float x) {
    uint32_t u = __float_as_uint(x);
    uint32_t hi = (u + 0x7FFFu + ((u >> 16) & 1u)) & 0xFFFF0000u;
    float r = x - __uint_as_float(hi);
    uint32_t v = __float_as_uint(r);
    uint32_t lo = ((v + 0x7FFFu + ((v >> 16) & 1u)) >> 16) & 0xFFFFu;
    return hi | lo;
}

// fp32 -> bf16 (RNE), low 16 bits of result.
__device__ __forceinline__ uint32_t bf16rne(float x) {
    uint32_t u = __float_as_uint(x);
    return ((u + 0x7FFFu + ((u >> 16) & 1u)) >> 16) & 0xFFFFu;
}

// bf16 (as short) -> fp32
__device__ __forceinline__ float bf16f(short v) {
    return __uint_as_float(((uint32_t)(uint16_t)v) << 16);
}

// async global->LDS DMA, 16 B per lane; lds dest must be wave-uniform base.
__device__ __forceinline__ void dma16(short* lds, const short* g) {
    __builtin_amdgcn_global_load_lds(
        (const __attribute__((address_space(1))) unsigned int*)g,
        (__attribute__((address_space(3))) unsigned int*)lds,
        16, 0, 0);
}

// ---------------------------------------------------------------------------
// Merged prep: conv weights (blocks 0..255) + activations (256..5375) +
// w1 packing (5376..5439).  w1 bf16-hi only.
// ---------------------------------------------------------------------------
__global__ __launch_bounds__(256) void prep_all(
    const float* __restrict__ wA, short* __restrict__ whA, short* __restrict__ wlA,
    const float* __restrict__ wB, short* __restrict__ whB, short* __restrict__ wlB,
    const float* __restrict__ xs, short* __restrict__ xhS,
    const float* __restrict__ xL, short* __restrict__ xhL,
    const float* __restrict__ xM, short* __restrict__ xhM,
    const float* __restrict__ xSm, short* __restrict__ xhSm,
    const float* __restrict__ w1, short* __restrict__ w1hT)
{
    const int blk = blockIdx.x;
    if (blk < 256) {
        // ---- weight prep: fetch-order layout.  Lane-linear A-fragments:
        // frag(tile, cob, lane) at ((tile)*16 + cob)*512 + lane*8  ----
        int bx = blk;
        const float* w; short *wh, *wl;
        if (bx < 128) { w = wA; wh = whA; wl = wlA; }
        else          { w = wB; wh = whB; wl = wlB; bx -= 128; }
        const int idx = bx * 256 + threadIdx.x;
        const int co = idx >> 7, jp = idx & 127;      // ci = 2*jp
        const int c4 = jp >> 4;                       // ci>>5
        const int g  = (jp >> 2) & 3;                 // (ci>>3)&3
        const int cw = 2 * (jp & 3);                  // ci&7
        const float* s0 = w + ((size_t)co * 256 + 2 * jp) * 9;
        #pragma unroll
        for (int r = 0; r < 9; ++r) {
            uint32_t q0 = pack_hilo(s0[r]);
            uint32_t q1 = pack_hilo(s0[9 + r]);
            size_t o = ((size_t)(r * 8 + c4) * 16 + (co >> 4)) * 512
                     + (size_t)(g * 16 + (co & 15)) * 8 + cw;
            *(uint32_t*)(wh + o) = (q0 >> 16) | (q1 & 0xFFFF0000u);
            *(uint32_t*)(wl + o) = (q0 & 0xFFFFu) | (q1 << 16);
        }
        return;
    }
    if (blk >= 5376) {
        // ---- w1 prep: granule-swizzled chunk-major, bf16-hi only ----
        const int idx = ((blk - 5376) * 256 + threadIdx.x) * 4;
        const int co = idx >> 8, ci = idx & 255;
        const int pos = (ci >> 5) * 8192 + (co >> 4) * 512 + ((ci >> 3) & 3) * 128
                      + (co & 15) * 8 + (ci & 7);
        float4 v4 = *(const float4*)(w1 + (size_t)co * 256 + ci);
        uint2 uh;
        uh.x = bf16rne(v4.x) | (bf16rne(v4.y) << 16);
        uh.y = bf16rne(v4.z) | (bf16rne(v4.w) << 16);
        *(uint2*)(w1hT + pos) = uh;
        return;
    }
    // ---- activation prep (bf16 hi only) ----
    const int i = blk - 256;            // 0..5119
    const int bx = i % 20;
    const int by = (i / 20) & 3;
    const int b  = i / 80;

    const float* x; short *xh; int HW, p0;
    if (bx < 16)      { x = xs;  xh = xhS;  HW = 961; p0 = bx * 64; }
    else if (bx < 18) { x = xL;  xh = xhL;  HW = 81;  p0 = (bx - 16) * 64; }
    else if (bx < 19) { x = xM;  xh = xhM;  HW = 49;  p0 = 0; }
    else              { x = xSm; xh = xhSm; HW = 25;  p0 = 0; }

    const int c0 = by * 64;
    const int tid = threadIdx.x;
    const int a = tid & 63, g = tid >> 6;
    __shared__ uint32_t t[64][65];
    #pragma unroll
    for (int ii = 0; ii < 16; ++ii) {
        int c = g + ii * 4;
        int p = p0 + a;
        float v = (p < HW) ? x[((size_t)(b * 256) + c0 + c) * HW + p] : 0.0f;
        t[c][a] = pack_hilo(v);
    }
    __syncthreads();
    const int j = tid & 31;
    const int gg = tid >> 5;
    #pragma unroll
    for (int ii = 0; ii < 8; ++ii) {
        int p = gg + ii * 8;
        if (p0 + p < HW) {
            uint32_t w0 = t[2 * j][p], w1v = t[2 * j + 1][p];
            size_t o = ((size_t)b * HW + p0 + p) * 256 + c0 + 2 * j;
            *(uint32_t*)(xh + o) = (w0 >> 16) | (w1v & 0xFFFF0000u);
        }
    }
}

// ===========================================================================
// MFMA conv body v11b (R21-proven schedule + BF16 OUTPUT: conv->corr
// interface is now bf16, halving conv writes and corr reads; corr's own
// output was already bf16-rounded, so this adds one ~2^-9 rounding stage —
// the same magnitude the last three numerics changes proved free).
// ===========================================================================
template<bool FULL>
__device__ __forceinline__ void conv_body(
    const short* __restrict__ xh,
    const short* __restrict__ wh,
    const float* __restrict__ bias,
    const float* __restrict__ gam, const float* __restrict__ bet,
    const float* __restrict__ mu,  const float* __restrict__ var,
    short* __restrict__ out,
    int b, int co0, int p0, int H, int W, short* smem)
{
    const int HW = H * W;
    const int Wo = W - 2, P = Wo * Wo;
    const int tid  = threadIdx.x;
    const int wave = tid >> 6, lane = tid & 63;
    const int l15  = lane & 15, quad = lane >> 4;

    int NT = 8;
    if (!FULL) {
        NT = (P - p0 + 15) >> 4;
        if (NT > 8) NT = 8;
    }

    // ---- A-fragment rolling global pointers (direct to VGPR) ----
    const int cob = (co0 >> 4) + wave * 2;
    const short* wA0 = wh + (size_t)cob * 512 + lane * 8;

    // ---- X staging (R2): coalesced rows + granule XOR ----
    const int lrow = lane >> 2;
    const int lci  = ((lane & 3) ^ ((lane >> 3) & 3)) * 8;
    int pr0 = p0 + wave * 32 + lrow;      if (pr0 >= P) pr0 = 0;
    int pr1 = p0 + wave * 32 + 16 + lrow; if (pr1 >= P) pr1 = 0;
    const size_t bbase0 = ((size_t)b * HW + (pr0 / Wo) * W + (pr0 % Wo)) * 256 + lci;
    const size_t bbase1 = ((size_t)b * HW + (pr1 / Wo) * W + (pr1 % Wo)) * 256 + lci;

    const short* xs0 = xh + bbase0;
    const short* xs1 = xh + bbase1;
    const int rowadv = (W - 2) * 256 - 224;

    const int ldsw = wave * 1024;
    const int fBB = l15 * 32 + ((quad ^ ((l15 >> 1) & 3)) * 8); // XOR-swizzled B

    floatx4 acc[2][8];
    #pragma unroll
    for (int s = 0; s < 2; ++s)
        #pragma unroll
        for (int t = 0; t < 8; ++t) acc[s][t] = (floatx4){0.f, 0.f, 0.f, 0.f};

    // LDS: 4 buffers x 4096 shorts (Xh only) = 32 KB
    int jn = 0;
    auto issueX = [&](int q) {          // one K=32 chunk into buffer q
        short* base = smem + q * 4096;
        dma16(base + ldsw,               xs0);
        dma16(base + ldsw + 512,         xs1);
        ++jn;
        const int adv = (jn % 24 == 0) ? rowadv : 32;
        xs0 += adv; xs1 += adv;
    };

    issueX(0);   // chunk 0
    issueX(1);   // chunk 1

    for (int ph = 0; ph < 36; ++ph) {
        const int c0q = (2 * ph) & 3;   // buffer of first chunk: 0 or 2
        // A(pair ph) issued FIRST: older than X(pair ph+1) in the vmcnt queue.
        short8 a0h = *(const short8*)(wA0);
        short8 a1h = *(const short8*)(wA0 + 512);
        short8 c0h = *(const short8*)(wA0 + 8192);
        short8 c1h = *(const short8*)(wA0 + 8704);
        wA0 += 16384;
        asm volatile("s_barrier" ::: "memory");            // pair p-1 compute done
        if (ph < 35) {
            issueX((c0q + 2) & 3);
            issueX((c0q + 3) & 3);
            asm volatile("s_waitcnt vmcnt(4)" ::: "memory"); // pair p + A done
        } else {
            asm volatile("s_waitcnt vmcnt(0)" ::: "memory");
        }
        asm volatile("s_barrier" ::: "memory");            // pair p visible
        const short* bq0 = smem + c0q * 4096;
        const short* bq1 = smem + ((c0q + 1) & 3) * 4096;
        __builtin_amdgcn_s_setprio(1);
        #pragma unroll
        for (int t = 0; t < 8; ++t) {
            if (FULL || t < NT) {
                short8 vh = *(const short8*)(bq0 + t * 512 + fBB);
                acc[0][t] = __builtin_amdgcn_mfma_f32_16x16x32_bf16(a0h, vh, acc[0][t], 0, 0, 0);
                acc[1][t] = __builtin_amdgcn_mfma_f32_16x16x32_bf16(a1h, vh, acc[1][t], 0, 0, 0);
            }
        }
        #pragma unroll
        for (int t = 0; t < 8; ++t) {
            if (FULL || t < NT) {
                short8 vh = *(const short8*)(bq1 + t * 512 + fBB);
                acc[0][t] = __builtin_amdgcn_mfma_f32_16x16x32_bf16(c0h, vh, acc[0][t], 0, 0, 0);
                acc[1][t] = __builtin_amdgcn_mfma_f32_16x16x32_bf16(c1h, vh, acc[1][t], 0, 0, 0);
            }
        }
        __builtin_amdgcn_s_setprio(0);
    }

    #pragma unroll
    for (int s = 0; s < 2; ++s) {
        const int cobase = co0 + wave * 32 + s * 16 + quad * 4;
        #pragma unroll
        for (int reg = 0; reg < 4; ++reg) {
            const int co = cobase + reg;
            const float A   = gam[co] * rsqrtf(var[co] + 1e-5f);
            const float OFF = fmaf(bias[co] - mu[co], A, bet[co]);
            short* orow = out + ((size_t)(b * 256 + co)) * P;
            #pragma unroll
            for (int t = 0; t < 8; ++t) {
                int px = p0 + t * 16 + l15;
                if ((FULL || t < NT) && px < P)
                    orow[px] = (short)bf16rne(fmaxf(fmaf(acc[s][t][reg], A, OFF), 0.0f));
            }
        }
    }
}

// ---------------------------------------------------------------------------
// conv_mfma_all: search (blocks 0..895, XCD swizzle) + all 3 template scales
// (blocks 896..1279) in ONE dispatch.  32 KB LDS.  Outputs bf16.
// ---------------------------------------------------------------------------
__global__ __launch_bounds__(256) void conv_mfma_all(
    const short* __restrict__ xh_s,
    const short* __restrict__ wh_s,
    const float* __restrict__ bs, const float* __restrict__ gs,
    const float* __restrict__ bes, const float* __restrict__ ms,
    const float* __restrict__ vs, short* __restrict__ sq,
    const short* __restrict__ xhL, const short* __restrict__ xhM,
    const short* __restrict__ xhS,
    const short* __restrict__ wh_t,
    const float* __restrict__ bt, const float* __restrict__ gt,
    const float* __restrict__ bet, const float* __restrict__ mt,
    const float* __restrict__ vt,
    short* __restrict__ lf, short* __restrict__ mf, short* __restrict__ sf)
{
    __shared__ __align__(16) short smem[16384];   // 4 x 4096-short X buffers
    const int i = blockIdx.x;
    if (i < 896) {
        const int xcd = i & 7, slot = i >> 3;
        const int bl = slot / 14, tile = slot - bl * 14;
        const int b = xcd * 8 + bl;
        const int cohalf = tile & 1, ptile = tile >> 1;
        if (ptile < 6)
            conv_body<true >(xh_s, wh_s, bs, gs, bes, ms, vs, sq,
                             b, cohalf * 128, ptile * 128, 31, 31, smem);
        else
            conv_body<false>(xh_s, wh_s, bs, gs, bes, ms, vs, sq,
                             b, cohalf * 128, ptile * 128, 31, 31, smem);
    } else {
        const int j = i - 896;                 // 0..383
        const int cohalf = j & 1, sb = j >> 1; // sb 0..191
        const int scale = sb >> 6, b = sb & 63;
        const short* xh = (scale == 0) ? xhL : (scale == 1) ? xhM : xhS;
        short* out      = (scale == 0) ? lf : (scale == 1) ? mf : sf;
        const int H     = (scale == 0) ? 9 : (scale == 1) ? 7 : 5;
        conv_body<false>(xh, wh_t, bt, gt, bet, mt, vt, out,
                         b, cohalf * 128, 0, H, H, smem);
    }
}

// ---------------------------------------------------------------------------
// corr v5 (R14 transposed lane map + bf16 IN and OUT). grid (64,64)
// ---------------------------------------------------------------------------
__global__ __launch_bounds__(256) void corr_kernel(
    const short* __restrict__ lf, const short* __restrict__ mf,
    const short* __restrict__ sf, const short* __restrict__ s,
    short* __restrict__ lc, short* __restrict__ mc, short* __restrict__ sc)
{
    const int b = blockIdx.y;
    const int wave = threadIdx.x >> 6, lane = threadIdx.x & 63;
    const int c = blockIdx.x * 4 + wave;
    const int bc = b * 256 + c;

    __shared__ __align__(16) float sp[4][33 * 36];
    __shared__ float tw[4][96];

    float* P = sp[wave];
    for (int i = lane; i < 33 * 36; i += 64) P[i] = 0.0f;
    if (lane < 49) tw[wave][lane]      = bf16f(lf[(size_t)bc * 49 + lane]);
    if (lane < 25) tw[wave][49 + lane] = bf16f(mf[(size_t)bc * 25 + lane]);
    if (lane < 9)  tw[wave][74 + lane] = bf16f(sf[(size_t)bc * 9 + lane]);
    for (int i = lane; i < 841; i += 64) {
        int y = i / 29, x = i - y * 29;
        P[(y + 2) * 36 + (x + 2)] = bf16f(s[(size_t)bc * 841 + i]);
    }
    __syncthreads();

    const int x = lane & 31;
    const int h = lane >> 5;

    // ---- lc: 7x7 kernel, 27x27 out, no offset ----
    {
        float t7[49];
        #pragma unroll
        for (int k = 0; k < 49; ++k) t7[k] = tw[wave][k];
        for (int pass = 0; pass < 4; ++pass) {
            const int ro = pass * 8 + h * 4;
            float a0 = 0, a1 = 0, a2 = 0, a3 = 0;
            #pragma unroll
            for (int ir = 0; ir < 10; ++ir) {
                int r = ro + ir; if (r > 32) r = 32;
                const float* rp = P + r * 36 + x;
                #pragma unroll
                for (int dx = 0; dx < 7; ++dx) {
                    float v = rp[dx];
                    if (ir <= 6)             a0 = fmaf(t7[ir * 7 + dx], v, a0);
                    if (ir >= 1 && ir <= 7)  a1 = fmaf(t7[(ir - 1) * 7 + dx], v, a1);
                    if (ir >= 2 && ir <= 8)  a2 = fmaf(t7[(ir - 2) * 7 + dx], v, a2);
                    if (ir >= 3)             a3 = fmaf(t7[(ir - 3) * 7 + dx], v, a3);
                }
            }
            if (x < 27) {
                size_t o = (size_t)bc * 729 + (size_t)ro * 27 + x;
                if (ro     < 27) lc[o]      = (short)bf16rne(a0);
                if (ro + 1 < 27) lc[o + 27] = (short)bf16rne(a1);
                if (ro + 2 < 27) lc[o + 54] = (short)bf16rne(a2);
                if (ro + 3 < 27) lc[o + 81] = (short)bf16rne(a3);
            }
        }
    }
    // ---- mc: 5x5 kernel, 25x25 out, +2 offset both dims ----
    {
        float t5[25];
        #pragma unroll
        for (int k = 0; k < 25; ++k) t5[k] = tw[wave][49 + k];
        for (int pass = 0; pass < 4; ++pass) {
            const int ro = pass * 8 + h * 4;
            float a0 = 0, a1 = 0, a2 = 0, a3 = 0;
            #pragma unroll
            for (int ir = 0; ir < 8; ++ir) {
                int r = ro + 2 + ir; if (r > 32) r = 32;
                const float* rp = P + r * 36 + x + 2;
                #pragma unroll
                for (int dx = 0; dx < 5; ++dx) {
                    float v = rp[dx];
                    if (ir <= 4)             a0 = fmaf(t5[ir * 5 + dx], v, a0);
                    if (ir >= 1 && ir <= 5)  a1 = fmaf(t5[(ir - 1) * 5 + dx], v, a1);
                    if (ir >= 2 && ir <= 6)  a2 = fmaf(t5[(ir - 2) * 5 + dx], v, a2);
                    if (ir >= 3)             a3 = fmaf(t5[(ir - 3) * 5 + dx], v, a3);
                }
            }
            if (x < 25) {
                size_t o = (size_t)bc * 625 + (size_t)ro * 25 + x;
                if (ro     < 25) mc[o]      = (short)bf16rne(a0);
                if (ro + 1 < 25) mc[o + 25] = (short)bf16rne(a1);
                if (ro + 2 < 25) mc[o + 50] = (short)bf16rne(a2);
                if (ro + 3 < 25) mc[o + 75] = (short)bf16rne(a3);
            }
        }
    }
    // ---- sc: 3x3 kernel, 27x27 out, +2 offset both dims ----
    {
        float t3[9];
        #pragma unroll
        for (int k = 0; k < 9; ++k) t3[k] = tw[wave][74 + k];
        for (int pass = 0; pass < 4; ++pass) {
            const int ro = pass * 8 + h * 4;
            float a0 = 0, a1 = 0, a2 = 0, a3 = 0;
            #pragma unroll
            for (int ir = 0; ir < 6; ++ir) {
                int r = ro + 2 + ir; if (r > 32) r = 32;
                const float* rp = P + r * 36 + x + 2;
                #pragma unroll
                for (int dx = 0; dx < 3; ++dx) {
                    float v = rp[dx];
                    if (ir <= 2)             a0 = fmaf(t3[ir * 3 + dx], v, a0);
                    if (ir >= 1 && ir <= 3)  a1 = fmaf(t3[(ir - 1) * 3 + dx], v, a1);
                    if (ir >= 2 && ir <= 4)  a2 = fmaf(t3[(ir - 2) * 3 + dx], v, a2);
                    if (ir >= 3)             a3 = fmaf(t3[(ir - 3) * 3 + dx], v, a3);
                }
            }
            if (x < 27) {
                size_t o = (size_t)bc * 729 + (size_t)ro * 27 + x;
                if (ro     < 27) sc[o]      = (short)bf16rne(a0);
                if (ro + 1 < 27) sc[o + 27] = (short)bf16rne(a1);
                if (ro + 2 < 27) sc[o + 54] = (short)bf16rne(a2);
                if (ro + 3 < 27) sc[o + 81] = (short)bf16rne(a3);
            }
        }
    }
}

// ---------------------------------------------------------------------------
// head v7 (R22-proven: 1-term W1, bf16 B inputs). grid (17, 64).
// ---------------------------------------------------------------------------
__global__ __launch_bounds__(512, 4) void head_mfma_kernel(
    const short* __restrict__ lc, const short* __restrict__ mc,
    const short* __restrict__ sc,
    const short* __restrict__ w1hT,
    const float* __restrict__ b1,
    const float* __restrict__ g1, const float* __restrict__ be1,
    const float* __restrict__ m1, const float* __restrict__ v1,
    const float* __restrict__ w2, const float* __restrict__ b2,
    float* __restrict__ out)
{
    const int bx = blockIdx.x;
    const short* X; int Np, ooff, p0;
    if (bx < 6)       { X = lc; Np = 729; ooff = 0;     p0 = bx * 128; }
    else if (bx < 11) { X = mc; Np = 625; ooff = 46656; p0 = (bx - 6) * 128; }
    else              { X = sc; Np = 729; ooff = 86656; p0 = (bx - 11) * 128; }

    const int b  = blockIdx.y;
    const int tid = threadIdx.x;
    const int wave = tid >> 6, lane = tid & 63;   // wave 0..7
    const int l15 = lane & 15, quad = lane >> 4;

    __shared__ __align__(16) short Ah[256 * 32];
    __shared__ __align__(16) short Bh[128 * 42];
    __shared__ float red[128 * 33];

    floatx4 acc[2][8];
    #pragma unroll
    for (int m = 0; m < 2; ++m)
        #pragma unroll
        for (int n = 0; n < 8; ++n) acc[m][n] = (floatx4){0.f, 0.f, 0.f, 0.f};

    const int pxq = tid & 31;      // p-quad: p = pxq*4 + j  (0..127)
    const int cp  = tid >> 5;      // 0..15: channels (2cp, 2cp+1) of 32-chunk

    for (int k0 = 0; k0 < 256; k0 += 32) {
        {
            const int kc = k0 >> 5;
            const short* srcH = w1hT + kc * 8192 + wave * 1024 + lane * 8;
            dma16(Ah + wave * 1024,       srcH);
            dma16(Ah + wave * 1024 + 512, srcH + 512);
        }
        {
            const int pxl = pxq * 4;
            const int gp = p0 + pxl;
            const short* r0 = X + ((size_t)(b * 256) + k0 + 2 * cp) * Np + gp;
            const short* r1 = r0 + Np;
            #pragma unroll
            for (int j = 0; j < 4; ++j) {
                uint32_t u = (gp + j < Np) ? (uint32_t)(uint16_t)r0[j] : 0u;
                uint32_t v = (gp + j < Np) ? (uint32_t)(uint16_t)r1[j] : 0u;
                int o = (pxl + j) * 42 + 2 * cp;
                *(uint32_t*)(Bh + o) = u | (v << 16);
            }
        }
        __syncthreads();
        short8 amh[2];
        #pragma unroll
        for (int m = 0; m < 2; ++m) {
            int ao = (wave * 2 + m) * 512 + lane * 8;   // lane-linear
            amh[m] = *(const short8*)(Ah + ao);
        }
        __builtin_amdgcn_s_setprio(1);
        #pragma unroll
        for (int n = 0; n < 8; ++n) {
            int bo = (n * 16 + l15) * 42 + quad * 8;
            short8 bh = *(const short8*)(Bh + bo);
            #pragma unroll
            for (int m = 0; m < 2; ++m) {
                acc[m][n] = __builtin_amdgcn_mfma_f32_16x16x32_bf16(amh[m], bh, acc[m][n], 0, 0, 0);
            }
        }
        __builtin_amdgcn_s_setprio(0);
        __syncthreads();
    }

    float Ac[8], Oc[8], Wc[8];
    #pragma unroll
    for (int m = 0; m < 2; ++m)
        #pragma unroll
        for (int reg = 0; reg < 4; ++reg) {
            int co = wave * 32 + m * 16 + quad * 4 + reg;
            float A = g1[co] * rsqrtf(v1[co] + 1e-5f);
            Ac[m * 4 + reg] = A;
            Oc[m * 4 + reg] = fmaf(b1[co] - m1[co], A, be1[co]);
            Wc[m * 4 + reg] = w2[co];
        }
    #pragma unroll
    for (int n = 0; n < 8; ++n) {
        float part = 0.0f;
        #pragma unroll
        for (int m = 0; m < 2; ++m)
            #pragma unroll
            for (int reg = 0; reg < 4; ++reg) {
                float y = fmaxf(fmaf(acc[m][n][reg], Ac[m * 4 + reg], Oc[m * 4 + reg]), 0.0f);
                part = fmaf(Wc[m * 4 + reg], y, part);
            }
        red[(n * 16 + l15) * 33 + wave * 4 + quad] = part;
    }
    __syncthreads();
    if (tid < 128) {
        float z = b2[0];
        #pragma unroll
        for (int k = 0; k < 32; ++k) z += red[tid * 33 + k];
        if (p0 + tid < Np)
            out[ooff + (size_t)b * Np + p0 + tid] = 1.0f / (1.0f + expf(-z));
    }
}

// ---------------------------------------------------------------------------
extern "C" void kernel_launch(void* const* d_in, const int* in_sizes, int n_in,
                              void* d_out, int out_size, void* d_ws, size_t ws_size,
                              hipStream_t stream)
{
    const float* large  = (const float*)d_in[0];
    const float* medium = (const float*)d_in[1];
    const float* small  = (const float*)d_in[2];
    const float* search = (const float*)d_in[3];
    const float* wt  = (const float*)d_in[4];
    const float* bt  = (const float*)d_in[5];
    const float* gt  = (const float*)d_in[6];
    const float* bet = (const float*)d_in[7];
    const float* mt  = (const float*)d_in[8];
    const float* vt  = (const float*)d_in[9];
    const float* wsc = (const float*)d_in[10];
    const float* bs  = (const float*)d_in[11];
    const float* gs  = (const float*)d_in[12];
    const float* bes = (const float*)d_in[13];
    const float* ms  = (const float*)d_in[14];
    const float* vs  = (const float*)d_in[15];
    const float* w1  = (const float*)d_in[16];
    const float* b1  = (const float*)d_in[17];
    const float* g1  = (const float*)d_in[18];
    const float* be1 = (const float*)d_in[19];
    const float* m1  = (const float*)d_in[20];
    const float* v1  = (const float*)d_in[21];
    const float* w2  = (const float*)d_in[22];
    const float* b2  = (const float*)d_in[23];

    float* ws = (float*)d_ws;
    size_t off = 0;
    short* lf = (short*)(ws + off); off += (size_t)64 * 256 * 49;
    short* mf = (short*)(ws + off); off += (size_t)64 * 256 * 25;
    short* sf = (short*)(ws + off); off += (size_t)64 * 256 * 9;
    short* sq = (short*)(ws + off); off += (size_t)64 * 256 * 841;
    // lc/mc/sc bf16 (regions keep fp32-sized reservations for aliasing)
    short* lc = (short*)(ws + off); off += (size_t)64 * 256 * 729;
    short* mc = (short*)(ws + off); off += (size_t)64 * 256 * 625;
    short* sc = (short*)(ws + off); off += (size_t)64 * 256 * 729;
    // w1 packed buffer: own region (no aliasing -> packed in prep_all)
    short* w1hT = (short*)(ws + off); off += 32768;

    // Aliased prep buffers (dead before corr writes lc/mc/sc):
    short* xh_s = (short*)lc;
    short* base = (short*)sc;
    short* xh_L = base;
    short* xh_M = base + 2654208;
    short* xh_S = base + 4259840;
    short* wh_t = base + 5079040;
    short* wl_t = base + 5668864;
    short* wh_s = base + 6258688;
    short* wl_s = base + 6848512;

    dim3 blk(256);
    prep_all<<<dim3(5440), blk, 0, stream>>>(
        wt, wh_t, wl_t, wsc, wh_s, wl_s,
        search, xh_s, large, xh_L,
        medium, xh_M, small, xh_S,
        w1, w1hT);

    conv_mfma_all<<<dim3(1280), blk, 0, stream>>>(
        xh_s, wh_s, bs, gs, bes, ms, vs, sq,
        xh_L, xh_M, xh_S, wh_t,
        bt, gt, bet, mt, vt, lf, mf, sf);

    corr_kernel<<<dim3(64, 64), blk, 0, stream>>>(lf, mf, sf, sq, lc, mc, sc);

    head_mfma_kernel<<<dim3(17, 64), dim3(512), 0, stream>>>(
        lc, mc, sc, w1hT, b1, g1, be1, m1, v1, w2, b2, (float*)d_out);
}